// Round 5
// baseline (1155.647 us; speedup 1.0000x reference)
//
#include <hip/hip_runtime.h>

typedef unsigned short u16;
typedef __attribute__((ext_vector_type(4))) float f32x4;
typedef __attribute__((ext_vector_type(8))) short s16x8;

__device__ __forceinline__ u16 f2bf(float f) {
    union { float f; unsigned u; } c; c.f = f;
    return (u16)((c.u + 0x7fffu + ((c.u >> 16) & 1u)) >> 16);
}
__device__ __forceinline__ float bf2f(u16 u) {
    union { unsigned u; float f; } c; c.u = ((unsigned)u) << 16; return c.f;
}
__device__ __forceinline__ unsigned pk2(float a, float b) {
    return (unsigned)f2bf(a) | ((unsigned)f2bf(b) << 16);
}
__device__ __forceinline__ float sigm(float x) { return 1.0f / (1.0f + __expf(-x)); }

// async global->LDS, 16B/lane; LDS dest = wave-uniform base + lane*16
__device__ __forceinline__ void load16_g2l(const void* g, void* l) {
    __builtin_amdgcn_global_load_lds(
        (const __attribute__((address_space(1))) unsigned int*)(unsigned long long)g,
        (__attribute__((address_space(3))) unsigned int*)(unsigned int)(unsigned long long)l,
        16, 0, 0);
}

// ---- f32 -> bf16 convert, 8 elems/thread -----------------------------------
__global__ __launch_bounds__(256) void convF(const float* __restrict__ in,
                                             u16* __restrict__ out, unsigned n8) {
    unsigned i = blockIdx.x * 256u + threadIdx.x;
    if (i >= n8) return;
    float4 a = ((const float4*)in)[2 * i];
    float4 b = ((const float4*)in)[2 * i + 1];
    uint4 o;
    o.x = pk2(a.x, a.y); o.y = pk2(a.z, a.w);
    o.z = pk2(b.x, b.y); o.w = pk2(b.z, b.w);
    ((uint4*)out)[i] = o;
}

// ---- masked-weight prep: Out_bf16 = (M!=0 ? bf16(W) : 0), 8 elems/thread ---
__global__ __launch_bounds__(256) void maskmulF(const float* __restrict__ W,
                                                const float* __restrict__ Mk,
                                                u16* __restrict__ Out, unsigned n8) {
    unsigned i = blockIdx.x * 256u + threadIdx.x;
    if (i >= n8) return;
    float4 w0 = ((const float4*)W)[2 * i], w1 = ((const float4*)W)[2 * i + 1];
    float4 m0 = ((const float4*)Mk)[2 * i], m1 = ((const float4*)Mk)[2 * i + 1];
    uint4 o;
    o.x = pk2(m0.x != 0.f ? w0.x : 0.f, m0.y != 0.f ? w0.y : 0.f);
    o.y = pk2(m0.z != 0.f ? w0.z : 0.f, m0.w != 0.f ? w0.w : 0.f);
    o.z = pk2(m1.x != 0.f ? w1.x : 0.f, m1.y != 0.f ? w1.y : 0.f);
    o.w = pk2(m1.z != 0.f ? w1.z : 0.f, m1.w != 0.f ? w1.w : 0.f);
    ((uint4*)Out)[i] = o;
}

// ---- idx init (defensive vs ws poison) -------------------------------------
__global__ void init_idx(int* __restrict__ idx) {
    if (threadIdx.x < 128) idx[threadIdx.x] = 0;
}

// ---- one-hot column index extraction: mask [n,32] f32 ----------------------
__global__ __launch_bounds__(256) void find_idx(const float* __restrict__ mask,
                                                int n, int* __restrict__ out) {
    int k = blockIdx.x;  // 0..31
    for (int i = threadIdx.x; i < n; i += 256)
        if (mask[(size_t)i * 32 + k] != 0.0f) out[k] = i;
}

// ---- column gathers --------------------------------------------------------
__global__ __launch_bounds__(256) void gatherF(const float* __restrict__ src, int ld,
                                               const int* __restrict__ idx,
                                               u16* __restrict__ dst, int B) {
    int i = blockIdx.x * 256 + threadIdx.x;
    if (i < B * 32) {
        int b = i >> 5, k = i & 31;
        dst[i] = f2bf(src[(size_t)b * ld + idx[k]]);
    }
}
__global__ __launch_bounds__(256) void gatherB(const u16* __restrict__ src, int ld,
                                               const int* __restrict__ idx,
                                               u16* __restrict__ dst, int B) {
    int i = blockIdx.x * 256 + threadIdx.x;
    if (i < B * 32) {
        int b = i >> 5, k = i & 31;
        dst[i] = src[(size_t)b * ld + idx[k]];
    }
}

// ---- xcat assembly (f32 out) ----------------------------------------------
__global__ __launch_bounds__(256) void build_xcat(float* __restrict__ xcat,
                                                  const u16* __restrict__ x5,
                                                  const u16* __restrict__ kg,
                                                  const u16* __restrict__ ki,
                                                  const u16* __restrict__ kc,
                                                  const u16* __restrict__ kp,
                                                  const float* __restrict__ clinn) {
    int i = blockIdx.x * 256 + threadIdx.x;
    if (i >= 2048 * 400) return;
    int b = i / 400, c = i - b * 400;
    float v;
    if (c < 256)      v = bf2f(x5[b * 256 + c]);
    else if (c < 288) v = bf2f(kg[b * 32 + (c - 256)]);
    else if (c < 320) v = bf2f(ki[b * 32 + (c - 288)]);
    else if (c < 352) v = bf2f(kc[b * 32 + (c - 320)]);
    else if (c < 384) v = bf2f(kp[b * 32 + (c - 352)]);
    else              v = clinn[b * 16 + (c - 384)];
    xcat[i] = v;
}

// ---- NT GEMM: 2-slot LDS, depth-2 async prefetch, no mid-loop vmcnt(0) -----
// Block tile 128 x (NT*32); 4 waves 2x2; wave tile 64 x (NT*16).
// Out_bf16[m,n] = inv[m,n]*(c1a*c1b)[n] + sigmoid(acc + bias[n]) * (c2a*c2b)[n]
// K-loop: wait vmcnt<=L, s_barrier, ds_read frags, lgkmcnt(0), s_barrier,
//         issue stage it+2 into the just-read slot, MFMA.
template <int NT>
__global__ __launch_bounds__(256) void gemm_bt(const u16* __restrict__ A,
                                               const u16* __restrict__ W,
                                               u16* __restrict__ Out,
                                               const float* __restrict__ bias,
                                               const float* __restrict__ c1a,
                                               const float* __restrict__ c1b,
                                               const float* __restrict__ c2a,
                                               const float* __restrict__ c2b,
                                               const float* __restrict__ inv,
                                               int N, int K) {
    constexpr int BN = NT * 32;           // 128 (NT=4) or 64 (NT=2)
    constexpr int CB = NT / 2;            // B staging chunks per stage
    constexpr int L  = 2 + CB;            // loads per stage per thread
    __shared__ u16 At[2][4096];           // 128x32 per slot
    __shared__ u16 Bt[2][BN * 32];

    const int tid = threadIdx.x;
    const int lane = tid & 63;
    const int wave = tid >> 6;
    const int wrow = wave >> 1, wcol = wave & 1;
    const int tn = blockIdx.x, tm = blockIdx.y;
    const int row = tid >> 2;             // 0..63
    const int kcol = (tid & 3) * 8;       // element offset within BK=32

    const u16* aS0 = A + (size_t)(tm * 128 + row) * K + kcol;
    const u16* aS1 = aS0 + (size_t)64 * K;
    const u16* bS0 = W + (size_t)(tn * BN + row) * K + kcol;
    const u16* bS1 = bS0 + (size_t)64 * K;    // used only when CB==2
    const int dOff = wave * 512;          // per-wave staging dest (elements)

    const int r16 = lane & 15;
    const int q = lane >> 4;
    const int aOff = (wrow * 64 + r16) * 32 + q * 8;
    const int bOff = (wcol * (NT * 16) + r16) * 32 + q * 8;

    const int nIter = K >> 5;

#define ISSUE(slot, it_)                                           \
    do {                                                           \
        const int k0_ = (it_) << 5;                                \
        load16_g2l(aS0 + k0_, &At[slot][dOff]);                    \
        load16_g2l(aS1 + k0_, &At[slot][2048 + dOff]);             \
        load16_g2l(bS0 + k0_, &Bt[slot][dOff]);                    \
        if (CB == 2) load16_g2l(bS1 + k0_, &Bt[slot][2048 + dOff]);\
    } while (0)

    ISSUE(0, 0);
    if (nIter > 1) ISSUE(1, 1);

    f32x4 acc[4][NT];
#pragma unroll
    for (int i = 0; i < 4; i++)
#pragma unroll
        for (int j = 0; j < NT; j++) acc[i][j] = (f32x4){0.f, 0.f, 0.f, 0.f};

    for (int it = 0; it < nIter; ++it) {
        const int s = it & 1;
        // stage it landed; stage it+1 (and older it+2 issue) stay in flight
        if (it + 1 < nIter) __builtin_amdgcn_s_waitcnt(0xF70 + L);  // vmcnt<=L
        else                __builtin_amdgcn_s_waitcnt(0xF70);      // vmcnt<=0
        __asm__ volatile("" ::: "memory");
        __builtin_amdgcn_s_barrier();
        __asm__ volatile("" ::: "memory");

        s16x8 af[4], bfr[NT];
#pragma unroll
        for (int mi = 0; mi < 4; mi++) af[mi] = *(const s16x8*)(&At[s][aOff + mi * 512]);
#pragma unroll
        for (int ni = 0; ni < NT; ni++) bfr[ni] = *(const s16x8*)(&Bt[s][bOff + ni * 512]);

        __asm__ volatile("" ::: "memory");
        __builtin_amdgcn_s_waitcnt(0xC07F);   // lgkmcnt(0): my ds_reads done
        __builtin_amdgcn_s_barrier();         // all waves done reading slot s
        __asm__ volatile("" ::: "memory");

        if (it + 2 < nIter) ISSUE(s, it + 2);

#pragma unroll
        for (int mi = 0; mi < 4; mi++)
#pragma unroll
            for (int ni = 0; ni < NT; ni++)
                acc[mi][ni] = __builtin_amdgcn_mfma_f32_16x16x32_bf16(af[mi], bfr[ni], acc[mi][ni], 0, 0, 0);
    }
#undef ISSUE

    // epilogue: C/D layout col=lane&15, row=(lane>>4)*4+reg
#pragma unroll
    for (int ni = 0; ni < NT; ni++) {
        const int n = tn * BN + wcol * (NT * 16) + ni * 16 + r16;
        const float bi = bias ? bias[n] : 0.f;
        float c1 = 0.f;
        if (c1a) { c1 = c1a[n]; if (c1b) c1 *= c1b[n]; }
        float c2 = 1.f;
        if (c2a) { c2 = c2a[n]; if (c2b) c2 *= c2b[n]; }
#pragma unroll
        for (int mi = 0; mi < 4; mi++) {
#pragma unroll
            for (int rg = 0; rg < 4; rg++) {
                const int m = tm * 128 + wrow * 64 + mi * 16 + q * 4 + rg;
                float v = sigm(acc[mi][ni][rg] + bi) * c2;
                if (inv) v += inv[(size_t)m * N + n] * c1;
                Out[(size_t)m * N + n] = f2bf(v);
            }
        }
    }
}

// ---- tail: lp = sigmoid(xcat @ W6^T); out = (lp - mean(lp,axis=1)) @ W7^T --
__global__ __launch_bounds__(256) void tail_k(const float* __restrict__ xcat,
                                              const float* __restrict__ W6,
                                              const float* __restrict__ W7,
                                              float* __restrict__ out) {
    __shared__ float xs[8 * 400];
    __shared__ float s1[4][8], s2[4][8], s3[4];
    const int tid = threadIdx.x;
    const int b0 = blockIdx.x * 8;
    for (int i = tid; i < 8 * 400; i += 256) {
        int r = i / 400, k = i - r * 400;
        xs[i] = xcat[(size_t)(b0 + r) * 400 + k];
    }
    __syncthreads();
    const int j = tid;  // output column 0..255
    float acc[8];
#pragma unroll
    for (int r = 0; r < 8; r++) acc[r] = 0.f;
    const float4* wrow = (const float4*)(W6 + (size_t)j * 400);
    for (int c = 0; c < 100; c++) {
        float4 wv = wrow[c];
        const float* wp = (const float*)&wv;
#pragma unroll
        for (int t = 0; t < 4; t++) {
            float w = wp[t];
            int k = c * 4 + t;
#pragma unroll
            for (int r = 0; r < 8; r++) acc[r] += w * xs[r * 400 + k];
        }
    }
    const float w7j = W7[j];
    const int lane = tid & 63, wave = tid >> 6;
    float t3 = w7j;
#pragma unroll
    for (int off = 32; off > 0; off >>= 1) t3 += __shfl_down(t3, off, 64);
    if (lane == 0) s3[wave] = t3;
#pragma unroll
    for (int r = 0; r < 8; r++) {
        float lp = sigm(acc[r]);
        float t1 = lp, t2 = lp * w7j;
#pragma unroll
        for (int off = 32; off > 0; off >>= 1) {
            t1 += __shfl_down(t1, off, 64);
            t2 += __shfl_down(t2, off, 64);
        }
        if (lane == 0) { s1[wave][r] = t1; s2[wave][r] = t2; }
    }
    __syncthreads();
    if (tid < 8) {
        float S1 = s1[0][tid] + s1[1][tid] + s1[2][tid] + s1[3][tid];
        float S2 = s2[0][tid] + s2[1][tid] + s2[2][tid] + s2[3][tid];
        float SW = s3[0] + s3[1] + s3[2] + s3[3];
        out[b0 + tid] = S2 - (S1 * (1.f / 256.f)) * SW;
    }
}

// ---------------------------------------------------------------------------
extern "C" void kernel_launch(void* const* d_in, const int* in_sizes, int n_in,
                              void* d_out, int out_size, void* d_ws, size_t ws_size,
                              hipStream_t stream) {
    const float* x_gene   = (const float*)d_in[0];
    const float* x_invmea = (const float*)d_in[1];
    const float* x_curv   = (const float*)d_in[2];
    const float* clinn    = (const float*)d_in[3];
    const float* Adj      = (const float*)d_in[4];
    const float* edge_m   = (const float*)d_in[5];
    const float* path_m   = (const float*)d_in[6];
    const float* tg_mask  = (const float*)d_in[7];
    const float* ti_mask  = (const float*)d_in[8];
    const float* tc_mask  = (const float*)d_in[9];
    const float* tp_mask  = (const float*)d_in[10];
    const float* W1 = (const float*)d_in[11];  const float* b1 = (const float*)d_in[12];
    const float* W2 = (const float*)d_in[13];  const float* b2 = (const float*)d_in[14];
    const float* W3 = (const float*)d_in[15];  const float* b3 = (const float*)d_in[16];
    const float* W4 = (const float*)d_in[17];  const float* b4 = (const float*)d_in[18];
    const float* W5 = (const float*)d_in[19];  const float* b5 = (const float*)d_in[20];
    const float* W6 = (const float*)d_in[21];
    const float* W7 = (const float*)d_in[22];
    const float* mp11 = (const float*)d_in[23];
    const float* mp12 = (const float*)d_in[24];
    const float* mp1  = (const float*)d_in[25];
    const float* mp21 = (const float*)d_in[26];
    const float* mp22 = (const float*)d_in[27];
    const float* mp2  = (const float*)d_in[28];
    const float* mp3  = (const float*)d_in[29];

    char* ws = (char*)d_ws;
    const float* nulf = nullptr;
    float* out = (float*)d_out;

    // ws layout (ws_size >= ~149 MB confirmed: BIG mode ran in round 3)
    u16*  wm   = (u16*)(ws + 0);               // 64 MiB masked-weight buffer
    u16*  xg   = (u16*)(ws + 67108864);        // 16 MiB (x_gene bf16; dead after L1)
    u16*  w4b  = (u16*)(ws + 67108864);        //  1 MiB (aliases dead xg, after L1)
    u16*  w5b  = (u16*)(ws + 68157440);        //  256 KiB
    u16*  x1   = (u16*)(ws + 83886080);        // 16 MiB
    u16*  x2   = (u16*)(ws + 100663296);       // 32 MiB
    u16*  x3   = (u16*)(ws + 134217728);       //  8 MiB
    u16*  x4   = (u16*)(ws + 142606336);       //  1 MiB
    u16*  x5   = (u16*)(ws + 143654912);       //  1 MiB
    float* xcat = (float*)(ws + 144703488);    //  3.2 MiB
    char* kbase = ws + 147980288;
    u16* kg = (u16*)(kbase + 0);
    u16* ki = (u16*)(kbase + 131072);
    u16* kc = (u16*)(kbase + 262144);
    u16* kp = (u16*)(kbase + 393216);
    int* idxg = (int*)(kbase + 524288);
    int* idxi = idxg + 32;
    int* idxc = idxg + 64;
    int* idxp = idxg + 96;

    // ---- small preps ----
    init_idx<<<1, 128, 0, stream>>>(idxg);
    find_idx<<<32, 256, 0, stream>>>(tg_mask, 4096, idxg);
    find_idx<<<32, 256, 0, stream>>>(ti_mask, 4096, idxi);
    find_idx<<<32, 256, 0, stream>>>(tc_mask, 8192, idxc);
    find_idx<<<32, 256, 0, stream>>>(tp_mask, 2048, idxp);
    gatherF<<<256, 256, 0, stream>>>(x_gene, 4096, idxg, kg, 2048);
    convF<<<4096, 256, 0, stream>>>(x_gene, xg, 1048576u);

    // ---- L1: x1 = x_invmea*(mp11*mp1) + sigmoid(xg @ (W1*Adj)^T + b1)*(mp12*mp1)
    maskmulF<<<8192, 256, 0, stream>>>(W1, Adj, wm, 2097152u);
    gemm_bt<2><<<dim3(64, 16), 256, 0, stream>>>(xg, wm, x1, b1,
                                                 mp11, mp1, mp12, mp1, x_invmea, 4096, 4096);
    gatherB<<<256, 256, 0, stream>>>(x1, 4096, idxi, ki, 2048);
    // xg now dead: convert W4/W5 into its zone
    convF<<<256, 256, 0, stream>>>(W4, w4b, 65536u);
    convF<<<32, 256, 0, stream>>>(W5, w5b, 8192u);

    // ---- L2: x2 = x_curv*(mp21*mp2) + sigmoid(x1 @ (W2*edge_m)^T + b2)*(mp22*mp2)
    maskmulF<<<16384, 256, 0, stream>>>(W2, edge_m, wm, 4194304u);
    gemm_bt<4><<<dim3(64, 16), 256, 0, stream>>>(x1, wm, x2, b2,
                                                 mp21, mp2, mp22, mp2, x_curv, 8192, 4096);
    gatherB<<<256, 256, 0, stream>>>(x2, 8192, idxc, kc, 2048);

    // ---- L3: x3 = sigmoid(x2 @ (W3*path_m)^T + b3) * mp3
    maskmulF<<<8192, 256, 0, stream>>>(W3, path_m, wm, 2097152u);
    gemm_bt<2><<<dim3(32, 16), 256, 0, stream>>>(x2, wm, x3, b3,
                                                 nulf, nulf, mp3, nulf, nulf, 2048, 8192);
    gatherB<<<256, 256, 0, stream>>>(x3, 2048, idxp, kp, 2048);

    // ---- L4: x4 = sigmoid(x3 @ W4^T + b4) ----
    gemm_bt<2><<<dim3(4, 16), 256, 0, stream>>>(x3, w4b, x4, b4,
                                                nulf, nulf, nulf, nulf, nulf, 256, 2048);
    // ---- L5: x5 = sigmoid(x4 @ W5^T + b5) ----
    gemm_bt<2><<<dim3(4, 16), 256, 0, stream>>>(x4, w5b, x5, b5,
                                                nulf, nulf, nulf, nulf, nulf, 256, 256);

    build_xcat<<<3200, 256, 0, stream>>>(xcat, x5, kg, ki, kc, kp, clinn);
    tail_k<<<256, 256, 0, stream>>>(xcat, W6, W7, out);
}

// Round 6
// 1094.146 us; speedup vs baseline: 1.0562x; 1.0562x over previous
//
#include <hip/hip_runtime.h>

typedef unsigned short u16;
typedef __attribute__((ext_vector_type(4))) float f32x4;
typedef __attribute__((ext_vector_type(8))) short s16x8;

__device__ __forceinline__ u16 f2bf(float f) {
    union { float f; unsigned u; } c; c.f = f;
    return (u16)((c.u + 0x7fffu + ((c.u >> 16) & 1u)) >> 16);
}
__device__ __forceinline__ float bf2f(u16 u) {
    union { unsigned u; float f; } c; c.u = ((unsigned)u) << 16; return c.f;
}
__device__ __forceinline__ unsigned pk2(float a, float b) {
    return (unsigned)f2bf(a) | ((unsigned)f2bf(b) << 16);
}
__device__ __forceinline__ float sigm(float x) { return 1.0f / (1.0f + __expf(-x)); }

// async global->LDS, 16B/lane; LDS dest = wave-uniform base + lane*16
__device__ __forceinline__ void load16_g2l(const void* g, void* l) {
    __builtin_amdgcn_global_load_lds(
        (const __attribute__((address_space(1))) unsigned int*)(unsigned long long)g,
        (__attribute__((address_space(3))) unsigned int*)(unsigned int)(unsigned long long)l,
        16, 0, 0);
}

// ---- f32 -> bf16 convert, 8 elems/thread -----------------------------------
__global__ __launch_bounds__(256) void convF(const float* __restrict__ in,
                                             u16* __restrict__ out, unsigned n8) {
    unsigned i = blockIdx.x * 256u + threadIdx.x;
    if (i >= n8) return;
    float4 a = ((const float4*)in)[2 * i];
    float4 b = ((const float4*)in)[2 * i + 1];
    uint4 o;
    o.x = pk2(a.x, a.y); o.y = pk2(a.z, a.w);
    o.z = pk2(b.x, b.y); o.w = pk2(b.z, b.w);
    ((uint4*)out)[i] = o;
}

// ---- masked-weight prep: Out_bf16 = (M!=0 ? bf16(W) : 0), 8 elems/thread ---
__global__ __launch_bounds__(256) void maskmulF(const float* __restrict__ W,
                                                const float* __restrict__ Mk,
                                                u16* __restrict__ Out, unsigned n8) {
    unsigned i = blockIdx.x * 256u + threadIdx.x;
    if (i >= n8) return;
    float4 w0 = ((const float4*)W)[2 * i], w1 = ((const float4*)W)[2 * i + 1];
    float4 m0 = ((const float4*)Mk)[2 * i], m1 = ((const float4*)Mk)[2 * i + 1];
    uint4 o;
    o.x = pk2(m0.x != 0.f ? w0.x : 0.f, m0.y != 0.f ? w0.y : 0.f);
    o.y = pk2(m0.z != 0.f ? w0.z : 0.f, m0.w != 0.f ? w0.w : 0.f);
    o.z = pk2(m1.x != 0.f ? w1.x : 0.f, m1.y != 0.f ? w1.y : 0.f);
    o.w = pk2(m1.z != 0.f ? w1.z : 0.f, m1.w != 0.f ? w1.w : 0.f);
    ((uint4*)Out)[i] = o;
}

// ---- idx init (defensive vs ws poison) -------------------------------------
__global__ void init_idx(int* __restrict__ idx) {
    if (threadIdx.x < 128) idx[threadIdx.x] = 0;
}

// ---- one-hot column index extraction: mask [n,32] f32 ----------------------
__global__ __launch_bounds__(256) void find_idx(const float* __restrict__ mask,
                                                int n, int* __restrict__ out) {
    int k = blockIdx.x;  // 0..31
    for (int i = threadIdx.x; i < n; i += 256)
        if (mask[(size_t)i * 32 + k] != 0.0f) out[k] = i;
}

// ---- column gathers --------------------------------------------------------
__global__ __launch_bounds__(256) void gatherF(const float* __restrict__ src, int ld,
                                               const int* __restrict__ idx,
                                               u16* __restrict__ dst, int B) {
    int i = blockIdx.x * 256 + threadIdx.x;
    if (i < B * 32) {
        int b = i >> 5, k = i & 31;
        dst[i] = f2bf(src[(size_t)b * ld + idx[k]]);
    }
}
__global__ __launch_bounds__(256) void gatherB(const u16* __restrict__ src, int ld,
                                               const int* __restrict__ idx,
                                               u16* __restrict__ dst, int B) {
    int i = blockIdx.x * 256 + threadIdx.x;
    if (i < B * 32) {
        int b = i >> 5, k = i & 31;
        dst[i] = src[(size_t)b * ld + idx[k]];
    }
}

// ---- xcat assembly (f32 out) ----------------------------------------------
__global__ __launch_bounds__(256) void build_xcat(float* __restrict__ xcat,
                                                  const u16* __restrict__ x5,
                                                  const u16* __restrict__ kg,
                                                  const u16* __restrict__ ki,
                                                  const u16* __restrict__ kc,
                                                  const u16* __restrict__ kp,
                                                  const float* __restrict__ clinn) {
    int i = blockIdx.x * 256 + threadIdx.x;
    if (i >= 2048 * 400) return;
    int b = i / 400, c = i - b * 400;
    float v;
    if (c < 256)      v = bf2f(x5[b * 256 + c]);
    else if (c < 288) v = bf2f(kg[b * 32 + (c - 256)]);
    else if (c < 320) v = bf2f(ki[b * 32 + (c - 288)]);
    else if (c < 352) v = bf2f(kc[b * 32 + (c - 320)]);
    else if (c < 384) v = bf2f(kp[b * 32 + (c - 352)]);
    else              v = clinn[b * 16 + (c - 384)];
    xcat[i] = v;
}

// ---- NT GEMM, templated tile: WRxWC waves, wave tile (MF*16)x(NF*16),
//      BK=KC*32, 2-slot LDS, depth-2 async prefetch, bank-XOR-swizzled staging.
// Out_bf16[m,n] = inv[m,n]*(c1a*c1b)[n] + sigmoid(acc + bias[n]) * (c2a*c2b)[n]
template <int WR, int WC, int MF, int NF, int KC, int WPE>
__global__ __launch_bounds__(WR * WC * 64, WPE)
void gemm_t(const u16* __restrict__ A, const u16* __restrict__ W,
            u16* __restrict__ Out,
            const float* __restrict__ bias,
            const float* __restrict__ c1a, const float* __restrict__ c1b,
            const float* __restrict__ c2a, const float* __restrict__ c2b,
            const float* __restrict__ inv, int N, int K) {
    constexpr int NTHR = WR * WC * 64;
    constexpr int BM = WR * MF * 16;
    constexpr int BN = WC * NF * 16;
    constexpr int BK = KC * 32;
    constexpr int CPR = KC * 4;           // 16B chunks per row
    constexpr int MSK = CPR - 1;          // bank-swizzle mask (3 or 7)
    constexpr int CA = BM * CPR / NTHR;   // A chunks per thread per stage
    constexpr int CB = BN * CPR / NTHR;   // B chunks per thread per stage
    constexpr int L  = CA + CB;           // loads per stage per thread

    __shared__ u16 At[2][BM * BK];
    __shared__ u16 Bt[2][BN * BK];

    const int tid = threadIdx.x;
    const int lane = tid & 63;
    const int wave = tid >> 6;
    const int wr = wave / WC, wc = wave % WC;
    const int tn = blockIdx.x, tm = blockIdx.y;
    const int r16 = lane & 15;
    const int q = lane >> 4;

    // staging: thread covers chunks c = tid + j*NTHR; LDS dest = c*16B (contiguous),
    // global source chunk-in-row = p_lds ^ (row & MSK)  (bank swizzle)
    const u16* aSrc[CA];
    int aDst[CA];
#pragma unroll
    for (int j = 0; j < CA; j++) {
        int c = tid + j * NTHR;
        int r = c / CPR, p = c - r * CPR;
        aSrc[j] = A + (size_t)(tm * BM + r) * K + (p ^ (r & MSK)) * 8;
        aDst[j] = c * 8;
    }
    const u16* bSrc[CB];
    int bDst[CB];
#pragma unroll
    for (int j = 0; j < CB; j++) {
        int c = tid + j * NTHR;
        int r = c / CPR, p = c - r * CPR;
        bSrc[j] = W + (size_t)(tn * BN + r) * K + (p ^ (r & MSK)) * 8;
        bDst[j] = c * 8;
    }

    // frag read offsets (elements), swizzle-inverted
    int aRd[MF][KC], bRd[NF][KC];
#pragma unroll
    for (int mi = 0; mi < MF; mi++)
#pragma unroll
        for (int kc = 0; kc < KC; kc++)
            aRd[mi][kc] = (wr * MF * 16 + mi * 16 + r16) * BK + (((kc * 4 + q) ^ (r16 & MSK)) << 3);
#pragma unroll
    for (int ni = 0; ni < NF; ni++)
#pragma unroll
        for (int kc = 0; kc < KC; kc++)
            bRd[ni][kc] = (wc * NF * 16 + ni * 16 + r16) * BK + (((kc * 4 + q) ^ (r16 & MSK)) << 3);

    const int nIter = K / BK;

#define ISSUE(slot, it_)                                              \
    do {                                                              \
        const int k0_ = (it_) * BK;                                   \
        _Pragma("unroll")                                             \
        for (int j = 0; j < CA; j++)                                  \
            load16_g2l(aSrc[j] + k0_, &At[slot][aDst[j]]);            \
        _Pragma("unroll")                                             \
        for (int j = 0; j < CB; j++)                                  \
            load16_g2l(bSrc[j] + k0_, &Bt[slot][bDst[j]]);            \
    } while (0)

    ISSUE(0, 0);
    if (nIter > 1) ISSUE(1, 1);

    f32x4 acc[MF][NF];
#pragma unroll
    for (int i = 0; i < MF; i++)
#pragma unroll
        for (int j = 0; j < NF; j++) acc[i][j] = (f32x4){0.f, 0.f, 0.f, 0.f};

    for (int it = 0; it < nIter; ++it) {
        const int s = it & 1;
        // stage it landed (drain own loads down to stage it+1's L)
        if (it + 1 < nIter) __builtin_amdgcn_s_waitcnt(0xF70 | L);  // vmcnt<=L
        else                __builtin_amdgcn_s_waitcnt(0xF70);      // vmcnt<=0
        __asm__ volatile("" ::: "memory");
        __builtin_amdgcn_s_barrier();
        __asm__ volatile("" ::: "memory");

        s16x8 af[KC][MF], bfr[KC][NF];
#pragma unroll
        for (int kc = 0; kc < KC; kc++) {
#pragma unroll
            for (int mi = 0; mi < MF; mi++) af[kc][mi] = *(const s16x8*)(&At[s][aRd[mi][kc]]);
#pragma unroll
            for (int ni = 0; ni < NF; ni++) bfr[kc][ni] = *(const s16x8*)(&Bt[s][bRd[ni][kc]]);
        }

        __asm__ volatile("" ::: "memory");
        __builtin_amdgcn_s_waitcnt(0xC07F);   // lgkmcnt(0): my ds_reads done
        __builtin_amdgcn_s_barrier();         // all waves done reading slot s
        __asm__ volatile("" ::: "memory");

        if (it + 2 < nIter) ISSUE(s, it + 2);

#pragma unroll
        for (int kc = 0; kc < KC; kc++)
#pragma unroll
            for (int mi = 0; mi < MF; mi++)
#pragma unroll
                for (int ni = 0; ni < NF; ni++)
                    acc[mi][ni] = __builtin_amdgcn_mfma_f32_16x16x32_bf16(af[kc][mi], bfr[kc][ni], acc[mi][ni], 0, 0, 0);
    }
#undef ISSUE

    // epilogue: C/D layout col=lane&15, row=(lane>>4)*4+reg
#pragma unroll
    for (int ni = 0; ni < NF; ni++) {
        const int n = tn * BN + wc * NF * 16 + ni * 16 + r16;
        const float bi = bias ? bias[n] : 0.f;
        float c1 = 0.f;
        if (c1a) { c1 = c1a[n]; if (c1b) c1 *= c1b[n]; }
        float c2 = 1.f;
        if (c2a) { c2 = c2a[n]; if (c2b) c2 *= c2b[n]; }
#pragma unroll
        for (int mi = 0; mi < MF; mi++) {
#pragma unroll
            for (int rg = 0; rg < 4; rg++) {
                const int m = tm * BM + wr * MF * 16 + mi * 16 + q * 4 + rg;
                float v = sigm(acc[mi][ni][rg] + bi) * c2;
                if (inv) v += inv[(size_t)m * N + n] * c1;
                Out[(size_t)m * N + n] = f2bf(v);
            }
        }
    }
}

// ---- tail: lp = sigmoid(xcat @ W6^T); out = (lp - mean(lp,axis=1)) @ W7^T --
__global__ __launch_bounds__(256) void tail_k(const float* __restrict__ xcat,
                                              const float* __restrict__ W6,
                                              const float* __restrict__ W7,
                                              float* __restrict__ out) {
    __shared__ float xs[8 * 400];
    __shared__ float s1[4][8], s2[4][8], s3[4];
    const int tid = threadIdx.x;
    const int b0 = blockIdx.x * 8;
    for (int i = tid; i < 8 * 400; i += 256) {
        int r = i / 400, k = i - r * 400;
        xs[i] = xcat[(size_t)(b0 + r) * 400 + k];
    }
    __syncthreads();
    const int j = tid;  // output column 0..255
    float acc[8];
#pragma unroll
    for (int r = 0; r < 8; r++) acc[r] = 0.f;
    const float4* wrow = (const float4*)(W6 + (size_t)j * 400);
    for (int c = 0; c < 100; c++) {
        float4 wv = wrow[c];
        const float* wp = (const float*)&wv;
#pragma unroll
        for (int t = 0; t < 4; t++) {
            float w = wp[t];
            int k = c * 4 + t;
#pragma unroll
            for (int r = 0; r < 8; r++) acc[r] += w * xs[r * 400 + k];
        }
    }
    const float w7j = W7[j];
    const int lane = tid & 63, wave = tid >> 6;
    float t3 = w7j;
#pragma unroll
    for (int off = 32; off > 0; off >>= 1) t3 += __shfl_down(t3, off, 64);
    if (lane == 0) s3[wave] = t3;
#pragma unroll
    for (int r = 0; r < 8; r++) {
        float lp = sigm(acc[r]);
        float t1 = lp, t2 = lp * w7j;
#pragma unroll
        for (int off = 32; off > 0; off >>= 1) {
            t1 += __shfl_down(t1, off, 64);
            t2 += __shfl_down(t2, off, 64);
        }
        if (lane == 0) { s1[wave][r] = t1; s2[wave][r] = t2; }
    }
    __syncthreads();
    if (tid < 8) {
        float S1 = s1[0][tid] + s1[1][tid] + s1[2][tid] + s1[3][tid];
        float S2 = s2[0][tid] + s2[1][tid] + s2[2][tid] + s2[3][tid];
        float SW = s3[0] + s3[1] + s3[2] + s3[3];
        out[b0 + tid] = S2 - (S1 * (1.f / 256.f)) * SW;
    }
}

// ---------------------------------------------------------------------------
extern "C" void kernel_launch(void* const* d_in, const int* in_sizes, int n_in,
                              void* d_out, int out_size, void* d_ws, size_t ws_size,
                              hipStream_t stream) {
    const float* x_gene   = (const float*)d_in[0];
    const float* x_invmea = (const float*)d_in[1];
    const float* x_curv   = (const float*)d_in[2];
    const float* clinn    = (const float*)d_in[3];
    const float* Adj      = (const float*)d_in[4];
    const float* edge_m   = (const float*)d_in[5];
    const float* path_m   = (const float*)d_in[6];
    const float* tg_mask  = (const float*)d_in[7];
    const float* ti_mask  = (const float*)d_in[8];
    const float* tc_mask  = (const float*)d_in[9];
    const float* tp_mask  = (const float*)d_in[10];
    const float* W1 = (const float*)d_in[11];  const float* b1 = (const float*)d_in[12];
    const float* W2 = (const float*)d_in[13];  const float* b2 = (const float*)d_in[14];
    const float* W3 = (const float*)d_in[15];  const float* b3 = (const float*)d_in[16];
    const float* W4 = (const float*)d_in[17];  const float* b4 = (const float*)d_in[18];
    const float* W5 = (const float*)d_in[19];  const float* b5 = (const float*)d_in[20];
    const float* W6 = (const float*)d_in[21];
    const float* W7 = (const float*)d_in[22];
    const float* mp11 = (const float*)d_in[23];
    const float* mp12 = (const float*)d_in[24];
    const float* mp1  = (const float*)d_in[25];
    const float* mp21 = (const float*)d_in[26];
    const float* mp22 = (const float*)d_in[27];
    const float* mp2  = (const float*)d_in[28];
    const float* mp3  = (const float*)d_in[29];

    char* ws = (char*)d_ws;
    const float* nulf = nullptr;
    float* out = (float*)d_out;

    // ws layout (ws_size >= ~149 MB confirmed: BIG mode ran in round 3)
    u16*  wm   = (u16*)(ws + 0);               // 64 MiB masked-weight buffer
    u16*  xg   = (u16*)(ws + 67108864);        // 16 MiB (x_gene bf16; dead after L1)
    u16*  w4b  = (u16*)(ws + 67108864);        //  1 MiB (aliases dead xg, after L1)
    u16*  w5b  = (u16*)(ws + 68157440);        //  256 KiB
    u16*  x1   = (u16*)(ws + 83886080);        // 16 MiB
    u16*  x2   = (u16*)(ws + 100663296);       // 32 MiB
    u16*  x3   = (u16*)(ws + 134217728);       //  8 MiB
    u16*  x4   = (u16*)(ws + 142606336);       //  1 MiB
    u16*  x5   = (u16*)(ws + 143654912);       //  1 MiB
    float* xcat = (float*)(ws + 144703488);    //  3.2 MiB
    char* kbase = ws + 147980288;
    u16* kg = (u16*)(kbase + 0);
    u16* ki = (u16*)(kbase + 131072);
    u16* kc = (u16*)(kbase + 262144);
    u16* kp = (u16*)(kbase + 393216);
    int* idxg = (int*)(kbase + 524288);
    int* idxi = idxg + 32;
    int* idxc = idxg + 64;
    int* idxp = idxg + 96;

    // ---- small preps ----
    init_idx<<<1, 128, 0, stream>>>(idxg);
    find_idx<<<32, 256, 0, stream>>>(tg_mask, 4096, idxg);
    find_idx<<<32, 256, 0, stream>>>(ti_mask, 4096, idxi);
    find_idx<<<32, 256, 0, stream>>>(tc_mask, 8192, idxc);
    find_idx<<<32, 256, 0, stream>>>(tp_mask, 2048, idxp);
    gatherF<<<256, 256, 0, stream>>>(x_gene, 4096, idxg, kg, 2048);
    convF<<<4096, 256, 0, stream>>>(x_gene, xg, 1048576u);

    // ---- L1: x1 = x_invmea*(mp11*mp1) + sigmoid(xg @ (W1*Adj)^T + b1)*(mp12*mp1)
    // tile 128x256, 8 waves
    maskmulF<<<8192, 256, 0, stream>>>(W1, Adj, wm, 2097152u);
    gemm_t<2, 4, 4, 4, 1, 4><<<dim3(16, 16), 512, 0, stream>>>(
        xg, wm, x1, b1, mp11, mp1, mp12, mp1, x_invmea, 4096, 4096);
    gatherB<<<256, 256, 0, stream>>>(x1, 4096, idxi, ki, 2048);
    // xg now dead: convert W4/W5 into its zone
    convF<<<256, 256, 0, stream>>>(W4, w4b, 65536u);
    convF<<<32, 256, 0, stream>>>(W5, w5b, 8192u);

    // ---- L2: x2 = x_curv*(mp21*mp2) + sigmoid(x1 @ (W2*edge_m)^T + b2)*(mp22*mp2)
    // tile 256x256, 8 waves
    maskmulF<<<16384, 256, 0, stream>>>(W2, edge_m, wm, 4194304u);
    gemm_t<2, 4, 8, 4, 1, 2><<<dim3(32, 8), 512, 0, stream>>>(
        x1, wm, x2, b2, mp21, mp2, mp22, mp2, x_curv, 8192, 4096);
    gatherB<<<256, 256, 0, stream>>>(x2, 8192, idxc, kc, 2048);

    // ---- L3: x3 = sigmoid(x2 @ (W3*path_m)^T + b3) * mp3
    // tile 128x128, BK=64, 8 waves
    maskmulF<<<8192, 256, 0, stream>>>(W3, path_m, wm, 2097152u);
    gemm_t<2, 4, 4, 2, 2, 4><<<dim3(16, 16), 512, 0, stream>>>(
        x2, wm, x3, b3, nulf, nulf, mp3, nulf, nulf, 2048, 8192);
    gatherB<<<256, 256, 0, stream>>>(x3, 2048, idxp, kp, 2048);

    // ---- L4: x4 = sigmoid(x3 @ W4^T + b4) ----
    gemm_t<2, 4, 4, 2, 2, 4><<<dim3(2, 16), 512, 0, stream>>>(
        x3, w4b, x4, b4, nulf, nulf, nulf, nulf, nulf, 256, 2048);
    // ---- L5: x5 = sigmoid(x4 @ W5^T + b5) ----
    gemm_t<2, 4, 4, 2, 2, 4><<<dim3(2, 16), 512, 0, stream>>>(
        x4, w5b, x5, b5, nulf, nulf, nulf, nulf, nulf, 256, 256);

    build_xcat<<<3200, 256, 0, stream>>>(xcat, x5, kg, ki, kc, kp, clinn);
    tail_k<<<256, 256, 0, stream>>>(xcat, W6, W7, out);
}

// Round 7
// 1016.332 us; speedup vs baseline: 1.1371x; 1.0766x over previous
//
#include <hip/hip_runtime.h>

typedef unsigned short u16;
typedef __attribute__((ext_vector_type(4))) float f32x4;
typedef __attribute__((ext_vector_type(8))) short s16x8;

__device__ __forceinline__ u16 f2bf(float f) {
    union { float f; unsigned u; } c; c.f = f;
    return (u16)((c.u + 0x7fffu + ((c.u >> 16) & 1u)) >> 16);
}
__device__ __forceinline__ float bf2f(u16 u) {
    union { unsigned u; float f; } c; c.u = ((unsigned)u) << 16; return c.f;
}
__device__ __forceinline__ unsigned pk2(float a, float b) {
    return (unsigned)f2bf(a) | ((unsigned)f2bf(b) << 16);
}
__device__ __forceinline__ float sigm(float x) { return 1.0f / (1.0f + __expf(-x)); }

// async global->LDS, 16B/lane (dense gemm for L4/L5)
__device__ __forceinline__ void load16_g2l(const void* g, void* l) {
    __builtin_amdgcn_global_load_lds(
        (const __attribute__((address_space(1))) unsigned int*)(unsigned long long)g,
        (__attribute__((address_space(3))) unsigned int*)(unsigned int)(unsigned long long)l,
        16, 0, 0);
}

// ---- f32 -> bf16 convert, 8 elems/thread -----------------------------------
__global__ __launch_bounds__(256) void convF(const float* __restrict__ in,
                                             u16* __restrict__ out, unsigned n8) {
    unsigned i = blockIdx.x * 256u + threadIdx.x;
    if (i >= n8) return;
    float4 a = ((const float4*)in)[2 * i];
    float4 b = ((const float4*)in)[2 * i + 1];
    uint4 o;
    o.x = pk2(a.x, a.y); o.y = pk2(a.z, a.w);
    o.z = pk2(b.x, b.y); o.w = pk2(b.z, b.w);
    ((uint4*)out)[i] = o;
}

// ---- f32 [Rr][Cc] -> bf16 transposed [Cc][Rr] ------------------------------
__global__ __launch_bounds__(256) void transpF(const float* __restrict__ in,
                                               u16* __restrict__ out, int Rr, int Cc) {
    __shared__ float t[64][65];
    const int r0 = blockIdx.y * 64, c0 = blockIdx.x * 64;
    const int tid = threadIdx.x;
#pragma unroll
    for (int i = 0; i < 16; i++) {
        int idx = tid + i * 256;
        int rr = idx >> 6, cc = idx & 63;
        t[rr][cc] = in[(size_t)(r0 + rr) * Cc + c0 + cc];
    }
    __syncthreads();
#pragma unroll
    for (int i = 0; i < 16; i++) {
        int idx = tid + i * 256;
        int cc = idx >> 6, rr = idx & 63;
        out[(size_t)(c0 + cc) * Rr + r0 + rr] = f2bf(t[rr][cc]);
    }
}

// ---- bf16 [Rr][Cc] -> bf16 transposed [Cc][Rr] -----------------------------
__global__ __launch_bounds__(256) void transpB(const u16* __restrict__ in,
                                               u16* __restrict__ out, int Rr, int Cc) {
    __shared__ u16 t[64][66];
    const int r0 = blockIdx.y * 64, c0 = blockIdx.x * 64;
    const int tid = threadIdx.x;
#pragma unroll
    for (int i = 0; i < 16; i++) {
        int idx = tid + i * 256;
        int rr = idx >> 6, cc = idx & 63;
        t[rr][cc] = in[(size_t)(r0 + rr) * Cc + c0 + cc];
    }
    __syncthreads();
#pragma unroll
    for (int i = 0; i < 16; i++) {
        int idx = tid + i * 256;
        int cc = idx >> 6, rr = idx & 63;
        out[(size_t)(c0 + cc) * Rr + r0 + rr] = t[rr][cc];
    }
}

// ---- ELL build: wave per row, prefix-sum slots, no atomics ------------------
// entry u32 = (bf16(w) << 16) | k ; cnt[row] = min(nnz, PAD)
__global__ __launch_bounds__(256) void ell_build(const float* __restrict__ M,
                                                 const float* __restrict__ W,
                                                 unsigned* __restrict__ ell,
                                                 int* __restrict__ cnt,
                                                 int C, int PAD, int R) {
    const int lane = threadIdx.x & 63;
    const int row = blockIdx.x * 4 + (threadIdx.x >> 6);
    if (row >= R) return;
    const float* mrow = M + (size_t)row * C;
    const float* wrow = W + (size_t)row * C;
    int n = 0;
    for (int c = lane * 4; c < C; c += 256) {
        float4 m = *(const float4*)(mrow + c);
        n += (m.x != 0.f) + (m.y != 0.f) + (m.z != 0.f) + (m.w != 0.f);
    }
    int pre = n;
#pragma unroll
    for (int off = 1; off < 64; off <<= 1) {
        int t = __shfl_up(pre, off, 64);
        if (lane >= off) pre += t;
    }
    int s = pre - n;  // exclusive prefix
    unsigned* erow = ell + (size_t)row * PAD;
    for (int c = lane * 4; c < C; c += 256) {
        float4 m = *(const float4*)(mrow + c);
        if (m.x != 0.f) { if (s < PAD) erow[s] = ((unsigned)f2bf(wrow[c + 0]) << 16) | (unsigned)(c + 0); s++; }
        if (m.y != 0.f) { if (s < PAD) erow[s] = ((unsigned)f2bf(wrow[c + 1]) << 16) | (unsigned)(c + 1); s++; }
        if (m.z != 0.f) { if (s < PAD) erow[s] = ((unsigned)f2bf(wrow[c + 2]) << 16) | (unsigned)(c + 2); s++; }
        if (m.w != 0.f) { if (s < PAD) erow[s] = ((unsigned)f2bf(wrow[c + 3]) << 16) | (unsigned)(c + 3); s++; }
    }
    int tot = __shfl(pre, 63, 64);
    if (lane == 0) cnt[row] = tot > PAD ? PAD : tot;
}

// ---- sparse layer: wave = row j, lanes = batch slice ------------------------
// outT[j][b] = invT[j][b]*(c1a*c1b)[j] + sigmoid(sum + bias[j]) * (c2a*c2b)[j]
// BPL = batch elems per lane (4 or 2). grid (B/(64*BPL), R/4); blockIdx.x -> XCD.
template <int BPL>
__global__ __launch_bounds__(256) void spmm(const unsigned* __restrict__ ell,
                                            const int* __restrict__ cnt,
                                            const u16* __restrict__ xT,    // [C][2048]
                                            u16* __restrict__ outT,        // [R][2048]
                                            const float* __restrict__ bias,
                                            const float* __restrict__ c1a,
                                            const float* __restrict__ c1b,
                                            const float* __restrict__ c2a,
                                            const float* __restrict__ c2b,
                                            const u16* __restrict__ invT,
                                            int PAD) {
    const int lane = threadIdx.x & 63;
    const int wv = __builtin_amdgcn_readfirstlane((int)(threadIdx.x >> 6));
    const int j = blockIdx.y * 4 + wv;
    const int b0 = blockIdx.x * (64 * BPL) + lane * BPL;

    const unsigned* ep = ell + (size_t)j * PAD;
    int len = cnt[j];
    if (len > PAD) len = PAD;

    float acc[BPL];
#pragma unroll
    for (int i = 0; i < BPL; i++) acc[i] = 0.f;

    auto body = [&](unsigned e) {
        const int k = (int)(e & 0xFFFFu);
        union { float f; unsigned u; } w; w.u = (e >> 16) << 16;
        const u16* xp = xT + (size_t)k * 2048 + b0;
        if (BPL == 4) {
            uint2 xv = *(const uint2*)xp;
            union { float f; unsigned u; } f0, f1, f2, f3;
            f0.u = xv.x << 16; f1.u = xv.x & 0xFFFF0000u;
            f2.u = xv.y << 16; f3.u = xv.y & 0xFFFF0000u;
            acc[0] += w.f * f0.f; acc[1] += w.f * f1.f;
            acc[2] += w.f * f2.f; acc[3] += w.f * f3.f;
        } else {
            unsigned xv = *(const unsigned*)xp;
            union { float f; unsigned u; } f0, f1;
            f0.u = xv << 16; f1.u = xv & 0xFFFF0000u;
            acc[0] += w.f * f0.f; acc[1] += w.f * f1.f;
        }
    };
    int s = 0;
    for (; s + 4 <= len; s += 4) {
        unsigned e0 = ep[s], e1 = ep[s + 1], e2 = ep[s + 2], e3 = ep[s + 3];
        body(e0); body(e1); body(e2); body(e3);
    }
    for (; s < len; ++s) body(ep[s]);

    const float bi = bias[j];
    float c1 = 0.f;
    if (c1a) { c1 = c1a[j]; if (c1b) c1 *= c1b[j]; }
    float c2 = 1.f;
    if (c2a) { c2 = c2a[j]; if (c2b) c2 *= c2b[j]; }

    float v[BPL];
#pragma unroll
    for (int i = 0; i < BPL; i++) v[i] = sigm(acc[i] + bi) * c2;
    if (invT) {
        const u16* ip = invT + (size_t)j * 2048 + b0;
        if (BPL == 4) {
            uint2 iv = *(const uint2*)ip;
            union { float f; unsigned u; } g0, g1, g2, g3;
            g0.u = iv.x << 16; g1.u = iv.x & 0xFFFF0000u;
            g2.u = iv.y << 16; g3.u = iv.y & 0xFFFF0000u;
            v[0] += g0.f * c1; v[1] += g1.f * c1;
            v[2] += g2.f * c1; v[3] += g3.f * c1;
        } else {
            unsigned iv = *(const unsigned*)ip;
            union { float f; unsigned u; } g0, g1;
            g0.u = iv << 16; g1.u = iv & 0xFFFF0000u;
            v[0] += g0.f * c1; v[1] += g1.f * c1;
        }
    }
    u16* op = outT + (size_t)j * 2048 + b0;
    if (BPL == 4) {
        uint2 ov; ov.x = pk2(v[0], v[1]); ov.y = pk2(v[2], v[3]);
        *(uint2*)op = ov;
    } else {
        *(unsigned*)op = pk2(v[0], v[1]);
    }
}

// ---- idx init (defensive vs ws poison) -------------------------------------
__global__ void init_idx(int* __restrict__ idx) {
    if (threadIdx.x < 128) idx[threadIdx.x] = 0;
}

// ---- one-hot column index extraction: mask [n,32] f32 ----------------------
__global__ __launch_bounds__(256) void find_idx(const float* __restrict__ mask,
                                                int n, int* __restrict__ out) {
    int k = blockIdx.x;  // 0..31
    for (int i = threadIdx.x; i < n; i += 256)
        if (mask[(size_t)i * 32 + k] != 0.0f) out[k] = i;
}

// ---- gathers into transposed kept arrays [32][2048] ------------------------
__global__ __launch_bounds__(256) void gatherFT(const float* __restrict__ src, int ld,
                                                const int* __restrict__ idx,
                                                u16* __restrict__ dstT) {
    int i = blockIdx.x * 256 + threadIdx.x;  // 65536
    int kk = i >> 11, b = i & 2047;
    dstT[i] = f2bf(src[(size_t)b * ld + idx[kk]]);
}
__global__ __launch_bounds__(256) void gatherT(const u16* __restrict__ xT,
                                               const int* __restrict__ idx,
                                               u16* __restrict__ dstT) {
    int i = blockIdx.x * 256 + threadIdx.x;
    int kk = i >> 11, b = i & 2047;
    dstT[i] = xT[(size_t)idx[kk] * 2048 + b];
}

// ---- xcat assembly (f32 out), kept arrays transposed -----------------------
__global__ __launch_bounds__(256) void build_xcat(float* __restrict__ xcat,
                                                  const u16* __restrict__ x5,
                                                  const u16* __restrict__ kgT,
                                                  const u16* __restrict__ kiT,
                                                  const u16* __restrict__ kcT,
                                                  const u16* __restrict__ kpT,
                                                  const float* __restrict__ clinn) {
    int i = blockIdx.x * 256 + threadIdx.x;
    if (i >= 2048 * 400) return;
    int b = i / 400, c = i - b * 400;
    float v;
    if (c < 256)      v = bf2f(x5[b * 256 + c]);
    else if (c < 288) v = bf2f(kgT[(c - 256) * 2048 + b]);
    else if (c < 320) v = bf2f(kiT[(c - 288) * 2048 + b]);
    else if (c < 352) v = bf2f(kcT[(c - 320) * 2048 + b]);
    else if (c < 384) v = bf2f(kpT[(c - 352) * 2048 + b]);
    else              v = clinn[b * 16 + (c - 384)];
    xcat[i] = v;
}

// ---- dense NT GEMM (round-6), used for small L4/L5 only --------------------
template <int WR, int WC, int MF, int NF, int KC, int WPE>
__global__ __launch_bounds__(WR * WC * 64, WPE)
void gemm_t(const u16* __restrict__ A, const u16* __restrict__ W,
            u16* __restrict__ Out, const float* __restrict__ bias, int N, int K) {
    constexpr int NTHR = WR * WC * 64;
    constexpr int BM = WR * MF * 16;
    constexpr int BN = WC * NF * 16;
    constexpr int BK = KC * 32;
    constexpr int CPR = KC * 4;
    constexpr int MSK = CPR - 1;
    constexpr int CA = BM * CPR / NTHR;
    constexpr int CB = BN * CPR / NTHR;
    constexpr int L  = CA + CB;

    __shared__ u16 At[2][BM * BK];
    __shared__ u16 Bt[2][BN * BK];

    const int tid = threadIdx.x;
    const int lane = tid & 63;
    const int wave = tid >> 6;
    const int wr = wave / WC, wc = wave % WC;
    const int tn = blockIdx.x, tm = blockIdx.y;
    const int r16 = lane & 15;
    const int q = lane >> 4;

    const u16* aSrc[CA]; int aDst[CA];
#pragma unroll
    for (int j = 0; j < CA; j++) {
        int c = tid + j * NTHR;
        int r = c / CPR, p = c - r * CPR;
        aSrc[j] = A + (size_t)(tm * BM + r) * K + (p ^ (r & MSK)) * 8;
        aDst[j] = c * 8;
    }
    const u16* bSrc[CB]; int bDst[CB];
#pragma unroll
    for (int j = 0; j < CB; j++) {
        int c = tid + j * NTHR;
        int r = c / CPR, p = c - r * CPR;
        bSrc[j] = W + (size_t)(tn * BN + r) * K + (p ^ (r & MSK)) * 8;
        bDst[j] = c * 8;
    }
    int aRd[MF][KC], bRd[NF][KC];
#pragma unroll
    for (int mi = 0; mi < MF; mi++)
#pragma unroll
        for (int kc = 0; kc < KC; kc++)
            aRd[mi][kc] = (wr * MF * 16 + mi * 16 + r16) * BK + (((kc * 4 + q) ^ (r16 & MSK)) << 3);
#pragma unroll
    for (int ni = 0; ni < NF; ni++)
#pragma unroll
        for (int kc = 0; kc < KC; kc++)
            bRd[ni][kc] = (wc * NF * 16 + ni * 16 + r16) * BK + (((kc * 4 + q) ^ (r16 & MSK)) << 3);

    const int nIter = K / BK;

#define ISSUE(slot, it_)                                              \
    do {                                                              \
        const int k0_ = (it_) * BK;                                   \
        _Pragma("unroll")                                             \
        for (int j = 0; j < CA; j++)                                  \
            load16_g2l(aSrc[j] + k0_, &At[slot][aDst[j]]);            \
        _Pragma("unroll")                                             \
        for (int j = 0; j < CB; j++)                                  \
            load16_g2l(bSrc[j] + k0_, &Bt[slot][bDst[j]]);            \
    } while (0)

    ISSUE(0, 0);
    if (nIter > 1) ISSUE(1, 1);

    f32x4 acc[MF][NF];
#pragma unroll
    for (int i = 0; i < MF; i++)
#pragma unroll
        for (int j = 0; j < NF; j++) acc[i][j] = (f32x4){0.f, 0.f, 0.f, 0.f};

    for (int it = 0; it < nIter; ++it) {
        const int s = it & 1;
        if (it + 1 < nIter) __builtin_amdgcn_s_waitcnt(0xF70 | L);
        else                __builtin_amdgcn_s_waitcnt(0xF70);
        __asm__ volatile("" ::: "memory");
        __builtin_amdgcn_s_barrier();
        __asm__ volatile("" ::: "memory");

        s16x8 af[KC][MF], bfr[KC][NF];
#pragma unroll
        for (int kc = 0; kc < KC; kc++) {
#pragma unroll
            for (int mi = 0; mi < MF; mi++) af[kc][mi] = *(const s16x8*)(&At[s][aRd[mi][kc]]);
#pragma unroll
            for (int ni = 0; ni < NF; ni++) bfr[kc][ni] = *(const s16x8*)(&Bt[s][bRd[ni][kc]]);
        }
        __asm__ volatile("" ::: "memory");
        __builtin_amdgcn_s_waitcnt(0xC07F);
        __builtin_amdgcn_s_barrier();
        __asm__ volatile("" ::: "memory");

        if (it + 2 < nIter) ISSUE(s, it + 2);

#pragma unroll
        for (int kc = 0; kc < KC; kc++)
#pragma unroll
            for (int mi = 0; mi < MF; mi++)
#pragma unroll
                for (int ni = 0; ni < NF; ni++)
                    acc[mi][ni] = __builtin_amdgcn_mfma_f32_16x16x32_bf16(af[kc][mi], bfr[kc][ni], acc[mi][ni], 0, 0, 0);
    }
#undef ISSUE

#pragma unroll
    for (int ni = 0; ni < NF; ni++) {
        const int n = tn * BN + wc * NF * 16 + ni * 16 + r16;
        const float bi = bias ? bias[n] : 0.f;
#pragma unroll
        for (int mi = 0; mi < MF; mi++) {
#pragma unroll
            for (int rg = 0; rg < 4; rg++) {
                const int m = tm * BM + wr * MF * 16 + mi * 16 + q * 4 + rg;
                Out[(size_t)m * N + n] = f2bf(sigm(acc[mi][ni][rg] + bi));
            }
        }
    }
}

// ---- tail: lp = sigmoid(xcat @ W6^T); out = (lp - mean(lp,axis=1)) @ W7^T --
__global__ __launch_bounds__(256) void tail_k(const float* __restrict__ xcat,
                                              const float* __restrict__ W6,
                                              const float* __restrict__ W7,
                                              float* __restrict__ out) {
    __shared__ float xs[8 * 400];
    __shared__ float s1[4][8], s2[4][8], s3[4];
    const int tid = threadIdx.x;
    const int b0 = blockIdx.x * 8;
    for (int i = tid; i < 8 * 400; i += 256) {
        int r = i / 400, k = i - r * 400;
        xs[i] = xcat[(size_t)(b0 + r) * 400 + k];
    }
    __syncthreads();
    const int j = tid;
    float acc[8];
#pragma unroll
    for (int r = 0; r < 8; r++) acc[r] = 0.f;
    const float4* wrow = (const float4*)(W6 + (size_t)j * 400);
    for (int c = 0; c < 100; c++) {
        float4 wv = wrow[c];
        const float* wp = (const float*)&wv;
#pragma unroll
        for (int t = 0; t < 4; t++) {
            float w = wp[t];
            int k = c * 4 + t;
#pragma unroll
            for (int r = 0; r < 8; r++) acc[r] += w * xs[r * 400 + k];
        }
    }
    const float w7j = W7[j];
    const int lane = tid & 63, wave = tid >> 6;
    float t3 = w7j;
#pragma unroll
    for (int off = 32; off > 0; off >>= 1) t3 += __shfl_down(t3, off, 64);
    if (lane == 0) s3[wave] = t3;
#pragma unroll
    for (int r = 0; r < 8; r++) {
        float lp = sigm(acc[r]);
        float t1 = lp, t2 = lp * w7j;
#pragma unroll
        for (int off = 32; off > 0; off >>= 1) {
            t1 += __shfl_down(t1, off, 64);
            t2 += __shfl_down(t2, off, 64);
        }
        if (lane == 0) { s1[wave][r] = t1; s2[wave][r] = t2; }
    }
    __syncthreads();
    if (tid < 8) {
        float S1 = s1[0][tid] + s1[1][tid] + s1[2][tid] + s1[3][tid];
        float S2 = s2[0][tid] + s2[1][tid] + s2[2][tid] + s2[3][tid];
        float SW = s3[0] + s3[1] + s3[2] + s3[3];
        out[b0 + tid] = S2 - (S1 * (1.f / 256.f)) * SW;
    }
}

// ---------------------------------------------------------------------------
extern "C" void kernel_launch(void* const* d_in, const int* in_sizes, int n_in,
                              void* d_out, int out_size, void* d_ws, size_t ws_size,
                              hipStream_t stream) {
    const float* x_gene   = (const float*)d_in[0];
    const float* x_invmea = (const float*)d_in[1];
    const float* x_curv   = (const float*)d_in[2];
    const float* clinn    = (const float*)d_in[3];
    const float* Adj      = (const float*)d_in[4];
    const float* edge_m   = (const float*)d_in[5];
    const float* path_m   = (const float*)d_in[6];
    const float* tg_mask  = (const float*)d_in[7];
    const float* ti_mask  = (const float*)d_in[8];
    const float* tc_mask  = (const float*)d_in[9];
    const float* tp_mask  = (const float*)d_in[10];
    const float* W1 = (const float*)d_in[11];  const float* b1 = (const float*)d_in[12];
    const float* W2 = (const float*)d_in[13];  const float* b2 = (const float*)d_in[14];
    const float* W3 = (const float*)d_in[15];  const float* b3 = (const float*)d_in[16];
    const float* W4 = (const float*)d_in[17];  const float* b4 = (const float*)d_in[18];
    const float* W5 = (const float*)d_in[19];  const float* b5 = (const float*)d_in[20];
    const float* W6 = (const float*)d_in[21];
    const float* W7 = (const float*)d_in[22];
    const float* mp11 = (const float*)d_in[23];
    const float* mp12 = (const float*)d_in[24];
    const float* mp1  = (const float*)d_in[25];
    const float* mp21 = (const float*)d_in[26];
    const float* mp22 = (const float*)d_in[27];
    const float* mp2  = (const float*)d_in[28];
    const float* mp3  = (const float*)d_in[29];

    char* ws = (char*)d_ws;
    const float* nulf = nullptr;
    float* out = (float*)d_out;

    // ws layout (ws_size >= 149e6 confirmed round 3)
    u16*  xTg   = (u16*)(ws + 0);            // 16 MiB [4096][2048]
    float* xcat = (float*)(ws + 0);          // 3.2 MiB, aliases dead xTg at the end
    u16*  xinvT = (u16*)(ws + 16777216);     // 16 MiB [4096][2048]
    u16*  xcvT  = (u16*)(ws + 33554432);     // 32 MiB [8192][2048]
    u16*  x1T   = (u16*)(ws + 67108864);     // 16 MiB [4096][2048]
    u16*  x2T   = (u16*)(ws + 83886080);     // 32 MiB [8192][2048]
    u16*  x3T   = (u16*)(ws + 117440512);    //  8 MiB [2048][2048]
    u16*  x3    = (u16*)(ws + 125829120);    //  8 MiB [2048][2048]
    unsigned* ell1 = (unsigned*)(ws + 134217728);  // 4096*256*4 = 4 MiB
    unsigned* ell2 = (unsigned*)(ws + 138412032);  // 8192*96*4  = 3 MiB
    unsigned* ell3 = (unsigned*)(ws + 141557760);  // 2048*320*4 = 2.5 MiB
    int* cnt1 = (int*)(ws + 144179200);      // 16 KiB
    int* cnt2 = (int*)(ws + 144195584);      // 32 KiB
    int* cnt3 = (int*)(ws + 144228352);      //  8 KiB
    int* idxg = (int*)(ws + 144236544);      // 512 B
    int* idxi = idxg + 32;
    int* idxc = idxg + 64;
    int* idxp = idxg + 96;
    u16* kgT  = (u16*)(ws + 144237056);      // 128 KiB [32][2048]
    u16* kiT  = (u16*)(ws + 144368128);
    u16* kcT  = (u16*)(ws + 144499200);
    u16* kpT  = (u16*)(ws + 144630272);
    u16* w4b  = (u16*)(ws + 144761344);      // 512 KiB wait: 256*2048*2 = 1 MiB
    u16* w5b  = (u16*)(ws + 145809920);      // 128 KiB
    u16* x4   = (u16*)(ws + 145940992);      // 1 MiB
    u16* x5   = (u16*)(ws + 146989568);      // 1 MiB -> ends 148038144 < 149e6

    // ---- preps ----
    init_idx<<<1, 128, 0, stream>>>(idxg);
    find_idx<<<32, 256, 0, stream>>>(tg_mask, 4096, idxg);
    find_idx<<<32, 256, 0, stream>>>(ti_mask, 4096, idxi);
    find_idx<<<32, 256, 0, stream>>>(tc_mask, 8192, idxc);
    find_idx<<<32, 256, 0, stream>>>(tp_mask, 2048, idxp);
    gatherFT<<<256, 256, 0, stream>>>(x_gene, 4096, idxg, kgT);

    transpF<<<dim3(64, 32), 256, 0, stream>>>(x_gene, xTg, 2048, 4096);
    transpF<<<dim3(64, 32), 256, 0, stream>>>(x_invmea, xinvT, 2048, 4096);
    transpF<<<dim3(128, 32), 256, 0, stream>>>(x_curv, xcvT, 2048, 8192);

    ell_build<<<1024, 256, 0, stream>>>(Adj,    W1, ell1, cnt1, 4096, 256, 4096);
    ell_build<<<2048, 256, 0, stream>>>(edge_m, W2, ell2, cnt2, 4096,  96, 8192);
    ell_build<<<512,  256, 0, stream>>>(path_m, W3, ell3, cnt3, 8192, 320, 2048);

    convF<<<256, 256, 0, stream>>>(W4, w4b, 65536u);
    convF<<<32, 256, 0, stream>>>(W5, w5b, 8192u);

    // ---- L1: x1T = xinvT*(mp11*mp1) + sig(sparse(W1*Adj) @ xTg + b1)*(mp12*mp1)
    spmm<4><<<dim3(8, 1024), 256, 0, stream>>>(ell1, cnt1, xTg, x1T, b1,
                                               mp11, mp1, mp12, mp1, xinvT, 256);
    gatherT<<<256, 256, 0, stream>>>(x1T, idxi, kiT);

    // ---- L2: x2T = xcvT*(mp21*mp2) + sig(sparse(W2*edge) @ x1T + b2)*(mp22*mp2)
    spmm<4><<<dim3(8, 2048), 256, 0, stream>>>(ell2, cnt2, x1T, x2T, b2,
                                               mp21, mp2, mp22, mp2, xcvT, 96);
    gatherT<<<256, 256, 0, stream>>>(x2T, idxc, kcT);

    // ---- L3: x3T = sig(sparse(W3*path) @ x2T + b3) * mp3
    spmm<2><<<dim3(16, 512), 256, 0, stream>>>(ell3, cnt3, x2T, x3T, b3,
                                               nulf, nulf, mp3, nulf, (const u16*)nullptr, 320);
    gatherT<<<256, 256, 0, stream>>>(x3T, idxp, kpT);
    transpB<<<dim3(32, 32), 256, 0, stream>>>(x3T, x3, 2048, 2048);

    // ---- L4/L5 dense ----
    gemm_t<2, 4, 4, 2, 2, 4><<<dim3(2, 16), 512, 0, stream>>>(x3, w4b, x4, b4, 256, 2048);
    gemm_t<2, 4, 4, 2, 2, 4><<<dim3(2, 16), 512, 0, stream>>>(x4, w5b, x5, b5, 256, 256);

    build_xcat<<<3200, 256, 0, stream>>>(xcat, x5, kgT, kiT, kcT, kpT, clinn);
    tail_k<<<256, 256, 0, stream>>>(xcat, W6, W7, out);
}

// Round 8
// 992.858 us; speedup vs baseline: 1.1640x; 1.0236x over previous
//
#include <hip/hip_runtime.h>

typedef unsigned short u16;
typedef __attribute__((ext_vector_type(4))) float f32x4;
typedef __attribute__((ext_vector_type(8))) short s16x8;

__device__ __forceinline__ u16 f2bf(float f) {
    union { float f; unsigned u; } c; c.f = f;
    return (u16)((c.u + 0x7fffu + ((c.u >> 16) & 1u)) >> 16);
}
__device__ __forceinline__ float bf2f(u16 u) {
    union { unsigned u; float f; } c; c.u = ((unsigned)u) << 16; return c.f;
}
__device__ __forceinline__ unsigned pk2(float a, float b) {
    return (unsigned)f2bf(a) | ((unsigned)f2bf(b) << 16);
}
__device__ __forceinline__ float sigm(float x) { return 1.0f / (1.0f + __expf(-x)); }

// async global->LDS, 16B/lane (dense gemm for L4/L5)
__device__ __forceinline__ void load16_g2l(const void* g, void* l) {
    __builtin_amdgcn_global_load_lds(
        (const __attribute__((address_space(1))) unsigned int*)(unsigned long long)g,
        (__attribute__((address_space(3))) unsigned int*)(unsigned int)(unsigned long long)l,
        16, 0, 0);
}

// ---- f32 -> bf16 convert, 8 elems/thread -----------------------------------
__global__ __launch_bounds__(256) void convF(const float* __restrict__ in,
                                             u16* __restrict__ out, unsigned n8) {
    unsigned i = blockIdx.x * 256u + threadIdx.x;
    if (i >= n8) return;
    float4 a = ((const float4*)in)[2 * i];
    float4 b = ((const float4*)in)[2 * i + 1];
    uint4 o;
    o.x = pk2(a.x, a.y); o.y = pk2(a.z, a.w);
    o.z = pk2(b.x, b.y); o.w = pk2(b.z, b.w);
    ((uint4*)out)[i] = o;
}

// ---- f32 [Rr][Cc] -> bf16 transposed [Cc][Rr] ------------------------------
__global__ __launch_bounds__(256) void transpF(const float* __restrict__ in,
                                               u16* __restrict__ out, int Rr, int Cc) {
    __shared__ float t[64][65];
    const int r0 = blockIdx.y * 64, c0 = blockIdx.x * 64;
    const int tid = threadIdx.x;
#pragma unroll
    for (int i = 0; i < 16; i++) {
        int idx = tid + i * 256;
        int rr = idx >> 6, cc = idx & 63;
        t[rr][cc] = in[(size_t)(r0 + rr) * Cc + c0 + cc];
    }
    __syncthreads();
#pragma unroll
    for (int i = 0; i < 16; i++) {
        int idx = tid + i * 256;
        int cc = idx >> 6, rr = idx & 63;
        out[(size_t)(c0 + cc) * Rr + r0 + rr] = f2bf(t[rr][cc]);
    }
}

// ---- bf16 [Rr][Cc] -> bf16 transposed [Cc][Rr] -----------------------------
__global__ __launch_bounds__(256) void transpB(const u16* __restrict__ in,
                                               u16* __restrict__ out, int Rr, int Cc) {
    __shared__ u16 t[64][66];
    const int r0 = blockIdx.y * 64, c0 = blockIdx.x * 64;
    const int tid = threadIdx.x;
#pragma unroll
    for (int i = 0; i < 16; i++) {
        int idx = tid + i * 256;
        int rr = idx >> 6, cc = idx & 63;
        t[rr][cc] = in[(size_t)(r0 + rr) * Cc + c0 + cc];
    }
    __syncthreads();
#pragma unroll
    for (int i = 0; i < 16; i++) {
        int idx = tid + i * 256;
        int cc = idx >> 6, rr = idx & 63;
        out[(size_t)(c0 + cc) * Rr + r0 + rr] = t[rr][cc];
    }
}

// ---- ELL build: wave per row, prefix-sum slots, no atomics ------------------
// entry u32 = (bf16(w) << 16) | k ; cnt[row] = min(nnz, PAD)
__global__ __launch_bounds__(256) void ell_build(const float* __restrict__ M,
                                                 const float* __restrict__ W,
                                                 unsigned* __restrict__ ell,
                                                 int* __restrict__ cnt,
                                                 int C, int PAD, int R) {
    const int lane = threadIdx.x & 63;
    const int row = blockIdx.x * 4 + (threadIdx.x >> 6);
    if (row >= R) return;
    const float* mrow = M + (size_t)row * C;
    const float* wrow = W + (size_t)row * C;
    int n = 0;
    for (int c = lane * 4; c < C; c += 256) {
        float4 m = *(const float4*)(mrow + c);
        n += (m.x != 0.f) + (m.y != 0.f) + (m.z != 0.f) + (m.w != 0.f);
    }
    int pre = n;
#pragma unroll
    for (int off = 1; off < 64; off <<= 1) {
        int t = __shfl_up(pre, off, 64);
        if (lane >= off) pre += t;
    }
    int s = pre - n;  // exclusive prefix
    unsigned* erow = ell + (size_t)row * PAD;
    for (int c = lane * 4; c < C; c += 256) {
        float4 m = *(const float4*)(mrow + c);
        if (m.x != 0.f) { if (s < PAD) erow[s] = ((unsigned)f2bf(wrow[c + 0]) << 16) | (unsigned)(c + 0); s++; }
        if (m.y != 0.f) { if (s < PAD) erow[s] = ((unsigned)f2bf(wrow[c + 1]) << 16) | (unsigned)(c + 1); s++; }
        if (m.z != 0.f) { if (s < PAD) erow[s] = ((unsigned)f2bf(wrow[c + 2]) << 16) | (unsigned)(c + 2); s++; }
        if (m.w != 0.f) { if (s < PAD) erow[s] = ((unsigned)f2bf(wrow[c + 3]) << 16) | (unsigned)(c + 3); s++; }
    }
    int tot = __shfl(pre, 63, 64);
    if (lane == 0) cnt[row] = tot > PAD ? PAD : tot;
}

// ---- sparse layer: wave = row j, lanes = batch slice ------------------------
// outT[j][b] = invT[j][b]*(c1a*c1b)[j] + sigmoid(sum + bias[j]) * (c2a*c2b)[j]
// BPL = batch elems per lane. grid (B/(64*BPL), R/4); blockIdx.x -> XCD slice.
// invT loads / outT stores are NON-TEMPORAL so the reused xT slice owns L2.
template <int BPL>
__global__ __launch_bounds__(256) void spmm(const unsigned* __restrict__ ell,
                                            const int* __restrict__ cnt,
                                            const u16* __restrict__ xT,    // [C][2048]
                                            u16* __restrict__ outT,        // [R][2048]
                                            const float* __restrict__ bias,
                                            const float* __restrict__ c1a,
                                            const float* __restrict__ c1b,
                                            const float* __restrict__ c2a,
                                            const float* __restrict__ c2b,
                                            const u16* __restrict__ invT,
                                            int PAD) {
    const int lane = threadIdx.x & 63;
    const int wv = __builtin_amdgcn_readfirstlane((int)(threadIdx.x >> 6));
    const int j = blockIdx.y * 4 + wv;
    const int b0 = blockIdx.x * (64 * BPL) + lane * BPL;

    const unsigned* ep = ell + (size_t)j * PAD;
    int len = cnt[j];
    if (len > PAD) len = PAD;

    float acc[BPL];
#pragma unroll
    for (int i = 0; i < BPL; i++) acc[i] = 0.f;

    auto body = [&](unsigned e) {
        const int k = (int)(e & 0xFFFFu);
        union { float f; unsigned u; } w; w.u = (e >> 16) << 16;
        const u16* xp = xT + (size_t)k * 2048 + b0;
        if (BPL == 4) {
            uint2 xv = *(const uint2*)xp;
            union { float f; unsigned u; } f0, f1, f2, f3;
            f0.u = xv.x << 16; f1.u = xv.x & 0xFFFF0000u;
            f2.u = xv.y << 16; f3.u = xv.y & 0xFFFF0000u;
            acc[0] += w.f * f0.f; acc[1] += w.f * f1.f;
            acc[2] += w.f * f2.f; acc[3] += w.f * f3.f;
        } else {
            unsigned xv = *(const unsigned*)xp;
            union { float f; unsigned u; } f0, f1;
            f0.u = xv << 16; f1.u = xv & 0xFFFF0000u;
            acc[0] += w.f * f0.f; acc[1] += w.f * f1.f;
        }
    };
    int s = 0;
    for (; s + 4 <= len; s += 4) {
        unsigned e0 = ep[s], e1 = ep[s + 1], e2 = ep[s + 2], e3 = ep[s + 3];
        body(e0); body(e1); body(e2); body(e3);
    }
    for (; s < len; ++s) body(ep[s]);

    const float bi = bias[j];
    float c1 = 0.f;
    if (c1a) { c1 = c1a[j]; if (c1b) c1 *= c1b[j]; }
    float c2 = 1.f;
    if (c2a) { c2 = c2a[j]; if (c2b) c2 *= c2b[j]; }

    float v[BPL];
#pragma unroll
    for (int i = 0; i < BPL; i++) v[i] = sigm(acc[i] + bi) * c2;
    if (invT) {
        const u16* ip = invT + (size_t)j * 2048 + b0;
        if (BPL == 4) {
            unsigned long long iv = __builtin_nontemporal_load((const unsigned long long*)ip);
            unsigned lo = (unsigned)iv, hi = (unsigned)(iv >> 32);
            union { float f; unsigned u; } g0, g1, g2, g3;
            g0.u = lo << 16; g1.u = lo & 0xFFFF0000u;
            g2.u = hi << 16; g3.u = hi & 0xFFFF0000u;
            v[0] += g0.f * c1; v[1] += g1.f * c1;
            v[2] += g2.f * c1; v[3] += g3.f * c1;
        } else {
            unsigned iv = __builtin_nontemporal_load((const unsigned*)ip);
            union { float f; unsigned u; } g0, g1;
            g0.u = iv << 16; g1.u = iv & 0xFFFF0000u;
            v[0] += g0.f * c1; v[1] += g1.f * c1;
        }
    }
    u16* op = outT + (size_t)j * 2048 + b0;
    if (BPL == 4) {
        unsigned long long ov = (unsigned long long)pk2(v[0], v[1])
                              | ((unsigned long long)pk2(v[2], v[3]) << 32);
        __builtin_nontemporal_store(ov, (unsigned long long*)op);
    } else {
        __builtin_nontemporal_store(pk2(v[0], v[1]), (unsigned*)op);
    }
}

// ---- fused one-hot index extraction: 4 masks, 32 cols each ------------------
// grid 128: block g -> mask (g>>5), column k (g&31). Max-reduce, self-init.
__global__ __launch_bounds__(256) void find_all(const float* __restrict__ m0, int n0,
                                                const float* __restrict__ m1, int n1,
                                                const float* __restrict__ m2, int n2,
                                                const float* __restrict__ m3, int n3,
                                                int* __restrict__ out) {
    __shared__ int red[256];
    const int g = blockIdx.x;
    const int which = g >> 5, k = g & 31;
    const float* mask; int n;
    if (which == 0)      { mask = m0; n = n0; }
    else if (which == 1) { mask = m1; n = n1; }
    else if (which == 2) { mask = m2; n = n2; }
    else                 { mask = m3; n = n3; }
    int best = -1;
    for (int i = threadIdx.x; i < n; i += 256)
        if (mask[(size_t)i * 32 + k] != 0.0f) best = i;
    red[threadIdx.x] = best;
    __syncthreads();
    for (int off = 128; off > 0; off >>= 1) {
        if (threadIdx.x < off) {
            int o = red[threadIdx.x + off];
            if (o > red[threadIdx.x]) red[threadIdx.x] = o;
        }
        __syncthreads();
    }
    if (threadIdx.x == 0) out[which * 32 + k] = red[0] < 0 ? 0 : red[0];
}

// ---- gathers into transposed kept arrays [32][2048] ------------------------
__global__ __launch_bounds__(256) void gatherFT(const float* __restrict__ src, int ld,
                                                const int* __restrict__ idx,
                                                u16* __restrict__ dstT) {
    int i = blockIdx.x * 256 + threadIdx.x;  // 65536
    int kk = i >> 11, b = i & 2047;
    dstT[i] = f2bf(src[(size_t)b * ld + idx[kk]]);
}
__global__ __launch_bounds__(256) void gatherT(const u16* __restrict__ xT,
                                               const int* __restrict__ idx,
                                               u16* __restrict__ dstT) {
    int i = blockIdx.x * 256 + threadIdx.x;
    int kk = i >> 11, b = i & 2047;
    dstT[i] = xT[(size_t)idx[kk] * 2048 + b];
}

// ---- xcat assembly (f32 out), kept arrays transposed -----------------------
__global__ __launch_bounds__(256) void build_xcat(float* __restrict__ xcat,
                                                  const u16* __restrict__ x5,
                                                  const u16* __restrict__ kgT,
                                                  const u16* __restrict__ kiT,
                                                  const u16* __restrict__ kcT,
                                                  const u16* __restrict__ kpT,
                                                  const float* __restrict__ clinn) {
    int i = blockIdx.x * 256 + threadIdx.x;
    if (i >= 2048 * 400) return;
    int b = i / 400, c = i - b * 400;
    float v;
    if (c < 256)      v = bf2f(x5[b * 256 + c]);
    else if (c < 288) v = bf2f(kgT[(c - 256) * 2048 + b]);
    else if (c < 320) v = bf2f(kiT[(c - 288) * 2048 + b]);
    else if (c < 352) v = bf2f(kcT[(c - 320) * 2048 + b]);
    else if (c < 384) v = bf2f(kpT[(c - 352) * 2048 + b]);
    else              v = clinn[b * 16 + (c - 384)];
    xcat[i] = v;
}

// ---- dense NT GEMM, used for small L4/L5 only ------------------------------
template <int WR, int WC, int MF, int NF, int KC, int WPE>
__global__ __launch_bounds__(WR * WC * 64, WPE)
void gemm_t(const u16* __restrict__ A, const u16* __restrict__ W,
            u16* __restrict__ Out, const float* __restrict__ bias, int N, int K) {
    constexpr int NTHR = WR * WC * 64;
    constexpr int BM = WR * MF * 16;
    constexpr int BN = WC * NF * 16;
    constexpr int BK = KC * 32;
    constexpr int CPR = KC * 4;
    constexpr int MSK = CPR - 1;
    constexpr int CA = BM * CPR / NTHR;
    constexpr int CB = BN * CPR / NTHR;
    constexpr int L  = CA + CB;

    __shared__ u16 At[2][BM * BK];
    __shared__ u16 Bt[2][BN * BK];

    const int tid = threadIdx.x;
    const int lane = tid & 63;
    const int wave = tid >> 6;
    const int wr = wave / WC, wc = wave % WC;
    const int tn = blockIdx.x, tm = blockIdx.y;
    const int r16 = lane & 15;
    const int q = lane >> 4;

    const u16* aSrc[CA]; int aDst[CA];
#pragma unroll
    for (int j = 0; j < CA; j++) {
        int c = tid + j * NTHR;
        int r = c / CPR, p = c - r * CPR;
        aSrc[j] = A + (size_t)(tm * BM + r) * K + (p ^ (r & MSK)) * 8;
        aDst[j] = c * 8;
    }
    const u16* bSrc[CB]; int bDst[CB];
#pragma unroll
    for (int j = 0; j < CB; j++) {
        int c = tid + j * NTHR;
        int r = c / CPR, p = c - r * CPR;
        bSrc[j] = W + (size_t)(tn * BN + r) * K + (p ^ (r & MSK)) * 8;
        bDst[j] = c * 8;
    }
    int aRd[MF][KC], bRd[NF][KC];
#pragma unroll
    for (int mi = 0; mi < MF; mi++)
#pragma unroll
        for (int kc = 0; kc < KC; kc++)
            aRd[mi][kc] = (wr * MF * 16 + mi * 16 + r16) * BK + (((kc * 4 + q) ^ (r16 & MSK)) << 3);
#pragma unroll
    for (int ni = 0; ni < NF; ni++)
#pragma unroll
        for (int kc = 0; kc < KC; kc++)
            bRd[ni][kc] = (wc * NF * 16 + ni * 16 + r16) * BK + (((kc * 4 + q) ^ (r16 & MSK)) << 3);

    const int nIter = K / BK;

#define ISSUE(slot, it_)                                              \
    do {                                                              \
        const int k0_ = (it_) * BK;                                   \
        _Pragma("unroll")                                             \
        for (int j = 0; j < CA; j++)                                  \
            load16_g2l(aSrc[j] + k0_, &At[slot][aDst[j]]);            \
        _Pragma("unroll")                                             \
        for (int j = 0; j < CB; j++)                                  \
            load16_g2l(bSrc[j] + k0_, &Bt[slot][bDst[j]]);            \
    } while (0)

    ISSUE(0, 0);
    if (nIter > 1) ISSUE(1, 1);

    f32x4 acc[MF][NF];
#pragma unroll
    for (int i = 0; i < MF; i++)
#pragma unroll
        for (int j = 0; j < NF; j++) acc[i][j] = (f32x4){0.f, 0.f, 0.f, 0.f};

    for (int it = 0; it < nIter; ++it) {
        const int s = it & 1;
        if (it + 1 < nIter) __builtin_amdgcn_s_waitcnt(0xF70 | L);
        else                __builtin_amdgcn_s_waitcnt(0xF70);
        __asm__ volatile("" ::: "memory");
        __builtin_amdgcn_s_barrier();
        __asm__ volatile("" ::: "memory");

        s16x8 af[KC][MF], bfr[KC][NF];
#pragma unroll
        for (int kc = 0; kc < KC; kc++) {
#pragma unroll
            for (int mi = 0; mi < MF; mi++) af[kc][mi] = *(const s16x8*)(&At[s][aRd[mi][kc]]);
#pragma unroll
            for (int ni = 0; ni < NF; ni++) bfr[kc][ni] = *(const s16x8*)(&Bt[s][bRd[ni][kc]]);
        }
        __asm__ volatile("" ::: "memory");
        __builtin_amdgcn_s_waitcnt(0xC07F);
        __builtin_amdgcn_s_barrier();
        __asm__ volatile("" ::: "memory");

        if (it + 2 < nIter) ISSUE(s, it + 2);

#pragma unroll
        for (int kc = 0; kc < KC; kc++)
#pragma unroll
            for (int mi = 0; mi < MF; mi++)
#pragma unroll
                for (int ni = 0; ni < NF; ni++)
                    acc[mi][ni] = __builtin_amdgcn_mfma_f32_16x16x32_bf16(af[kc][mi], bfr[kc][ni], acc[mi][ni], 0, 0, 0);
    }
#undef ISSUE

#pragma unroll
    for (int ni = 0; ni < NF; ni++) {
        const int n = tn * BN + wc * NF * 16 + ni * 16 + r16;
        const float bi = bias ? bias[n] : 0.f;
#pragma unroll
        for (int mi = 0; mi < MF; mi++) {
#pragma unroll
            for (int rg = 0; rg < 4; rg++) {
                const int m = tm * BM + wr * MF * 16 + mi * 16 + q * 4 + rg;
                Out[(size_t)m * N + n] = f2bf(sigm(acc[mi][ni][rg] + bi));
            }
        }
    }
}

// ---- tail: lp = sigmoid(xcat @ W6^T); out = (lp - mean(lp,axis=1)) @ W7^T --
__global__ __launch_bounds__(256) void tail_k(const float* __restrict__ xcat,
                                              const float* __restrict__ W6,
                                              const float* __restrict__ W7,
                                              float* __restrict__ out) {
    __shared__ float xs[8 * 400];
    __shared__ float s1[4][8], s2[4][8], s3[4];
    const int tid = threadIdx.x;
    const int b0 = blockIdx.x * 8;
    for (int i = tid; i < 8 * 400; i += 256) {
        int r = i / 400, k = i - r * 400;
        xs[i] = xcat[(size_t)(b0 + r) * 400 + k];
    }
    __syncthreads();
    const int j = tid;
    float acc[8];
#pragma unroll
    for (int r = 0; r < 8; r++) acc[r] = 0.f;
    const float4* wrow = (const float4*)(W6 + (size_t)j * 400);
    for (int c = 0; c < 100; c++) {
        float4 wv = wrow[c];
        const float* wp = (const float*)&wv;
#pragma unroll
        for (int t = 0; t < 4; t++) {
            float w = wp[t];
            int k = c * 4 + t;
#pragma unroll
            for (int r = 0; r < 8; r++) acc[r] += w * xs[r * 400 + k];
        }
    }
    const float w7j = W7[j];
    const int lane = tid & 63, wave = tid >> 6;
    float t3 = w7j;
#pragma unroll
    for (int off = 32; off > 0; off >>= 1) t3 += __shfl_down(t3, off, 64);
    if (lane == 0) s3[wave] = t3;
#pragma unroll
    for (int r = 0; r < 8; r++) {
        float lp = sigm(acc[r]);
        float t1 = lp, t2 = lp * w7j;
#pragma unroll
        for (int off = 32; off > 0; off >>= 1) {
            t1 += __shfl_down(t1, off, 64);
            t2 += __shfl_down(t2, off, 64);
        }
        if (lane == 0) { s1[wave][r] = t1; s2[wave][r] = t2; }
    }
    __syncthreads();
    if (tid < 8) {
        float S1 = s1[0][tid] + s1[1][tid] + s1[2][tid] + s1[3][tid];
        float S2 = s2[0][tid] + s2[1][tid] + s2[2][tid] + s2[3][tid];
        float SW = s3[0] + s3[1] + s3[2] + s3[3];
        out[b0 + tid] = S2 - (S1 * (1.f / 256.f)) * SW;
    }
}

// ---------------------------------------------------------------------------
extern "C" void kernel_launch(void* const* d_in, const int* in_sizes, int n_in,
                              void* d_out, int out_size, void* d_ws, size_t ws_size,
                              hipStream_t stream) {
    const float* x_gene   = (const float*)d_in[0];
    const float* x_invmea = (const float*)d_in[1];
    const float* x_curv   = (const float*)d_in[2];
    const float* clinn    = (const float*)d_in[3];
    const float* Adj      = (const float*)d_in[4];
    const float* edge_m   = (const float*)d_in[5];
    const float* path_m   = (const float*)d_in[6];
    const float* tg_mask  = (const float*)d_in[7];
    const float* ti_mask  = (const float*)d_in[8];
    const float* tc_mask  = (const float*)d_in[9];
    const float* tp_mask  = (const float*)d_in[10];
    const float* W1 = (const float*)d_in[11];  const float* b1 = (const float*)d_in[12];
    const float* W2 = (const float*)d_in[13];  const float* b2 = (const float*)d_in[14];
    const float* W3 = (const float*)d_in[15];  const float* b3 = (const float*)d_in[16];
    const float* W4 = (const float*)d_in[17];  const float* b4 = (const float*)d_in[18];
    const float* W5 = (const float*)d_in[19];  const float* b5 = (const float*)d_in[20];
    const float* W6 = (const float*)d_in[21];
    const float* W7 = (const float*)d_in[22];
    const float* mp11 = (const float*)d_in[23];
    const float* mp12 = (const float*)d_in[24];
    const float* mp1  = (const float*)d_in[25];
    const float* mp21 = (const float*)d_in[26];
    const float* mp22 = (const float*)d_in[27];
    const float* mp2  = (const float*)d_in[28];
    const float* mp3  = (const float*)d_in[29];

    char* ws = (char*)d_ws;
    const float* nulf = nullptr;
    float* out = (float*)d_out;

    // ws layout (ws_size >= 149e6 confirmed round 3; fills show ~676 MB actual)
    u16*  xTg   = (u16*)(ws + 0);            // 16 MiB [4096][2048]
    float* xcat = (float*)(ws + 0);          // 3.2 MiB, aliases dead xTg
    u16*  xinvT = (u16*)(ws + 16777216);     // 16 MiB [4096][2048]
    u16*  xcvT  = (u16*)(ws + 33554432);     // 32 MiB [8192][2048]
    u16*  x1T   = (u16*)(ws + 67108864);     // 16 MiB [4096][2048]
    u16*  x2T   = (u16*)(ws + 83886080);     // 32 MiB [8192][2048]
    u16*  x3T   = (u16*)(ws + 117440512);    //  8 MiB [2048][2048]
    u16*  x3    = (u16*)(ws + 125829120);    //  8 MiB [2048][2048]
    unsigned* ell1 = (unsigned*)(ws + 134217728);  // 4 MiB
    unsigned* ell2 = (unsigned*)(ws + 138412032);  // 3 MiB
    unsigned* ell3 = (unsigned*)(ws + 141557760);  // 2.5 MiB
    int* cnt1 = (int*)(ws + 144179200);
    int* cnt2 = (int*)(ws + 144195584);
    int* cnt3 = (int*)(ws + 144228352);
    int* idxg = (int*)(ws + 144236544);      // 512 B (4 x 32 ints)
    int* idxi = idxg + 32;
    int* idxc = idxg + 64;
    int* idxp = idxg + 96;
    u16* kgT  = (u16*)(ws + 144237056);      // 128 KiB [32][2048]
    u16* kiT  = (u16*)(ws + 144368128);
    u16* kcT  = (u16*)(ws + 144499200);
    u16* kpT  = (u16*)(ws + 144630272);
    u16* w4b  = (u16*)(ws + 144761344);      // 1 MiB
    u16* w5b  = (u16*)(ws + 145809920);      // 128 KiB
    u16* x4   = (u16*)(ws + 145940992);      // 1 MiB
    u16* x5   = (u16*)(ws + 146989568);      // 1 MiB

    // ---- preps ----
    find_all<<<128, 256, 0, stream>>>(tg_mask, 4096, ti_mask, 4096,
                                      tc_mask, 8192, tp_mask, 2048, idxg);
    gatherFT<<<256, 256, 0, stream>>>(x_gene, 4096, idxg, kgT);

    transpF<<<dim3(64, 32), 256, 0, stream>>>(x_gene, xTg, 2048, 4096);
    transpF<<<dim3(64, 32), 256, 0, stream>>>(x_invmea, xinvT, 2048, 4096);
    transpF<<<dim3(128, 32), 256, 0, stream>>>(x_curv, xcvT, 2048, 8192);

    ell_build<<<1024, 256, 0, stream>>>(Adj,    W1, ell1, cnt1, 4096, 256, 4096);
    ell_build<<<2048, 256, 0, stream>>>(edge_m, W2, ell2, cnt2, 4096,  96, 8192);
    ell_build<<<512,  256, 0, stream>>>(path_m, W3, ell3, cnt3, 8192, 320, 2048);

    convF<<<256, 256, 0, stream>>>(W4, w4b, 65536u);
    convF<<<32, 256, 0, stream>>>(W5, w5b, 8192u);

    // ---- L1: x1T = xinvT*(mp11*mp1) + sig(sparse(W1*Adj) @ xTg + b1)*(mp12*mp1)
    spmm<4><<<dim3(8, 1024), 256, 0, stream>>>(ell1, cnt1, xTg, x1T, b1,
                                               mp11, mp1, mp12, mp1, xinvT, 256);
    gatherT<<<256, 256, 0, stream>>>(x1T, idxi, kiT);

    // ---- L2: x2T = xcvT*(mp21*mp2) + sig(sparse(W2*edge) @ x1T + b2)*(mp22*mp2)
    spmm<4><<<dim3(8, 2048), 256, 0, stream>>>(ell2, cnt2, x1T, x2T, b2,
                                               mp21, mp2, mp22, mp2, xcvT, 96);
    gatherT<<<256, 256, 0, stream>>>(x2T, idxc, kcT);

    // ---- L3: x3T = sig(sparse(W3*path) @ x2T + b3) * mp3
    spmm<2><<<dim3(16, 512), 256, 0, stream>>>(ell3, cnt3, x2T, x3T, b3,
                                               nulf, nulf, mp3, nulf, (const u16*)nullptr, 320);
    gatherT<<<256, 256, 0, stream>>>(x3T, idxp, kpT);
    transpB<<<dim3(32, 32), 256, 0, stream>>>(x3T, x3, 2048, 2048);

    // ---- L4/L5 dense, 64x64 tiles for occupancy (128 blocks each) ----
    gemm_t<2, 2, 2, 2, 2, 4><<<dim3(4, 32), 256, 0, stream>>>(x3, w4b, x4, b4, 256, 2048);
    gemm_t<2, 2, 2, 2, 2, 4><<<dim3(4, 32), 256, 0, stream>>>(x4, w5b, x5, b5, 256, 256);

    build_xcat<<<3200, 256, 0, stream>>>(xcat, x5, kgT, kiT, kcT, kpT, clinn);
    tail_k<<<256, 256, 0, stream>>>(xcat, W6, W7, out);
}

// Round 9
// 950.587 us; speedup vs baseline: 1.2157x; 1.0445x over previous
//
#include <hip/hip_runtime.h>

typedef unsigned short u16;
typedef __attribute__((ext_vector_type(4))) float f32x4;
typedef __attribute__((ext_vector_type(8))) short s16x8;

__device__ __forceinline__ u16 f2bf(float f) {
    union { float f; unsigned u; } c; c.f = f;
    return (u16)((c.u + 0x7fffu + ((c.u >> 16) & 1u)) >> 16);
}
__device__ __forceinline__ float bf2f(u16 u) {
    union { unsigned u; float f; } c; c.u = ((unsigned)u) << 16; return c.f;
}
__device__ __forceinline__ unsigned pk2(float a, float b) {
    return (unsigned)f2bf(a) | ((unsigned)f2bf(b) << 16);
}
__device__ __forceinline__ float sigm(float x) { return 1.0f / (1.0f + __expf(-x)); }
__device__ __forceinline__ void fma2(unsigned xv, float w, float& a0, float& a1) {
    union { float f; unsigned u; } lo, hi;
    lo.u = xv << 16; hi.u = xv & 0xFFFF0000u;
    a0 += w * lo.f; a1 += w * hi.f;
}

// async global->LDS, 16B/lane (dense gemm for L4/L5)
__device__ __forceinline__ void load16_g2l(const void* g, void* l) {
    __builtin_amdgcn_global_load_lds(
        (const __attribute__((address_space(1))) unsigned int*)(unsigned long long)g,
        (__attribute__((address_space(3))) unsigned int*)(unsigned int)(unsigned long long)l,
        16, 0, 0);
}

// ---- f32 -> bf16 convert, 8 elems/thread -----------------------------------
__global__ __launch_bounds__(256) void convF(const float* __restrict__ in,
                                             u16* __restrict__ out, unsigned n8) {
    unsigned i = blockIdx.x * 256u + threadIdx.x;
    if (i >= n8) return;
    float4 a = ((const float4*)in)[2 * i];
    float4 b = ((const float4*)in)[2 * i + 1];
    uint4 o;
    o.x = pk2(a.x, a.y); o.y = pk2(a.z, a.w);
    o.z = pk2(b.x, b.y); o.w = pk2(b.z, b.w);
    ((uint4*)out)[i] = o;
}

// ---- f32 [Rr][Cc] -> bf16 transposed [Cc][Rr] ------------------------------
__global__ __launch_bounds__(256) void transpF(const float* __restrict__ in,
                                               u16* __restrict__ out, int Rr, int Cc) {
    __shared__ float t[64][65];
    const int r0 = blockIdx.y * 64, c0 = blockIdx.x * 64;
    const int tid = threadIdx.x;
#pragma unroll
    for (int i = 0; i < 16; i++) {
        int idx = tid + i * 256;
        int rr = idx >> 6, cc = idx & 63;
        t[rr][cc] = in[(size_t)(r0 + rr) * Cc + c0 + cc];
    }
    __syncthreads();
#pragma unroll
    for (int i = 0; i < 16; i++) {
        int idx = tid + i * 256;
        int cc = idx >> 6, rr = idx & 63;
        out[(size_t)(c0 + cc) * Rr + r0 + rr] = f2bf(t[rr][cc]);
    }
}

// ---- bf16 [Rr][Cc] -> bf16 transposed [Cc][Rr] -----------------------------
__global__ __launch_bounds__(256) void transpB(const u16* __restrict__ in,
                                               u16* __restrict__ out, int Rr, int Cc) {
    __shared__ u16 t[64][66];
    const int r0 = blockIdx.y * 64, c0 = blockIdx.x * 64;
    const int tid = threadIdx.x;
#pragma unroll
    for (int i = 0; i < 16; i++) {
        int idx = tid + i * 256;
        int rr = idx >> 6, cc = idx & 63;
        t[rr][cc] = in[(size_t)(r0 + rr) * Cc + c0 + cc];
    }
    __syncthreads();
#pragma unroll
    for (int i = 0; i < 16; i++) {
        int idx = tid + i * 256;
        int cc = idx >> 6, rr = idx & 63;
        out[(size_t)(c0 + cc) * Rr + r0 + rr] = t[rr][cc];
    }
}

// ---- ELL build: wave per row, prefix-sum slots, no atomics ------------------
// entry u32 = (bf16(w) << 16) | k ; cnt[row] = min(nnz, PAD)
// W loaded only at nonzero mask positions (selective scalar loads).
__global__ __launch_bounds__(256) void ell_build(const float* __restrict__ M,
                                                 const float* __restrict__ W,
                                                 unsigned* __restrict__ ell,
                                                 int* __restrict__ cnt,
                                                 int C, int PAD, int R) {
    const int lane = threadIdx.x & 63;
    const int row = blockIdx.x * 4 + (threadIdx.x >> 6);
    if (row >= R) return;
    const float* mrow = M + (size_t)row * C;
    const float* wrow = W + (size_t)row * C;
    int n = 0;
    for (int c = lane * 4; c < C; c += 256) {
        float4 m = *(const float4*)(mrow + c);
        n += (m.x != 0.f) + (m.y != 0.f) + (m.z != 0.f) + (m.w != 0.f);
    }
    int pre = n;
#pragma unroll
    for (int off = 1; off < 64; off <<= 1) {
        int t = __shfl_up(pre, off, 64);
        if (lane >= off) pre += t;
    }
    int s = pre - n;  // exclusive prefix
    unsigned* erow = ell + (size_t)row * PAD;
    for (int c = lane * 4; c < C; c += 256) {
        float4 m = *(const float4*)(mrow + c);
        if (m.x != 0.f) { if (s < PAD) erow[s] = ((unsigned)f2bf(wrow[c + 0]) << 16) | (unsigned)(c + 0); s++; }
        if (m.y != 0.f) { if (s < PAD) erow[s] = ((unsigned)f2bf(wrow[c + 1]) << 16) | (unsigned)(c + 1); s++; }
        if (m.z != 0.f) { if (s < PAD) erow[s] = ((unsigned)f2bf(wrow[c + 2]) << 16) | (unsigned)(c + 2); s++; }
        if (m.w != 0.f) { if (s < PAD) erow[s] = ((unsigned)f2bf(wrow[c + 3]) << 16) | (unsigned)(c + 3); s++; }
    }
    int tot = __shfl(pre, 63, 64);
    if (lane == 0) cnt[row] = tot > PAD ? PAD : tot;
}

// ---- sparse layer v2: wave = row j, lanes = batch slice ---------------------
// Double-buffered entry groups of 8: group g+1's (wave-uniform) ELL entries
// load while group g's 8 independent x-loads + FMAs retire.
// outT[j][b] = invT[j][b]*(c1a*c1b)[j] + sigmoid(sum + bias[j]) * (c2a*c2b)[j]
template <int BPL>
__global__ __launch_bounds__(256) void spmm(const unsigned* __restrict__ ell,
                                            const int* __restrict__ cnt,
                                            const u16* __restrict__ xT,    // [C][2048]
                                            u16* __restrict__ outT,        // [R][2048]
                                            const float* __restrict__ bias,
                                            const float* __restrict__ c1a,
                                            const float* __restrict__ c1b,
                                            const float* __restrict__ c2a,
                                            const float* __restrict__ c2b,
                                            const u16* __restrict__ invT,
                                            int PAD) {
    const int lane = threadIdx.x & 63;
    const int wv = __builtin_amdgcn_readfirstlane((int)(threadIdx.x >> 6));
    const int j = blockIdx.y * 4 + wv;
    const int b0 = blockIdx.x * (64 * BPL) + lane * BPL;

    const unsigned* ep = ell + (size_t)j * PAD;
    int len = cnt[j];
    if (len > PAD) len = PAD;

    float acc[BPL];
#pragma unroll
    for (int i = 0; i < BPL; i++) acc[i] = 0.f;

    const int nfull = len >> 3;
    unsigned eA[8];
    if (nfull > 0) {
#pragma unroll
        for (int t = 0; t < 8; t++) eA[t] = ep[t];
    }
    for (int g = 0; g < nfull; g++) {
        unsigned eB[8];
        const bool more = (g + 1 < nfull);
        if (more) {
#pragma unroll
            for (int t = 0; t < 8; t++) eB[t] = ep[(g + 1) * 8 + t];
        }
        if (BPL == 8) {
            uint4 xv[8];
#pragma unroll
            for (int t = 0; t < 8; t++)
                xv[t] = *(const uint4*)(xT + ((size_t)(eA[t] & 0xFFFFu) << 11) + b0);
#pragma unroll
            for (int t = 0; t < 8; t++) {
                union { float f; unsigned u; } w; w.u = (eA[t] >> 16) << 16;
                fma2(xv[t].x, w.f, acc[0], acc[1]);
                fma2(xv[t].y, w.f, acc[2], acc[3]);
                fma2(xv[t].z, w.f, acc[4], acc[5]);
                fma2(xv[t].w, w.f, acc[6], acc[7]);
            }
        } else {
            uint2 xv[8];
#pragma unroll
            for (int t = 0; t < 8; t++)
                xv[t] = *(const uint2*)(xT + ((size_t)(eA[t] & 0xFFFFu) << 11) + b0);
#pragma unroll
            for (int t = 0; t < 8; t++) {
                union { float f; unsigned u; } w; w.u = (eA[t] >> 16) << 16;
                fma2(xv[t].x, w.f, acc[0], acc[1]);
                fma2(xv[t].y, w.f, acc[2], acc[3]);
            }
        }
        if (more) {
#pragma unroll
            for (int t = 0; t < 8; t++) eA[t] = eB[t];
        }
    }
    for (int s = nfull * 8; s < len; ++s) {
        unsigned e = ep[s];
        union { float f; unsigned u; } w; w.u = (e >> 16) << 16;
        const u16* xp = xT + ((size_t)(e & 0xFFFFu) << 11) + b0;
        if (BPL == 8) {
            uint4 xv = *(const uint4*)xp;
            fma2(xv.x, w.f, acc[0], acc[1]); fma2(xv.y, w.f, acc[2], acc[3]);
            fma2(xv.z, w.f, acc[4], acc[5]); fma2(xv.w, w.f, acc[6], acc[7]);
        } else {
            uint2 xv = *(const uint2*)xp;
            fma2(xv.x, w.f, acc[0], acc[1]); fma2(xv.y, w.f, acc[2], acc[3]);
        }
    }

    const float bi = bias[j];
    float c1 = 0.f;
    if (c1a) { c1 = c1a[j]; if (c1b) c1 *= c1b[j]; }
    float c2 = 1.f;
    if (c2a) { c2 = c2a[j]; if (c2b) c2 *= c2b[j]; }

    float v[BPL];
#pragma unroll
    for (int i = 0; i < BPL; i++) v[i] = sigm(acc[i] + bi) * c2;
    if (invT) {
        const unsigned long long* ip = (const unsigned long long*)(invT + ((size_t)j << 11) + b0);
#pragma unroll
        for (int h = 0; h < BPL / 4; h++) {
            unsigned long long iv = __builtin_nontemporal_load(ip + h);
            unsigned lo = (unsigned)iv, hi = (unsigned)(iv >> 32);
            union { float f; unsigned u; } g0, g1, g2, g3;
            g0.u = lo << 16; g1.u = lo & 0xFFFF0000u;
            g2.u = hi << 16; g3.u = hi & 0xFFFF0000u;
            v[4 * h + 0] += g0.f * c1; v[4 * h + 1] += g1.f * c1;
            v[4 * h + 2] += g2.f * c1; v[4 * h + 3] += g3.f * c1;
        }
    }
    unsigned long long* op = (unsigned long long*)(outT + ((size_t)j << 11) + b0);
#pragma unroll
    for (int h = 0; h < BPL / 4; h++) {
        unsigned long long ov = (unsigned long long)pk2(v[4 * h + 0], v[4 * h + 1])
                              | ((unsigned long long)pk2(v[4 * h + 2], v[4 * h + 3]) << 32);
        __builtin_nontemporal_store(ov, op + h);
    }
}

// ---- fused one-hot index extraction: 4 masks, 32 cols each ------------------
__global__ __launch_bounds__(256) void find_all(const float* __restrict__ m0, int n0,
                                                const float* __restrict__ m1, int n1,
                                                const float* __restrict__ m2, int n2,
                                                const float* __restrict__ m3, int n3,
                                                int* __restrict__ out) {
    __shared__ int red[256];
    const int g = blockIdx.x;
    const int which = g >> 5, k = g & 31;
    const float* mask; int n;
    if (which == 0)      { mask = m0; n = n0; }
    else if (which == 1) { mask = m1; n = n1; }
    else if (which == 2) { mask = m2; n = n2; }
    else                 { mask = m3; n = n3; }
    int best = -1;
    for (int i = threadIdx.x; i < n; i += 256)
        if (mask[(size_t)i * 32 + k] != 0.0f) best = i;
    red[threadIdx.x] = best;
    __syncthreads();
    for (int off = 128; off > 0; off >>= 1) {
        if (threadIdx.x < off) {
            int o = red[threadIdx.x + off];
            if (o > red[threadIdx.x]) red[threadIdx.x] = o;
        }
        __syncthreads();
    }
    if (threadIdx.x == 0) out[which * 32 + k] = red[0] < 0 ? 0 : red[0];
}

// ---- gathers into transposed kept arrays [32][2048] ------------------------
__global__ __launch_bounds__(256) void gatherFT(const float* __restrict__ src, int ld,
                                                const int* __restrict__ idx,
                                                u16* __restrict__ dstT) {
    int i = blockIdx.x * 256 + threadIdx.x;  // 65536
    int kk = i >> 11, b = i & 2047;
    dstT[i] = f2bf(src[(size_t)b * ld + idx[kk]]);
}
__global__ __launch_bounds__(256) void gatherT(const u16* __restrict__ xT,
                                               const int* __restrict__ idx,
                                               u16* __restrict__ dstT) {
    int i = blockIdx.x * 256 + threadIdx.x;
    int kk = i >> 11, b = i & 2047;
    dstT[i] = xT[(size_t)idx[kk] * 2048 + b];
}

// ---- xcat assembly (f32 out), kept arrays transposed -----------------------
__global__ __launch_bounds__(256) void build_xcat(float* __restrict__ xcat,
                                                  const u16* __restrict__ x5,
                                                  const u16* __restrict__ kgT,
                                                  const u16* __restrict__ kiT,
                                                  const u16* __restrict__ kcT,
                                                  const u16* __restrict__ kpT,
                                                  const float* __restrict__ clinn) {
    int i = blockIdx.x * 256 + threadIdx.x;
    if (i >= 2048 * 400) return;
    int b = i / 400, c = i - b * 400;
    float v;
    if (c < 256)      v = bf2f(x5[b * 256 + c]);
    else if (c < 288) v = bf2f(kgT[(c - 256) * 2048 + b]);
    else if (c < 320) v = bf2f(kiT[(c - 288) * 2048 + b]);
    else if (c < 352) v = bf2f(kcT[(c - 320) * 2048 + b]);
    else if (c < 384) v = bf2f(kpT[(c - 352) * 2048 + b]);
    else              v = clinn[b * 16 + (c - 384)];
    xcat[i] = v;
}

// ---- dense NT GEMM, used for small L4/L5 only ------------------------------
template <int WR, int WC, int MF, int NF, int KC, int WPE>
__global__ __launch_bounds__(WR * WC * 64, WPE)
void gemm_t(const u16* __restrict__ A, const u16* __restrict__ W,
            u16* __restrict__ Out, const float* __restrict__ bias, int N, int K) {
    constexpr int NTHR = WR * WC * 64;
    constexpr int BM = WR * MF * 16;
    constexpr int BN = WC * NF * 16;
    constexpr int BK = KC * 32;
    constexpr int CPR = KC * 4;
    constexpr int MSK = CPR - 1;
    constexpr int CA = BM * CPR / NTHR;
    constexpr int CB = BN * CPR / NTHR;
    constexpr int L  = CA + CB;

    __shared__ u16 At[2][BM * BK];
    __shared__ u16 Bt[2][BN * BK];

    const int tid = threadIdx.x;
    const int lane = tid & 63;
    const int wave = tid >> 6;
    const int wr = wave / WC, wc = wave % WC;
    const int tn = blockIdx.x, tm = blockIdx.y;
    const int r16 = lane & 15;
    const int q = lane >> 4;

    const u16* aSrc[CA]; int aDst[CA];
#pragma unroll
    for (int j = 0; j < CA; j++) {
        int c = tid + j * NTHR;
        int r = c / CPR, p = c - r * CPR;
        aSrc[j] = A + (size_t)(tm * BM + r) * K + (p ^ (r & MSK)) * 8;
        aDst[j] = c * 8;
    }
    const u16* bSrc[CB]; int bDst[CB];
#pragma unroll
    for (int j = 0; j < CB; j++) {
        int c = tid + j * NTHR;
        int r = c / CPR, p = c - r * CPR;
        bSrc[j] = W + (size_t)(tn * BN + r) * K + (p ^ (r & MSK)) * 8;
        bDst[j] = c * 8;
    }
    int aRd[MF][KC], bRd[NF][KC];
#pragma unroll
    for (int mi = 0; mi < MF; mi++)
#pragma unroll
        for (int kc = 0; kc < KC; kc++)
            aRd[mi][kc] = (wr * MF * 16 + mi * 16 + r16) * BK + (((kc * 4 + q) ^ (r16 & MSK)) << 3);
#pragma unroll
    for (int ni = 0; ni < NF; ni++)
#pragma unroll
        for (int kc = 0; kc < KC; kc++)
            bRd[ni][kc] = (wc * NF * 16 + ni * 16 + r16) * BK + (((kc * 4 + q) ^ (r16 & MSK)) << 3);

    const int nIter = K / BK;

#define ISSUE(slot, it_)                                              \
    do {                                                              \
        const int k0_ = (it_) * BK;                                   \
        _Pragma("unroll")                                             \
        for (int j = 0; j < CA; j++)                                  \
            load16_g2l(aSrc[j] + k0_, &At[slot][aDst[j]]);            \
        _Pragma("unroll")                                             \
        for (int j = 0; j < CB; j++)                                  \
            load16_g2l(bSrc[j] + k0_, &Bt[slot][bDst[j]]);            \
    } while (0)

    ISSUE(0, 0);
    if (nIter > 1) ISSUE(1, 1);

    f32x4 acc[MF][NF];
#pragma unroll
    for (int i = 0; i < MF; i++)
#pragma unroll
        for (int j = 0; j < NF; j++) acc[i][j] = (f32x4){0.f, 0.f, 0.f, 0.f};

    for (int it = 0; it < nIter; ++it) {
        const int s = it & 1;
        if (it + 1 < nIter) __builtin_amdgcn_s_waitcnt(0xF70 | L);
        else                __builtin_amdgcn_s_waitcnt(0xF70);
        __asm__ volatile("" ::: "memory");
        __builtin_amdgcn_s_barrier();
        __asm__ volatile("" ::: "memory");

        s16x8 af[KC][MF], bfr[KC][NF];
#pragma unroll
        for (int kc = 0; kc < KC; kc++) {
#pragma unroll
            for (int mi = 0; mi < MF; mi++) af[kc][mi] = *(const s16x8*)(&At[s][aRd[mi][kc]]);
#pragma unroll
            for (int ni = 0; ni < NF; ni++) bfr[kc][ni] = *(const s16x8*)(&Bt[s][bRd[ni][kc]]);
        }
        __asm__ volatile("" ::: "memory");
        __builtin_amdgcn_s_waitcnt(0xC07F);
        __builtin_amdgcn_s_barrier();
        __asm__ volatile("" ::: "memory");

        if (it + 2 < nIter) ISSUE(s, it + 2);

#pragma unroll
        for (int kc = 0; kc < KC; kc++)
#pragma unroll
            for (int mi = 0; mi < MF; mi++)
#pragma unroll
                for (int ni = 0; ni < NF; ni++)
                    acc[mi][ni] = __builtin_amdgcn_mfma_f32_16x16x32_bf16(af[kc][mi], bfr[kc][ni], acc[mi][ni], 0, 0, 0);
    }
#undef ISSUE

#pragma unroll
    for (int ni = 0; ni < NF; ni++) {
        const int n = tn * BN + wc * NF * 16 + ni * 16 + r16;
        const float bi = bias ? bias[n] : 0.f;
#pragma unroll
        for (int mi = 0; mi < MF; mi++) {
#pragma unroll
            for (int rg = 0; rg < 4; rg++) {
                const int m = tm * BM + wr * MF * 16 + mi * 16 + q * 4 + rg;
                Out[(size_t)m * N + n] = f2bf(sigm(acc[mi][ni][rg] + bi));
            }
        }
    }
}

// ---- tail: lp = sigmoid(xcat @ W6^T); out = (lp - mean(lp,axis=1)) @ W7^T --
__global__ __launch_bounds__(256) void tail_k(const float* __restrict__ xcat,
                                              const float* __restrict__ W6,
                                              const float* __restrict__ W7,
                                              float* __restrict__ out) {
    __shared__ float xs[8 * 400];
    __shared__ float s1[4][8], s2[4][8], s3[4];
    const int tid = threadIdx.x;
    const int b0 = blockIdx.x * 8;
    for (int i = tid; i < 8 * 400; i += 256) {
        int r = i / 400, k = i - r * 400;
        xs[i] = xcat[(size_t)(b0 + r) * 400 + k];
    }
    __syncthreads();
    const int j = tid;
    float acc[8];
#pragma unroll
    for (int r = 0; r < 8; r++) acc[r] = 0.f;
    const float4* wrow = (const float4*)(W6 + (size_t)j * 400);
    for (int c = 0; c < 100; c++) {
        float4 wv = wrow[c];
        const float* wp = (const float*)&wv;
#pragma unroll
        for (int t = 0; t < 4; t++) {
            float w = wp[t];
            int k = c * 4 + t;
#pragma unroll
            for (int r = 0; r < 8; r++) acc[r] += w * xs[r * 400 + k];
        }
    }
    const float w7j = W7[j];
    const int lane = tid & 63, wave = tid >> 6;
    float t3 = w7j;
#pragma unroll
    for (int off = 32; off > 0; off >>= 1) t3 += __shfl_down(t3, off, 64);
    if (lane == 0) s3[wave] = t3;
#pragma unroll
    for (int r = 0; r < 8; r++) {
        float lp = sigm(acc[r]);
        float t1 = lp, t2 = lp * w7j;
#pragma unroll
        for (int off = 32; off > 0; off >>= 1) {
            t1 += __shfl_down(t1, off, 64);
            t2 += __shfl_down(t2, off, 64);
        }
        if (lane == 0) { s1[wave][r] = t1; s2[wave][r] = t2; }
    }
    __syncthreads();
    if (tid < 8) {
        float S1 = s1[0][tid] + s1[1][tid] + s1[2][tid] + s1[3][tid];
        float S2 = s2[0][tid] + s2[1][tid] + s2[2][tid] + s2[3][tid];
        float SW = s3[0] + s3[1] + s3[2] + s3[3];
        out[b0 + tid] = S2 - (S1 * (1.f / 256.f)) * SW;
    }
}

// ---------------------------------------------------------------------------
extern "C" void kernel_launch(void* const* d_in, const int* in_sizes, int n_in,
                              void* d_out, int out_size, void* d_ws, size_t ws_size,
                              hipStream_t stream) {
    const float* x_gene   = (const float*)d_in[0];
    const float* x_invmea = (const float*)d_in[1];
    const float* x_curv   = (const float*)d_in[2];
    const float* clinn    = (const float*)d_in[3];
    const float* Adj      = (const float*)d_in[4];
    const float* edge_m   = (const float*)d_in[5];
    const float* path_m   = (const float*)d_in[6];
    const float* tg_mask  = (const float*)d_in[7];
    const float* ti_mask  = (const float*)d_in[8];
    const float* tc_mask  = (const float*)d_in[9];
    const float* tp_mask  = (const float*)d_in[10];
    const float* W1 = (const float*)d_in[11];  const float* b1 = (const float*)d_in[12];
    const float* W2 = (const float*)d_in[13];  const float* b2 = (const float*)d_in[14];
    const float* W3 = (const float*)d_in[15];  const float* b3 = (const float*)d_in[16];
    const float* W4 = (const float*)d_in[17];  const float* b4 = (const float*)d_in[18];
    const float* W5 = (const float*)d_in[19];  const float* b5 = (const float*)d_in[20];
    const float* W6 = (const float*)d_in[21];
    const float* W7 = (const float*)d_in[22];
    const float* mp11 = (const float*)d_in[23];
    const float* mp12 = (const float*)d_in[24];
    const float* mp1  = (const float*)d_in[25];
    const float* mp21 = (const float*)d_in[26];
    const float* mp22 = (const float*)d_in[27];
    const float* mp2  = (const float*)d_in[28];
    const float* mp3  = (const float*)d_in[29];

    char* ws = (char*)d_ws;
    const float* nulf = nullptr;
    float* out = (float*)d_out;

    u16*  xTg   = (u16*)(ws + 0);            // 16 MiB [4096][2048]
    float* xcat = (float*)(ws + 0);          // 3.2 MiB, aliases dead xTg
    u16*  xinvT = (u16*)(ws + 16777216);     // 16 MiB [4096][2048]
    u16*  xcvT  = (u16*)(ws + 33554432);     // 32 MiB [8192][2048]
    u16*  x1T   = (u16*)(ws + 67108864);     // 16 MiB [4096][2048]
    u16*  x2T   = (u16*)(ws + 83886080);     // 32 MiB [8192][2048]
    u16*  x3T   = (u16*)(ws + 117440512);    //  8 MiB [2048][2048]
    u16*  x3    = (u16*)(ws + 125829120);    //  8 MiB [2048][2048]
    unsigned* ell1 = (unsigned*)(ws + 134217728);  // 4 MiB
    unsigned* ell2 = (unsigned*)(ws + 138412032);  // 3 MiB
    unsigned* ell3 = (unsigned*)(ws + 141557760);  // 2.5 MiB
    int* cnt1 = (int*)(ws + 144179200);
    int* cnt2 = (int*)(ws + 144195584);
    int* cnt3 = (int*)(ws + 144228352);
    int* idxg = (int*)(ws + 144236544);      // 512 B (4 x 32 ints)
    int* idxi = idxg + 32;
    int* idxc = idxg + 64;
    int* idxp = idxg + 96;
    u16* kgT  = (u16*)(ws + 144237056);      // 128 KiB [32][2048]
    u16* kiT  = (u16*)(ws + 144368128);
    u16* kcT  = (u16*)(ws + 144499200);
    u16* kpT  = (u16*)(ws + 144630272);
    u16* w4b  = (u16*)(ws + 144761344);      // 1 MiB
    u16* w5b  = (u16*)(ws + 145809920);      // 128 KiB
    u16* x4   = (u16*)(ws + 145940992);      // 1 MiB
    u16* x5   = (u16*)(ws + 146989568);      // 1 MiB

    // ---- preps ----
    find_all<<<128, 256, 0, stream>>>(tg_mask, 4096, ti_mask, 4096,
                                      tc_mask, 8192, tp_mask, 2048, idxg);
    gatherFT<<<256, 256, 0, stream>>>(x_gene, 4096, idxg, kgT);

    transpF<<<dim3(64, 32), 256, 0, stream>>>(x_gene, xTg, 2048, 4096);
    transpF<<<dim3(64, 32), 256, 0, stream>>>(x_invmea, xinvT, 2048, 4096);
    transpF<<<dim3(128, 32), 256, 0, stream>>>(x_curv, xcvT, 2048, 8192);

    ell_build<<<1024, 256, 0, stream>>>(Adj,    W1, ell1, cnt1, 4096, 256, 4096);
    ell_build<<<2048, 256, 0, stream>>>(edge_m, W2, ell2, cnt2, 4096,  96, 8192);
    ell_build<<<512,  256, 0, stream>>>(path_m, W3, ell3, cnt3, 8192, 320, 2048);

    convF<<<256, 256, 0, stream>>>(W4, w4b, 65536u);
    convF<<<32, 256, 0, stream>>>(W5, w5b, 8192u);

    // ---- L1: x1T = xinvT*(mp11*mp1) + sig(sparse(W1*Adj) @ xTg + b1)*(mp12*mp1)
    spmm<8><<<dim3(4, 1024), 256, 0, stream>>>(ell1, cnt1, xTg, x1T, b1,
                                               mp11, mp1, mp12, mp1, xinvT, 256);
    gatherT<<<256, 256, 0, stream>>>(x1T, idxi, kiT);

    // ---- L2: x2T = xcvT*(mp21*mp2) + sig(sparse(W2*edge) @ x1T + b2)*(mp22*mp2)
    spmm<8><<<dim3(4, 2048), 256, 0, stream>>>(ell2, cnt2, x1T, x2T, b2,
                                               mp21, mp2, mp22, mp2, xcvT, 96);
    gatherT<<<256, 256, 0, stream>>>(x2T, idxc, kcT);

    // ---- L3: x3T = sig(sparse(W3*path) @ x2T + b3) * mp3 (BPL=4: 4MB L2 slice)
    spmm<4><<<dim3(8, 512), 256, 0, stream>>>(ell3, cnt3, x2T, x3T, b3,
                                              nulf, nulf, mp3, nulf, (const u16*)nullptr, 320);
    gatherT<<<256, 256, 0, stream>>>(x3T, idxp, kpT);
    transpB<<<dim3(32, 32), 256, 0, stream>>>(x3T, x3, 2048, 2048);

    // ---- L4/L5 dense, 64x64 tiles (128 blocks each) ----
    gemm_t<2, 2, 2, 2, 2, 4><<<dim3(4, 32), 256, 0, stream>>>(x3, w4b, x4, b4, 256, 2048);
    gemm_t<2, 2, 2, 2, 2, 4><<<dim3(4, 32), 256, 0, stream>>>(x4, w5b, x5, b5, 256, 256);

    build_xcat<<<3200, 256, 0, stream>>>(xcat, x5, kgT, kiT, kcT, kpT, clinn);
    tail_k<<<256, 256, 0, stream>>>(xcat, W6, W7, out);
}

// Round 10
// 940.830 us; speedup vs baseline: 1.2283x; 1.0104x over previous
//
#include <hip/hip_runtime.h>

typedef unsigned short u16;
typedef __attribute__((ext_vector_type(4))) float f32x4;
typedef __attribute__((ext_vector_type(8))) short s16x8;

__device__ __forceinline__ u16 f2bf(float f) {
    union { float f; unsigned u; } c; c.f = f;
    return (u16)((c.u + 0x7fffu + ((c.u >> 16) & 1u)) >> 16);
}
__device__ __forceinline__ float bf2f(u16 u) {
    union { unsigned u; float f; } c; c.u = ((unsigned)u) << 16; return c.f;
}
__device__ __forceinline__ unsigned pk2(float a, float b) {
    return (unsigned)f2bf(a) | ((unsigned)f2bf(b) << 16);
}
__device__ __forceinline__ float sigm(float x) { return 1.0f / (1.0f + __expf(-x)); }
__device__ __forceinline__ void fma2(unsigned xv, float w, float& a0, float& a1) {
    union { float f; unsigned u; } lo, hi;
    lo.u = xv << 16; hi.u = xv & 0xFFFF0000u;
    a0 += w * lo.f; a1 += w * hi.f;
}

// async global->LDS, 16B/lane (dense gemm for L4/L5)
__device__ __forceinline__ void load16_g2l(const void* g, void* l) {
    __builtin_amdgcn_global_load_lds(
        (const __attribute__((address_space(1))) unsigned int*)(unsigned long long)g,
        (__attribute__((address_space(3))) unsigned int*)(unsigned int)(unsigned long long)l,
        16, 0, 0);
}

// ======================= fused prep mega-kernel ==============================
__device__ void d_transpF(const float* __restrict__ in, u16* __restrict__ out,
                          int Rr, int Cc, int bx, int by, float (*t)[65]) {
    const int r0 = by * 64, c0 = bx * 64;
    const int tid = threadIdx.x;
#pragma unroll
    for (int i = 0; i < 16; i++) {
        int idx = tid + i * 256;
        int rr = idx >> 6, cc = idx & 63;
        t[rr][cc] = in[(size_t)(r0 + rr) * Cc + c0 + cc];
    }
    __syncthreads();
#pragma unroll
    for (int i = 0; i < 16; i++) {
        int idx = tid + i * 256;
        int cc = idx >> 6, rr = idx & 63;
        out[(size_t)(c0 + cc) * Rr + r0 + rr] = f2bf(t[rr][cc]);
    }
}

__device__ void d_ell(const float* __restrict__ M, const float* __restrict__ W,
                      unsigned* __restrict__ ell, int* __restrict__ cnt,
                      int C, int PAD, int R, int bid) {
    const int lane = threadIdx.x & 63;
    const int row = bid * 4 + (threadIdx.x >> 6);
    if (row >= R) return;
    const float* mrow = M + (size_t)row * C;
    const float* wrow = W + (size_t)row * C;
    int n = 0;
    for (int c = lane * 4; c < C; c += 256) {
        float4 m = *(const float4*)(mrow + c);
        n += (m.x != 0.f) + (m.y != 0.f) + (m.z != 0.f) + (m.w != 0.f);
    }
    int pre = n;
#pragma unroll
    for (int off = 1; off < 64; off <<= 1) {
        int t = __shfl_up(pre, off, 64);
        if (lane >= off) pre += t;
    }
    int s = pre - n;
    unsigned* erow = ell + (size_t)row * PAD;
    for (int c = lane * 4; c < C; c += 256) {
        float4 m = *(const float4*)(mrow + c);
        if (m.x != 0.f) { if (s < PAD) erow[s] = ((unsigned)f2bf(wrow[c + 0]) << 16) | (unsigned)(c + 0); s++; }
        if (m.y != 0.f) { if (s < PAD) erow[s] = ((unsigned)f2bf(wrow[c + 1]) << 16) | (unsigned)(c + 1); s++; }
        if (m.z != 0.f) { if (s < PAD) erow[s] = ((unsigned)f2bf(wrow[c + 2]) << 16) | (unsigned)(c + 2); s++; }
        if (m.w != 0.f) { if (s < PAD) erow[s] = ((unsigned)f2bf(wrow[c + 3]) << 16) | (unsigned)(c + 3); s++; }
    }
    int tot = __shfl(pre, 63, 64);
    if (lane == 0) cnt[row] = tot > PAD ? PAD : tot;
}

__device__ void d_find(const float* __restrict__ mask, int n, int* __restrict__ outp,
                       int* red) {
    int best = -1;
    for (int i = threadIdx.x; i < n; i += 256)
        if (mask[(size_t)i * 32 + (blockIdx.x & 31)] != 0.0f) best = i;
    red[threadIdx.x] = best;
    __syncthreads();
    for (int off = 128; off > 0; off >>= 1) {
        if (threadIdx.x < off) {
            int o = red[threadIdx.x + off];
            if (o > red[threadIdx.x]) red[threadIdx.x] = o;
        }
        __syncthreads();
    }
    if (threadIdx.x == 0) *outp = red[0] < 0 ? 0 : red[0];
}

__device__ void d_conv(const float* __restrict__ in, u16* __restrict__ out,
                       int bid, unsigned n8) {
    unsigned i = bid * 256u + threadIdx.x;
    if (i >= n8) return;
    float4 a = ((const float4*)in)[2 * i];
    float4 b = ((const float4*)in)[2 * i + 1];
    uint4 o;
    o.x = pk2(a.x, a.y); o.y = pk2(a.z, a.w);
    o.z = pk2(b.x, b.y); o.w = pk2(b.z, b.w);
    ((uint4*)out)[i] = o;
}

// grid = 2048 + 2048 + 4096 + 1024 + 2048 + 512 + 128 + 256 + 32 = 12192
__global__ __launch_bounds__(256) void prep_all(
    const float* __restrict__ xg_f, const float* __restrict__ xinv_f,
    const float* __restrict__ xcv_f,
    u16* __restrict__ xTg, u16* __restrict__ xinvT, u16* __restrict__ xcvT,
    const float* __restrict__ Adj, const float* __restrict__ W1,
    unsigned* __restrict__ ell1, int* __restrict__ cnt1,
    const float* __restrict__ edge, const float* __restrict__ W2,
    unsigned* __restrict__ ell2, int* __restrict__ cnt2,
    const float* __restrict__ path, const float* __restrict__ W3,
    unsigned* __restrict__ ell3, int* __restrict__ cnt3,
    const float* __restrict__ m0, const float* __restrict__ m1,
    const float* __restrict__ m2, const float* __restrict__ m3,
    int* __restrict__ idx,
    const float* __restrict__ W4, u16* __restrict__ w4b,
    const float* __restrict__ W5, u16* __restrict__ w5b) {
    __shared__ float tile[64][65];
    int id = blockIdx.x;
    if (id < 2048) { d_transpF(xg_f, xTg, 2048, 4096, id & 63, id >> 6, tile); return; }
    id -= 2048;
    if (id < 2048) { d_transpF(xinv_f, xinvT, 2048, 4096, id & 63, id >> 6, tile); return; }
    id -= 2048;
    if (id < 4096) { d_transpF(xcv_f, xcvT, 2048, 8192, id & 127, id >> 7, tile); return; }
    id -= 4096;
    if (id < 1024) { d_ell(Adj, W1, ell1, cnt1, 4096, 256, 4096, id); return; }
    id -= 1024;
    if (id < 2048) { d_ell(edge, W2, ell2, cnt2, 4096, 96, 8192, id); return; }
    id -= 2048;
    if (id < 512) { d_ell(path, W3, ell3, cnt3, 8192, 320, 2048, id); return; }
    id -= 512;
    if (id < 128) {
        const float* mk; int n;
        int which = id >> 5;
        if (which == 0)      { mk = m0; n = 4096; }
        else if (which == 1) { mk = m1; n = 4096; }
        else if (which == 2) { mk = m2; n = 8192; }
        else                 { mk = m3; n = 2048; }
        d_find(mk, n, idx + which * 32 + (id & 31), (int*)tile);
        return;
    }
    id -= 128;
    if (id < 256) { d_conv(W4, w4b, id, 65536u); return; }
    id -= 256;
    d_conv(W5, w5b, id, 8192u);
}

// ---- sparse layer v2: wave = row j, lanes = batch slice ---------------------
// BPL=4, grid.x = 8 -> block id % 8 == batch-slice -> XCD-pinned x working set.
template <int BPL>
__global__ __launch_bounds__(256) void spmm(const unsigned* __restrict__ ell,
                                            const int* __restrict__ cnt,
                                            const u16* __restrict__ xT,    // [C][2048]
                                            u16* __restrict__ outT,        // [R][2048]
                                            const float* __restrict__ bias,
                                            const float* __restrict__ c1a,
                                            const float* __restrict__ c1b,
                                            const float* __restrict__ c2a,
                                            const float* __restrict__ c2b,
                                            const u16* __restrict__ invT,
                                            int PAD) {
    const int lane = threadIdx.x & 63;
    const int wv = __builtin_amdgcn_readfirstlane((int)(threadIdx.x >> 6));
    const int j = blockIdx.y * 4 + wv;
    const int b0 = blockIdx.x * (64 * BPL) + lane * BPL;

    const unsigned* ep = ell + (size_t)j * PAD;
    int len = cnt[j];
    if (len > PAD) len = PAD;

    float acc[BPL];
#pragma unroll
    for (int i = 0; i < BPL; i++) acc[i] = 0.f;

    const int nfull = len >> 3;
    unsigned eA[8];
    if (nfull > 0) {
#pragma unroll
        for (int t = 0; t < 8; t++) eA[t] = ep[t];
    }
    for (int g = 0; g < nfull; g++) {
        unsigned eB[8];
        const bool more = (g + 1 < nfull);
        if (more) {
#pragma unroll
            for (int t = 0; t < 8; t++) eB[t] = ep[(g + 1) * 8 + t];
        }
        if (BPL == 8) {
            uint4 xv[8];
#pragma unroll
            for (int t = 0; t < 8; t++)
                xv[t] = *(const uint4*)(xT + ((size_t)(eA[t] & 0xFFFFu) << 11) + b0);
#pragma unroll
            for (int t = 0; t < 8; t++) {
                union { float f; unsigned u; } w; w.u = (eA[t] >> 16) << 16;
                fma2(xv[t].x, w.f, acc[0], acc[1]);
                fma2(xv[t].y, w.f, acc[2], acc[3]);
                fma2(xv[t].z, w.f, acc[4], acc[5]);
                fma2(xv[t].w, w.f, acc[6], acc[7]);
            }
        } else {
            uint2 xv[8];
#pragma unroll
            for (int t = 0; t < 8; t++)
                xv[t] = *(const uint2*)(xT + ((size_t)(eA[t] & 0xFFFFu) << 11) + b0);
#pragma unroll
            for (int t = 0; t < 8; t++) {
                union { float f; unsigned u; } w; w.u = (eA[t] >> 16) << 16;
                fma2(xv[t].x, w.f, acc[0], acc[1]);
                fma2(xv[t].y, w.f, acc[2], acc[3]);
            }
        }
        if (more) {
#pragma unroll
            for (int t = 0; t < 8; t++) eA[t] = eB[t];
        }
    }
    for (int s = nfull * 8; s < len; ++s) {
        unsigned e = ep[s];
        union { float f; unsigned u; } w; w.u = (e >> 16) << 16;
        const u16* xp = xT + ((size_t)(e & 0xFFFFu) << 11) + b0;
        if (BPL == 8) {
            uint4 xv = *(const uint4*)xp;
            fma2(xv.x, w.f, acc[0], acc[1]); fma2(xv.y, w.f, acc[2], acc[3]);
            fma2(xv.z, w.f, acc[4], acc[5]); fma2(xv.w, w.f, acc[6], acc[7]);
        } else {
            uint2 xv = *(const uint2*)xp;
            fma2(xv.x, w.f, acc[0], acc[1]); fma2(xv.y, w.f, acc[2], acc[3]);
        }
    }

    const float bi = bias[j];
    float c1 = 0.f;
    if (c1a) { c1 = c1a[j]; if (c1b) c1 *= c1b[j]; }
    float c2 = 1.f;
    if (c2a) { c2 = c2a[j]; if (c2b) c2 *= c2b[j]; }

    float v[BPL];
#pragma unroll
    for (int i = 0; i < BPL; i++) v[i] = sigm(acc[i] + bi) * c2;
    if (invT) {
        const unsigned long long* ip = (const unsigned long long*)(invT + ((size_t)j << 11) + b0);
#pragma unroll
        for (int h = 0; h < BPL / 4; h++) {
            unsigned long long iv = __builtin_nontemporal_load(ip + h);
            unsigned lo = (unsigned)iv, hi = (unsigned)(iv >> 32);
            union { float f; unsigned u; } g0, g1, g2, g3;
            g0.u = lo << 16; g1.u = lo & 0xFFFF0000u;
            g2.u = hi << 16; g3.u = hi & 0xFFFF0000u;
            v[4 * h + 0] += g0.f * c1; v[4 * h + 1] += g1.f * c1;
            v[4 * h + 2] += g2.f * c1; v[4 * h + 3] += g3.f * c1;
        }
    }
    unsigned long long* op = (unsigned long long*)(outT + ((size_t)j << 11) + b0);
#pragma unroll
    for (int h = 0; h < BPL / 4; h++) {
        unsigned long long ov = (unsigned long long)pk2(v[4 * h + 0], v[4 * h + 1])
                              | ((unsigned long long)pk2(v[4 * h + 2], v[4 * h + 3]) << 32);
        __builtin_nontemporal_store(ov, op + h);
    }
}

// ---- gathers into transposed kept arrays [32][2048] ------------------------
__global__ __launch_bounds__(256) void gatherFT(const float* __restrict__ src, int ld,
                                                const int* __restrict__ idx,
                                                u16* __restrict__ dstT) {
    int i = blockIdx.x * 256 + threadIdx.x;  // 65536
    int kk = i >> 11, b = i & 2047;
    dstT[i] = f2bf(src[(size_t)b * ld + idx[kk]]);
}
__global__ __launch_bounds__(256) void gatherT(const u16* __restrict__ xT,
                                               const int* __restrict__ idx,
                                               u16* __restrict__ dstT) {
    int i = blockIdx.x * 256 + threadIdx.x;
    int kk = i >> 11, b = i & 2047;
    dstT[i] = xT[(size_t)idx[kk] * 2048 + b];
}

// ---- bf16 [Rr][Cc] -> bf16 transposed [Cc][Rr] -----------------------------
__global__ __launch_bounds__(256) void transpB(const u16* __restrict__ in,
                                               u16* __restrict__ out, int Rr, int Cc) {
    __shared__ u16 t[64][66];
    const int r0 = blockIdx.y * 64, c0 = blockIdx.x * 64;
    const int tid = threadIdx.x;
#pragma unroll
    for (int i = 0; i < 16; i++) {
        int idx = tid + i * 256;
        int rr = idx >> 6, cc = idx & 63;
        t[rr][cc] = in[(size_t)(r0 + rr) * Cc + c0 + cc];
    }
    __syncthreads();
#pragma unroll
    for (int i = 0; i < 16; i++) {
        int idx = tid + i * 256;
        int cc = idx >> 6, rr = idx & 63;
        out[(size_t)(c0 + cc) * Rr + r0 + rr] = t[rr][cc];
    }
}

// ---- dense NT GEMM, used for small L4/L5 only ------------------------------
template <int WR, int WC, int MF, int NF, int KC, int WPE>
__global__ __launch_bounds__(WR * WC * 64, WPE)
void gemm_t(const u16* __restrict__ A, const u16* __restrict__ W,
            u16* __restrict__ Out, const float* __restrict__ bias, int N, int K) {
    constexpr int NTHR = WR * WC * 64;
    constexpr int BM = WR * MF * 16;
    constexpr int BN = WC * NF * 16;
    constexpr int BK = KC * 32;
    constexpr int CPR = KC * 4;
    constexpr int MSK = CPR - 1;
    constexpr int CA = BM * CPR / NTHR;
    constexpr int CB = BN * CPR / NTHR;
    constexpr int L  = CA + CB;

    __shared__ u16 At[2][BM * BK];
    __shared__ u16 Bt[2][BN * BK];

    const int tid = threadIdx.x;
    const int lane = tid & 63;
    const int wave = tid >> 6;
    const int wr = wave / WC, wc = wave % WC;
    const int tn = blockIdx.x, tm = blockIdx.y;
    const int r16 = lane & 15;
    const int q = lane >> 4;

    const u16* aSrc[CA]; int aDst[CA];
#pragma unroll
    for (int j = 0; j < CA; j++) {
        int c = tid + j * NTHR;
        int r = c / CPR, p = c - r * CPR;
        aSrc[j] = A + (size_t)(tm * BM + r) * K + (p ^ (r & MSK)) * 8;
        aDst[j] = c * 8;
    }
    const u16* bSrc[CB]; int bDst[CB];
#pragma unroll
    for (int j = 0; j < CB; j++) {
        int c = tid + j * NTHR;
        int r = c / CPR, p = c - r * CPR;
        bSrc[j] = W + (size_t)(tn * BN + r) * K + (p ^ (r & MSK)) * 8;
        bDst[j] = c * 8;
    }
    int aRd[MF][KC], bRd[NF][KC];
#pragma unroll
    for (int mi = 0; mi < MF; mi++)
#pragma unroll
        for (int kc = 0; kc < KC; kc++)
            aRd[mi][kc] = (wr * MF * 16 + mi * 16 + r16) * BK + (((kc * 4 + q) ^ (r16 & MSK)) << 3);
#pragma unroll
    for (int ni = 0; ni < NF; ni++)
#pragma unroll
        for (int kc = 0; kc < KC; kc++)
            bRd[ni][kc] = (wc * NF * 16 + ni * 16 + r16) * BK + (((kc * 4 + q) ^ (r16 & MSK)) << 3);

    const int nIter = K / BK;

#define ISSUE(slot, it_)                                              \
    do {                                                              \
        const int k0_ = (it_) * BK;                                   \
        _Pragma("unroll")                                             \
        for (int j = 0; j < CA; j++)                                  \
            load16_g2l(aSrc[j] + k0_, &At[slot][aDst[j]]);            \
        _Pragma("unroll")                                             \
        for (int j = 0; j < CB; j++)                                  \
            load16_g2l(bSrc[j] + k0_, &Bt[slot][bDst[j]]);            \
    } while (0)

    ISSUE(0, 0);
    if (nIter > 1) ISSUE(1, 1);

    f32x4 acc[MF][NF];
#pragma unroll
    for (int i = 0; i < MF; i++)
#pragma unroll
        for (int j = 0; j < NF; j++) acc[i][j] = (f32x4){0.f, 0.f, 0.f, 0.f};

    for (int it = 0; it < nIter; ++it) {
        const int s = it & 1;
        if (it + 1 < nIter) __builtin_amdgcn_s_waitcnt(0xF70 | L);
        else                __builtin_amdgcn_s_waitcnt(0xF70);
        __asm__ volatile("" ::: "memory");
        __builtin_amdgcn_s_barrier();
        __asm__ volatile("" ::: "memory");

        s16x8 af[KC][MF], bfr[KC][NF];
#pragma unroll
        for (int kc = 0; kc < KC; kc++) {
#pragma unroll
            for (int mi = 0; mi < MF; mi++) af[kc][mi] = *(const s16x8*)(&At[s][aRd[mi][kc]]);
#pragma unroll
            for (int ni = 0; ni < NF; ni++) bfr[kc][ni] = *(const s16x8*)(&Bt[s][bRd[ni][kc]]);
        }
        __asm__ volatile("" ::: "memory");
        __builtin_amdgcn_s_waitcnt(0xC07F);
        __builtin_amdgcn_s_barrier();
        __asm__ volatile("" ::: "memory");

        if (it + 2 < nIter) ISSUE(s, it + 2);

#pragma unroll
        for (int kc = 0; kc < KC; kc++)
#pragma unroll
            for (int mi = 0; mi < MF; mi++)
#pragma unroll
                for (int ni = 0; ni < NF; ni++)
                    acc[mi][ni] = __builtin_amdgcn_mfma_f32_16x16x32_bf16(af[kc][mi], bfr[kc][ni], acc[mi][ni], 0, 0, 0);
    }
#undef ISSUE

#pragma unroll
    for (int ni = 0; ni < NF; ni++) {
        const int n = tn * BN + wc * NF * 16 + ni * 16 + r16;
        const float bi = bias ? bias[n] : 0.f;
#pragma unroll
        for (int mi = 0; mi < MF; mi++) {
#pragma unroll
            for (int rg = 0; rg < 4; rg++) {
                const int m = tm * BM + wr * MF * 16 + mi * 16 + q * 4 + rg;
                Out[(size_t)m * N + n] = f2bf(sigm(acc[mi][ni][rg] + bi));
            }
        }
    }
}

// ---- tail (fused xcat): lp = sig(xcat @ W6^T); out = (lp - mean) @ W7^T ----
__global__ __launch_bounds__(256) void tail_k(const u16* __restrict__ x5,
                                              const u16* __restrict__ kgT,
                                              const u16* __restrict__ kiT,
                                              const u16* __restrict__ kcT,
                                              const u16* __restrict__ kpT,
                                              const float* __restrict__ clinn,
                                              const float* __restrict__ W6,
                                              const float* __restrict__ W7,
                                              float* __restrict__ out) {
    __shared__ float xs[8 * 400];
    __shared__ float s1[4][8], s2[4][8], s3[4];
    const int tid = threadIdx.x;
    const int b0 = blockIdx.x * 8;
    for (int i = tid; i < 8 * 400; i += 256) {
        int r = i / 400, c = i - r * 400;
        int b = b0 + r;
        float v;
        if (c < 256)      v = bf2f(x5[b * 256 + c]);
        else if (c < 288) v = bf2f(kgT[(c - 256) * 2048 + b]);
        else if (c < 320) v = bf2f(kiT[(c - 288) * 2048 + b]);
        else if (c < 352) v = bf2f(kcT[(c - 320) * 2048 + b]);
        else if (c < 384) v = bf2f(kpT[(c - 352) * 2048 + b]);
        else              v = clinn[b * 16 + (c - 384)];
        xs[i] = v;
    }
    __syncthreads();
    const int j = tid;
    float acc[8];
#pragma unroll
    for (int r = 0; r < 8; r++) acc[r] = 0.f;
    const float4* wrow = (const float4*)(W6 + (size_t)j * 400);
    for (int c = 0; c < 100; c++) {
        float4 wv = wrow[c];
        const float* wp = (const float*)&wv;
#pragma unroll
        for (int t = 0; t < 4; t++) {
            float w = wp[t];
            int k = c * 4 + t;
#pragma unroll
            for (int r = 0; r < 8; r++) acc[r] += w * xs[r * 400 + k];
        }
    }
    const float w7j = W7[j];
    const int lane = tid & 63, wave = tid >> 6;
    float t3 = w7j;
#pragma unroll
    for (int off = 32; off > 0; off >>= 1) t3 += __shfl_down(t3, off, 64);
    if (lane == 0) s3[wave] = t3;
#pragma unroll
    for (int r = 0; r < 8; r++) {
        float lp = sigm(acc[r]);
        float t1 = lp, t2 = lp * w7j;
#pragma unroll
        for (int off = 32; off > 0; off >>= 1) {
            t1 += __shfl_down(t1, off, 64);
            t2 += __shfl_down(t2, off, 64);
        }
        if (lane == 0) { s1[wave][r] = t1; s2[wave][r] = t2; }
    }
    __syncthreads();
    if (tid < 8) {
        float S1 = s1[0][tid] + s1[1][tid] + s1[2][tid] + s1[3][tid];
        float S2 = s2[0][tid] + s2[1][tid] + s2[2][tid] + s2[3][tid];
        float SW = s3[0] + s3[1] + s3[2] + s3[3];
        out[b0 + tid] = S2 - (S1 * (1.f / 256.f)) * SW;
    }
}

// ---------------------------------------------------------------------------
extern "C" void kernel_launch(void* const* d_in, const int* in_sizes, int n_in,
                              void* d_out, int out_size, void* d_ws, size_t ws_size,
                              hipStream_t stream) {
    const float* x_gene   = (const float*)d_in[0];
    const float* x_invmea = (const float*)d_in[1];
    const float* x_curv   = (const float*)d_in[2];
    const float* clinn    = (const float*)d_in[3];
    const float* Adj      = (const float*)d_in[4];
    const float* edge_m   = (const float*)d_in[5];
    const float* path_m   = (const float*)d_in[6];
    const float* tg_mask  = (const float*)d_in[7];
    const float* ti_mask  = (const float*)d_in[8];
    const float* tc_mask  = (const float*)d_in[9];
    const float* tp_mask  = (const float*)d_in[10];
    const float* W1 = (const float*)d_in[11];  const float* b1 = (const float*)d_in[12];
    const float* W2 = (const float*)d_in[13];  const float* b2 = (const float*)d_in[14];
    const float* W3 = (const float*)d_in[15];  const float* b3 = (const float*)d_in[16];
    const float* W4 = (const float*)d_in[17];  const float* b4 = (const float*)d_in[18];
    const float* W5 = (const float*)d_in[19];  const float* b5 = (const float*)d_in[20];
    const float* W6 = (const float*)d_in[21];
    const float* W7 = (const float*)d_in[22];
    const float* mp11 = (const float*)d_in[23];
    const float* mp12 = (const float*)d_in[24];
    const float* mp1  = (const float*)d_in[25];
    const float* mp21 = (const float*)d_in[26];
    const float* mp22 = (const float*)d_in[27];
    const float* mp2  = (const float*)d_in[28];
    const float* mp3  = (const float*)d_in[29];

    char* ws = (char*)d_ws;
    const float* nulf = nullptr;
    float* out = (float*)d_out;

    u16*  xTg   = (u16*)(ws + 0);            // 16 MiB [4096][2048]
    u16*  xinvT = (u16*)(ws + 16777216);     // 16 MiB
    u16*  xcvT  = (u16*)(ws + 33554432);     // 32 MiB
    u16*  x1T   = (u16*)(ws + 67108864);     // 16 MiB
    u16*  x2T   = (u16*)(ws + 83886080);     // 32 MiB
    u16*  x3T   = (u16*)(ws + 117440512);    //  8 MiB
    u16*  x3    = (u16*)(ws + 125829120);    //  8 MiB
    unsigned* ell1 = (unsigned*)(ws + 134217728);  // 4 MiB
    unsigned* ell2 = (unsigned*)(ws + 138412032);  // 3 MiB
    unsigned* ell3 = (unsigned*)(ws + 141557760);  // 2.5 MiB
    int* cnt1 = (int*)(ws + 144179200);
    int* cnt2 = (int*)(ws + 144195584);
    int* cnt3 = (int*)(ws + 144228352);
    int* idxg = (int*)(ws + 144236544);      // 512 B (4 x 32 ints)
    int* idxi = idxg + 32;
    int* idxc = idxg + 64;
    int* idxp = idxg + 96;
    u16* kgT  = (u16*)(ws + 144237056);      // 128 KiB [32][2048]
    u16* kiT  = (u16*)(ws + 144368128);
    u16* kcT  = (u16*)(ws + 144499200);
    u16* kpT  = (u16*)(ws + 144630272);
    u16* w4b  = (u16*)(ws + 144761344);      // 1 MiB
    u16* w5b  = (u16*)(ws + 145809920);      // 128 KiB
    u16* x4   = (u16*)(ws + 145940992);      // 1 MiB
    u16* x5   = (u16*)(ws + 146989568);      // 1 MiB

    // ---- fused prep: transposes + ELL builds + find_idx + W4/W5 conv -------
    prep_all<<<12192, 256, 0, stream>>>(
        x_gene, x_invmea, x_curv, xTg, xinvT, xcvT,
        Adj, W1, ell1, cnt1, edge_m, W2, ell2, cnt2, path_m, W3, ell3, cnt3,
        tg_mask, ti_mask, tc_mask, tp_mask, idxg, W4, w4b, W5, w5b);
    gatherFT<<<256, 256, 0, stream>>>(x_gene, 4096, idxg, kgT);

    // ---- L1 ----
    spmm<4><<<dim3(8, 1024), 256, 0, stream>>>(ell1, cnt1, xTg, x1T, b1,
                                               mp11, mp1, mp12, mp1, xinvT, 256);
    gatherT<<<256, 256, 0, stream>>>(x1T, idxi, kiT);

    // ---- L2 ----
    spmm<4><<<dim3(8, 2048), 256, 0, stream>>>(ell2, cnt2, x1T, x2T, b2,
                                               mp21, mp2, mp22, mp2, xcvT, 96);
    gatherT<<<256, 256, 0, stream>>>(x2T, idxc, kcT);

    // ---- L3 ----
    spmm<4><<<dim3(8, 512), 256, 0, stream>>>(ell3, cnt3, x2T, x3T, b3,
                                              nulf, nulf, mp3, nulf, (const u16*)nullptr, 320);
    gatherT<<<256, 256, 0, stream>>>(x3T, idxp, kpT);
    transpB<<<dim3(32, 32), 256, 0, stream>>>(x3T, x3, 2048, 2048);

    // ---- L4/L5 dense ----
    gemm_t<2, 2, 2, 2, 2, 4><<<dim3(4, 32), 256, 0, stream>>>(x3, w4b, x4, b4, 256, 2048);
    gemm_t<2, 2, 2, 2, 2, 4><<<dim3(4, 32), 256, 0, stream>>>(x4, w5b, x5, b5, 256, 256);

    // ---- fused xcat + tail ----
    tail_k<<<256, 256, 0, stream>>>(x5, kgT, kiT, kcT, kpT, clinn, W6, W7, out);
}

// Round 11
// 911.059 us; speedup vs baseline: 1.2685x; 1.0327x over previous
//
#include <hip/hip_runtime.h>

typedef unsigned short u16;
typedef __attribute__((ext_vector_type(4))) float f32x4;
typedef __attribute__((ext_vector_type(8))) short s16x8;

__device__ __forceinline__ u16 f2bf(float f) {
    union { float f; unsigned u; } c; c.f = f;
    return (u16)((c.u + 0x7fffu + ((c.u >> 16) & 1u)) >> 16);
}
__device__ __forceinline__ float bf2f(u16 u) {
    union { unsigned u; float f; } c; c.u = ((unsigned)u) << 16; return c.f;
}
__device__ __forceinline__ unsigned pk2(float a, float b) {
    return (unsigned)f2bf(a) | ((unsigned)f2bf(b) << 16);
}
__device__ __forceinline__ float sigm(float x) { return 1.0f / (1.0f + __expf(-x)); }
__device__ __forceinline__ void fma2(unsigned xv, float w, float& a0, float& a1) {
    union { float f; unsigned u; } lo, hi;
    lo.u = xv << 16; hi.u = xv & 0xFFFF0000u;
    a0 += w * lo.f; a1 += w * hi.f;
}

// async global->LDS, 16B/lane (dense gemm for L4/L5)
__device__ __forceinline__ void load16_g2l(const void* g, void* l) {
    __builtin_amdgcn_global_load_lds(
        (const __attribute__((address_space(1))) unsigned int*)(unsigned long long)g,
        (__attribute__((address_space(3))) unsigned int*)(unsigned int)(unsigned long long)l,
        16, 0, 0);
}

// ======================= prep_misc: transposes + find + conv =================
__device__ void d_transpF(const float* __restrict__ in, u16* __restrict__ out,
                          int Rr, int Cc, int bx, int by, float (*t)[65]) {
    const int r0 = by * 64, c0 = bx * 64;
    const int tid = threadIdx.x;
#pragma unroll
    for (int i = 0; i < 16; i++) {
        int idx = tid + i * 256;
        int rr = idx >> 6, cc = idx & 63;
        t[rr][cc] = in[(size_t)(r0 + rr) * Cc + c0 + cc];
    }
    __syncthreads();
#pragma unroll
    for (int i = 0; i < 16; i++) {
        int idx = tid + i * 256;
        int cc = idx >> 6, rr = idx & 63;
        out[(size_t)(c0 + cc) * Rr + r0 + rr] = f2bf(t[rr][cc]);
    }
}

__device__ void d_find(const float* __restrict__ mask, int n, int* __restrict__ outp,
                       int* red, int k) {
    int best = -1;
    for (int i = threadIdx.x; i < n; i += 256)
        if (mask[(size_t)i * 32 + k] != 0.0f) best = i;
    red[threadIdx.x] = best;
    __syncthreads();
    for (int off = 128; off > 0; off >>= 1) {
        if (threadIdx.x < off) {
            int o = red[threadIdx.x + off];
            if (o > red[threadIdx.x]) red[threadIdx.x] = o;
        }
        __syncthreads();
    }
    if (threadIdx.x == 0) *outp = red[0] < 0 ? 0 : red[0];
}

__device__ void d_conv(const float* __restrict__ in, u16* __restrict__ out,
                       int bid, unsigned n8) {
    unsigned i = bid * 256u + threadIdx.x;
    if (i >= n8) return;
    float4 a = ((const float4*)in)[2 * i];
    float4 b = ((const float4*)in)[2 * i + 1];
    uint4 o;
    o.x = pk2(a.x, a.y); o.y = pk2(a.z, a.w);
    o.z = pk2(b.x, b.y); o.w = pk2(b.z, b.w);
    ((uint4*)out)[i] = o;
}

// grid = 2048 + 2048 + 4096 + 128 + 256 + 32 = 8608
__global__ __launch_bounds__(256) void prep_misc(
    const float* __restrict__ xg_f, const float* __restrict__ xinv_f,
    const float* __restrict__ xcv_f,
    u16* __restrict__ xTg, u16* __restrict__ xinvT, u16* __restrict__ xcvT,
    const float* __restrict__ m0, const float* __restrict__ m1,
    const float* __restrict__ m2, const float* __restrict__ m3,
    int* __restrict__ idx,
    const float* __restrict__ W4, u16* __restrict__ w4b,
    const float* __restrict__ W5, u16* __restrict__ w5b) {
    __shared__ float tile[64][65];
    int id = blockIdx.x;
    if (id < 2048) { d_transpF(xg_f, xTg, 2048, 4096, id & 63, id >> 6, tile); return; }
    id -= 2048;
    if (id < 2048) { d_transpF(xinv_f, xinvT, 2048, 4096, id & 63, id >> 6, tile); return; }
    id -= 2048;
    if (id < 4096) { d_transpF(xcv_f, xcvT, 2048, 8192, id & 127, id >> 7, tile); return; }
    id -= 4096;
    if (id < 128) {
        const float* mk; int n;
        int which = id >> 5;
        if (which == 0)      { mk = m0; n = 4096; }
        else if (which == 1) { mk = m1; n = 4096; }
        else if (which == 2) { mk = m2; n = 8192; }
        else                 { mk = m3; n = 2048; }
        d_find(mk, n, idx + which * 32 + (id & 31), (int*)tile, id & 31);
        return;
    }
    id -= 128;
    if (id < 256) { d_conv(W4, w4b, id, 65536u); return; }
    id -= 256;
    d_conv(W5, w5b, id, 8192u);
}

// ======================= prep_ell: register-resident ELL build ===============
// HALVES * 4096 = C. Mask row half (16 KB) loaded as 16 unrolled float4/lane
// -> 16 loads in flight -> full MLP. Single pass: write uses registers.
template <int HALVES>
__device__ void d_ell_reg(const float* __restrict__ M, const float* __restrict__ W,
                          unsigned* __restrict__ ell, int* __restrict__ cnt,
                          int PAD, int R, int bid) {
    const int lane = threadIdx.x & 63;
    const int row = bid * 4 + (threadIdx.x >> 6);
    if (row >= R) return;
    const float4* mrow = (const float4*)(M + (size_t)row * (HALVES * 4096));
    const float* wrow = W + (size_t)row * (HALVES * 4096);
    unsigned* erow = ell + (size_t)row * PAD;
    int base = 0;
#pragma unroll
    for (int h = 0; h < HALVES; h++) {
        float4 m[16];
#pragma unroll
        for (int i = 0; i < 16; i++) m[i] = mrow[h * 1024 + lane + i * 64];
        int n = 0;
#pragma unroll
        for (int i = 0; i < 16; i++)
            n += (m[i].x != 0.f) + (m[i].y != 0.f) + (m[i].z != 0.f) + (m[i].w != 0.f);
        int pre = n;
#pragma unroll
        for (int off = 1; off < 64; off <<= 1) {
            int t = __shfl_up(pre, off, 64);
            if (lane >= off) pre += t;
        }
        int s = base + pre - n;
#pragma unroll
        for (int i = 0; i < 16; i++) {
            int c = h * 4096 + lane * 4 + i * 256;
            if (m[i].x != 0.f) { if (s < PAD) erow[s] = ((unsigned)f2bf(wrow[c + 0]) << 16) | (unsigned)(c + 0); s++; }
            if (m[i].y != 0.f) { if (s < PAD) erow[s] = ((unsigned)f2bf(wrow[c + 1]) << 16) | (unsigned)(c + 1); s++; }
            if (m[i].z != 0.f) { if (s < PAD) erow[s] = ((unsigned)f2bf(wrow[c + 2]) << 16) | (unsigned)(c + 2); s++; }
            if (m[i].w != 0.f) { if (s < PAD) erow[s] = ((unsigned)f2bf(wrow[c + 3]) << 16) | (unsigned)(c + 3); s++; }
        }
        base += __shfl(pre, 63, 64);
    }
    if (lane == 0) cnt[row] = base > PAD ? PAD : base;
}

// grid = 1024 + 2048 + 512 = 3584
__global__ __launch_bounds__(256) void prep_ell(
    const float* __restrict__ Adj, const float* __restrict__ W1,
    unsigned* __restrict__ ell1, int* __restrict__ cnt1,
    const float* __restrict__ edge, const float* __restrict__ W2,
    unsigned* __restrict__ ell2, int* __restrict__ cnt2,
    const float* __restrict__ path, const float* __restrict__ W3,
    unsigned* __restrict__ ell3, int* __restrict__ cnt3) {
    int id = blockIdx.x;
    if (id < 1024) { d_ell_reg<1>(Adj, W1, ell1, cnt1, 256, 4096, id); return; }
    id -= 1024;
    if (id < 2048) { d_ell_reg<1>(edge, W2, ell2, cnt2, 96, 8192, id); return; }
    id -= 2048;
    d_ell_reg<2>(path, W3, ell3, cnt3, 320, 2048, id);
}

// ---- sparse layer: wave = row j, lanes = batch slice -----------------------
// BPL=4, grid.x = 8 -> block id % 8 == batch-slice -> XCD-pinned x working set.
// Fused one-hot gather: if j is in gidx, mirror the packed store into gdst.
template <int BPL>
__global__ __launch_bounds__(256) void spmm(const unsigned* __restrict__ ell,
                                            const int* __restrict__ cnt,
                                            const u16* __restrict__ xT,    // [C][2048]
                                            u16* __restrict__ outT,        // [R][2048]
                                            const float* __restrict__ bias,
                                            const float* __restrict__ c1a,
                                            const float* __restrict__ c1b,
                                            const float* __restrict__ c2a,
                                            const float* __restrict__ c2b,
                                            const u16* __restrict__ invT,
                                            const int* __restrict__ gidx,
                                            u16* __restrict__ gdst,
                                            int PAD) {
    const int lane = threadIdx.x & 63;
    const int wv = __builtin_amdgcn_readfirstlane((int)(threadIdx.x >> 6));
    const int j = blockIdx.y * 4 + wv;
    const int b0 = blockIdx.x * (64 * BPL) + lane * BPL;

    const unsigned* ep = ell + (size_t)j * PAD;
    int len = cnt[j];
    if (len > PAD) len = PAD;

    float acc[BPL];
#pragma unroll
    for (int i = 0; i < BPL; i++) acc[i] = 0.f;

    const int nfull = len >> 3;
    unsigned eA[8];
    if (nfull > 0) {
#pragma unroll
        for (int t = 0; t < 8; t++) eA[t] = ep[t];
    }
    for (int g = 0; g < nfull; g++) {
        unsigned eB[8];
        const bool more = (g + 1 < nfull);
        if (more) {
#pragma unroll
            for (int t = 0; t < 8; t++) eB[t] = ep[(g + 1) * 8 + t];
        }
        if (BPL == 8) {
            uint4 xv[8];
#pragma unroll
            for (int t = 0; t < 8; t++)
                xv[t] = *(const uint4*)(xT + ((size_t)(eA[t] & 0xFFFFu) << 11) + b0);
#pragma unroll
            for (int t = 0; t < 8; t++) {
                union { float f; unsigned u; } w; w.u = (eA[t] >> 16) << 16;
                fma2(xv[t].x, w.f, acc[0], acc[1]);
                fma2(xv[t].y, w.f, acc[2], acc[3]);
                fma2(xv[t].z, w.f, acc[4], acc[5]);
                fma2(xv[t].w, w.f, acc[6], acc[7]);
            }
        } else {
            uint2 xv[8];
#pragma unroll
            for (int t = 0; t < 8; t++)
                xv[t] = *(const uint2*)(xT + ((size_t)(eA[t] & 0xFFFFu) << 11) + b0);
#pragma unroll
            for (int t = 0; t < 8; t++) {
                union { float f; unsigned u; } w; w.u = (eA[t] >> 16) << 16;
                fma2(xv[t].x, w.f, acc[0], acc[1]);
                fma2(xv[t].y, w.f, acc[2], acc[3]);
            }
        }
        if (more) {
#pragma unroll
            for (int t = 0; t < 8; t++) eA[t] = eB[t];
        }
    }
    for (int s = nfull * 8; s < len; ++s) {
        unsigned e = ep[s];
        union { float f; unsigned u; } w; w.u = (e >> 16) << 16;
        const u16* xp = xT + ((size_t)(e & 0xFFFFu) << 11) + b0;
        if (BPL == 8) {
            uint4 xv = *(const uint4*)xp;
            fma2(xv.x, w.f, acc[0], acc[1]); fma2(xv.y, w.f, acc[2], acc[3]);
            fma2(xv.z, w.f, acc[4], acc[5]); fma2(xv.w, w.f, acc[6], acc[7]);
        } else {
            uint2 xv = *(const uint2*)xp;
            fma2(xv.x, w.f, acc[0], acc[1]); fma2(xv.y, w.f, acc[2], acc[3]);
        }
    }

    const float bi = bias[j];
    float c1 = 0.f;
    if (c1a) { c1 = c1a[j]; if (c1b) c1 *= c1b[j]; }
    float c2 = 1.f;
    if (c2a) { c2 = c2a[j]; if (c2b) c2 *= c2b[j]; }

    float v[BPL];
#pragma unroll
    for (int i = 0; i < BPL; i++) v[i] = sigm(acc[i] + bi) * c2;
    if (invT) {
        const unsigned long long* ip = (const unsigned long long*)(invT + ((size_t)j << 11) + b0);
#pragma unroll
        for (int h = 0; h < BPL / 4; h++) {
            unsigned long long iv = __builtin_nontemporal_load(ip + h);
            unsigned lo = (unsigned)iv, hi = (unsigned)(iv >> 32);
            union { float f; unsigned u; } g0, g1, g2, g3;
            g0.u = lo << 16; g1.u = lo & 0xFFFF0000u;
            g2.u = hi << 16; g3.u = hi & 0xFFFF0000u;
            v[4 * h + 0] += g0.f * c1; v[4 * h + 1] += g1.f * c1;
            v[4 * h + 2] += g2.f * c1; v[4 * h + 3] += g3.f * c1;
        }
    }
    unsigned long long pkv[BPL / 4];
#pragma unroll
    for (int h = 0; h < BPL / 4; h++)
        pkv[h] = (unsigned long long)pk2(v[4 * h + 0], v[4 * h + 1])
               | ((unsigned long long)pk2(v[4 * h + 2], v[4 * h + 3]) << 32);
    unsigned long long* op = (unsigned long long*)(outT + ((size_t)j << 11) + b0);
#pragma unroll
    for (int h = 0; h < BPL / 4; h++) __builtin_nontemporal_store(pkv[h], op + h);

    // fused one-hot column gather (wave-uniform scalar compares)
    if (gdst) {
        for (int t = 0; t < 32; t++) {
            if (gidx[t] == j) {
                unsigned long long* gp = (unsigned long long*)(gdst + t * 2048 + b0);
#pragma unroll
                for (int h = 0; h < BPL / 4; h++) gp[h] = pkv[h];
            }
        }
    }
}

// ---- gather into transposed kept array [32][2048] from f32 source ----------
__global__ __launch_bounds__(256) void gatherFT(const float* __restrict__ src, int ld,
                                                const int* __restrict__ idx,
                                                u16* __restrict__ dstT) {
    int i = blockIdx.x * 256 + threadIdx.x;  // 65536
    int kk = i >> 11, b = i & 2047;
    dstT[i] = f2bf(src[(size_t)b * ld + idx[kk]]);
}

// ---- bf16 [Rr][Cc] -> bf16 transposed [Cc][Rr] -----------------------------
__global__ __launch_bounds__(256) void transpB(const u16* __restrict__ in,
                                               u16* __restrict__ out, int Rr, int Cc) {
    __shared__ u16 t[64][66];
    const int r0 = blockIdx.y * 64, c0 = blockIdx.x * 64;
    const int tid = threadIdx.x;
#pragma unroll
    for (int i = 0; i < 16; i++) {
        int idx = tid + i * 256;
        int rr = idx >> 6, cc = idx & 63;
        t[rr][cc] = in[(size_t)(r0 + rr) * Cc + c0 + cc];
    }
    __syncthreads();
#pragma unroll
    for (int i = 0; i < 16; i++) {
        int idx = tid + i * 256;
        int cc = idx >> 6, rr = idx & 63;
        out[(size_t)(c0 + cc) * Rr + r0 + rr] = t[rr][cc];
    }
}

// ---- dense NT GEMM, used for small L4/L5 only ------------------------------
template <int WR, int WC, int MF, int NF, int KC, int WPE>
__global__ __launch_bounds__(WR * WC * 64, WPE)
void gemm_t(const u16* __restrict__ A, const u16* __restrict__ W,
            u16* __restrict__ Out, const float* __restrict__ bias, int N, int K) {
    constexpr int NTHR = WR * WC * 64;
    constexpr int BM = WR * MF * 16;
    constexpr int BN = WC * NF * 16;
    constexpr int BK = KC * 32;
    constexpr int CPR = KC * 4;
    constexpr int MSK = CPR - 1;
    constexpr int CA = BM * CPR / NTHR;
    constexpr int CB = BN * CPR / NTHR;
    constexpr int L  = CA + CB;

    __shared__ u16 At[2][BM * BK];
    __shared__ u16 Bt[2][BN * BK];

    const int tid = threadIdx.x;
    const int lane = tid & 63;
    const int wave = tid >> 6;
    const int wr = wave / WC, wc = wave % WC;
    const int tn = blockIdx.x, tm = blockIdx.y;
    const int r16 = lane & 15;
    const int q = lane >> 4;

    const u16* aSrc[CA]; int aDst[CA];
#pragma unroll
    for (int j = 0; j < CA; j++) {
        int c = tid + j * NTHR;
        int r = c / CPR, p = c - r * CPR;
        aSrc[j] = A + (size_t)(tm * BM + r) * K + (p ^ (r & MSK)) * 8;
        aDst[j] = c * 8;
    }
    const u16* bSrc[CB]; int bDst[CB];
#pragma unroll
    for (int j = 0; j < CB; j++) {
        int c = tid + j * NTHR;
        int r = c / CPR, p = c - r * CPR;
        bSrc[j] = W + (size_t)(tn * BN + r) * K + (p ^ (r & MSK)) * 8;
        bDst[j] = c * 8;
    }
    int aRd[MF][KC], bRd[NF][KC];
#pragma unroll
    for (int mi = 0; mi < MF; mi++)
#pragma unroll
        for (int kc = 0; kc < KC; kc++)
            aRd[mi][kc] = (wr * MF * 16 + mi * 16 + r16) * BK + (((kc * 4 + q) ^ (r16 & MSK)) << 3);
#pragma unroll
    for (int ni = 0; ni < NF; ni++)
#pragma unroll
        for (int kc = 0; kc < KC; kc++)
            bRd[ni][kc] = (wc * NF * 16 + ni * 16 + r16) * BK + (((kc * 4 + q) ^ (r16 & MSK)) << 3);

    const int nIter = K / BK;

#define ISSUE(slot, it_)                                              \
    do {                                                              \
        const int k0_ = (it_) * BK;                                   \
        _Pragma("unroll")                                             \
        for (int j = 0; j < CA; j++)                                  \
            load16_g2l(aSrc[j] + k0_, &At[slot][aDst[j]]);            \
        _Pragma("unroll")                                             \
        for (int j = 0; j < CB; j++)                                  \
            load16_g2l(bSrc[j] + k0_, &Bt[slot][bDst[j]]);            \
    } while (0)

    ISSUE(0, 0);
    if (nIter > 1) ISSUE(1, 1);

    f32x4 acc[MF][NF];
#pragma unroll
    for (int i = 0; i < MF; i++)
#pragma unroll
        for (int j = 0; j < NF; j++) acc[i][j] = (f32x4){0.f, 0.f, 0.f, 0.f};

    for (int it = 0; it < nIter; ++it) {
        const int s = it & 1;
        if (it + 1 < nIter) __builtin_amdgcn_s_waitcnt(0xF70 | L);
        else                __builtin_amdgcn_s_waitcnt(0xF70);
        __asm__ volatile("" ::: "memory");
        __builtin_amdgcn_s_barrier();
        __asm__ volatile("" ::: "memory");

        s16x8 af[KC][MF], bfr[KC][NF];
#pragma unroll
        for (int kc = 0; kc < KC; kc++) {
#pragma unroll
            for (int mi = 0; mi < MF; mi++) af[kc][mi] = *(const s16x8*)(&At[s][aRd[mi][kc]]);
#pragma unroll
            for (int ni = 0; ni < NF; ni++) bfr[kc][ni] = *(const s16x8*)(&Bt[s][bRd[ni][kc]]);
        }
        __asm__ volatile("" ::: "memory");
        __builtin_amdgcn_s_waitcnt(0xC07F);
        __builtin_amdgcn_s_barrier();
        __asm__ volatile("" ::: "memory");

        if (it + 2 < nIter) ISSUE(s, it + 2);

#pragma unroll
        for (int kc = 0; kc < KC; kc++)
#pragma unroll
            for (int mi = 0; mi < MF; mi++)
#pragma unroll
                for (int ni = 0; ni < NF; ni++)
                    acc[mi][ni] = __builtin_amdgcn_mfma_f32_16x16x32_bf16(af[kc][mi], bfr[kc][ni], acc[mi][ni], 0, 0, 0);
    }
#undef ISSUE

#pragma unroll
    for (int ni = 0; ni < NF; ni++) {
        const int n = tn * BN + wc * NF * 16 + ni * 16 + r16;
        const float bi = bias ? bias[n] : 0.f;
#pragma unroll
        for (int mi = 0; mi < MF; mi++) {
#pragma unroll
            for (int rg = 0; rg < 4; rg++) {
                const int m = tm * BM + wr * MF * 16 + mi * 16 + q * 4 + rg;
                Out[(size_t)m * N + n] = f2bf(sigm(acc[mi][ni][rg] + bi));
            }
        }
    }
}

// ---- tail (fused xcat): lp = sig(xcat @ W6^T); out = (lp - mean) @ W7^T ----
__global__ __launch_bounds__(256) void tail_k(const u16* __restrict__ x5,
                                              const u16* __restrict__ kgT,
                                              const u16* __restrict__ kiT,
                                              const u16* __restrict__ kcT,
                                              const u16* __restrict__ kpT,
                                              const float* __restrict__ clinn,
                                              const float* __restrict__ W6,
                                              const float* __restrict__ W7,
                                              float* __restrict__ out) {
    __shared__ float xs[8 * 400];
    __shared__ float s1[4][8], s2[4][8], s3[4];
    const int tid = threadIdx.x;
    const int b0 = blockIdx.x * 8;
    for (int i = tid; i < 8 * 400; i += 256) {
        int r = i / 400, c = i - r * 400;
        int b = b0 + r;
        float v;
        if (c < 256)      v = bf2f(x5[b * 256 + c]);
        else if (c < 288) v = bf2f(kgT[(c - 256) * 2048 + b]);
        else if (c < 320) v = bf2f(kiT[(c - 288) * 2048 + b]);
        else if (c < 352) v = bf2f(kcT[(c - 320) * 2048 + b]);
        else if (c < 384) v = bf2f(kpT[(c - 352) * 2048 + b]);
        else              v = clinn[b * 16 + (c - 384)];
        xs[i] = v;
    }
    __syncthreads();
    const int j = tid;
    float acc[8];
#pragma unroll
    for (int r = 0; r < 8; r++) acc[r] = 0.f;
    const float4* wrow = (const float4*)(W6 + (size_t)j * 400);
    for (int c = 0; c < 100; c++) {
        float4 wv = wrow[c];
        const float* wp = (const float*)&wv;
#pragma unroll
        for (int t = 0; t < 4; t++) {
            float w = wp[t];
            int k = c * 4 + t;
#pragma unroll
            for (int r = 0; r < 8; r++) acc[r] += w * xs[r * 400 + k];
        }
    }
    const float w7j = W7[j];
    const int lane = tid & 63, wave = tid >> 6;
    float t3 = w7j;
#pragma unroll
    for (int off = 32; off > 0; off >>= 1) t3 += __shfl_down(t3, off, 64);
    if (lane == 0) s3[wave] = t3;
#pragma unroll
    for (int r = 0; r < 8; r++) {
        float lp = sigm(acc[r]);
        float t1 = lp, t2 = lp * w7j;
#pragma unroll
        for (int off = 32; off > 0; off >>= 1) {
            t1 += __shfl_down(t1, off, 64);
            t2 += __shfl_down(t2, off, 64);
        }
        if (lane == 0) { s1[wave][r] = t1; s2[wave][r] = t2; }
    }
    __syncthreads();
    if (tid < 8) {
        float S1 = s1[0][tid] + s1[1][tid] + s1[2][tid] + s1[3][tid];
        float S2 = s2[0][tid] + s2[1][tid] + s2[2][tid] + s2[3][tid];
        float SW = s3[0] + s3[1] + s3[2] + s3[3];
        out[b0 + tid] = S2 - (S1 * (1.f / 256.f)) * SW;
    }
}

// ---------------------------------------------------------------------------
extern "C" void kernel_launch(void* const* d_in, const int* in_sizes, int n_in,
                              void* d_out, int out_size, void* d_ws, size_t ws_size,
                              hipStream_t stream) {
    const float* x_gene   = (const float*)d_in[0];
    const float* x_invmea = (const float*)d_in[1];
    const float* x_curv   = (const float*)d_in[2];
    const float* clinn    = (const float*)d_in[3];
    const float* Adj      = (const float*)d_in[4];
    const float* edge_m   = (const float*)d_in[5];
    const float* path_m   = (const float*)d_in[6];
    const float* tg_mask  = (const float*)d_in[7];
    const float* ti_mask  = (const float*)d_in[8];
    const float* tc_mask  = (const float*)d_in[9];
    const float* tp_mask  = (const float*)d_in[10];
    const float* W1 = (const float*)d_in[11];  const float* b1 = (const float*)d_in[12];
    const float* W2 = (const float*)d_in[13];  const float* b2 = (const float*)d_in[14];
    const float* W3 = (const float*)d_in[15];  const float* b3 = (const float*)d_in[16];
    const float* W4 = (const float*)d_in[17];  const float* b4 = (const float*)d_in[18];
    const float* W5 = (const float*)d_in[19];  const float* b5 = (const float*)d_in[20];
    const float* W6 = (const float*)d_in[21];
    const float* W7 = (const float*)d_in[22];
    const float* mp11 = (const float*)d_in[23];
    const float* mp12 = (const float*)d_in[24];
    const float* mp1  = (const float*)d_in[25];
    const float* mp21 = (const float*)d_in[26];
    const float* mp22 = (const float*)d_in[27];
    const float* mp2  = (const float*)d_in[28];
    const float* mp3  = (const float*)d_in[29];

    char* ws = (char*)d_ws;
    const float* nulf = nullptr;
    float* out = (float*)d_out;

    u16*  xTg   = (u16*)(ws + 0);            // 16 MiB [4096][2048]
    u16*  xinvT = (u16*)(ws + 16777216);     // 16 MiB
    u16*  xcvT  = (u16*)(ws + 33554432);     // 32 MiB
    u16*  x1T   = (u16*)(ws + 67108864);     // 16 MiB
    u16*  x2T   = (u16*)(ws + 83886080);     // 32 MiB
    u16*  x3T   = (u16*)(ws + 117440512);    //  8 MiB
    u16*  x3    = (u16*)(ws + 125829120);    //  8 MiB
    unsigned* ell1 = (unsigned*)(ws + 134217728);  // 4 MiB
    unsigned* ell2 = (unsigned*)(ws + 138412032);  // 3 MiB
    unsigned* ell3 = (unsigned*)(ws + 141557760);  // 2.5 MiB
    int* cnt1 = (int*)(ws + 144179200);
    int* cnt2 = (int*)(ws + 144195584);
    int* cnt3 = (int*)(ws + 144228352);
    int* idxg = (int*)(ws + 144236544);      // 512 B (4 x 32 ints)
    int* idxi = idxg + 32;
    int* idxc = idxg + 64;
    int* idxp = idxg + 96;
    u16* kgT  = (u16*)(ws + 144237056);      // 128 KiB [32][2048]
    u16* kiT  = (u16*)(ws + 144368128);
    u16* kcT  = (u16*)(ws + 144499200);
    u16* kpT  = (u16*)(ws + 144630272);
    u16* w4b  = (u16*)(ws + 144761344);      // 1 MiB
    u16* w5b  = (u16*)(ws + 145809920);      // 128 KiB
    u16* x4   = (u16*)(ws + 145940992);      // 1 MiB
    u16* x5   = (u16*)(ws + 146989568);      // 1 MiB

    // ---- prep (split: streaming misc + register-resident ELL builds) -------
    prep_ell<<<3584, 256, 0, stream>>>(
        Adj, W1, ell1, cnt1, edge_m, W2, ell2, cnt2, path_m, W3, ell3, cnt3);
    prep_misc<<<8608, 256, 0, stream>>>(
        x_gene, x_invmea, x_curv, xTg, xinvT, xcvT,
        tg_mask, ti_mask, tc_mask, tp_mask, idxg, W4, w4b, W5, w5b);
    gatherFT<<<256, 256, 0, stream>>>(x_gene, 4096, idxg, kgT);

    // ---- L1 (fused kiT gather) ----
    spmm<4><<<dim3(8, 1024), 256, 0, stream>>>(ell1, cnt1, xTg, x1T, b1,
                                               mp11, mp1, mp12, mp1, xinvT,
                                               idxi, kiT, 256);
    // ---- L2 (fused kcT gather) ----
    spmm<4><<<dim3(8, 2048), 256, 0, stream>>>(ell2, cnt2, x1T, x2T, b2,
                                               mp21, mp2, mp22, mp2, xcvT,
                                               idxc, kcT, 96);
    // ---- L3 (fused kpT gather) ----
    spmm<4><<<dim3(8, 512), 256, 0, stream>>>(ell3, cnt3, x2T, x3T, b3,
                                              nulf, nulf, mp3, nulf, (const u16*)nullptr,
                                              idxp, kpT, 320);
    transpB<<<dim3(32, 32), 256, 0, stream>>>(x3T, x3, 2048, 2048);

    // ---- L4/L5 dense ----
    gemm_t<2, 2, 2, 2, 2, 4><<<dim3(4, 32), 256, 0, stream>>>(x3, w4b, x4, b4, 256, 2048);
    gemm_t<2, 2, 2, 2, 2, 4><<<dim3(4, 32), 256, 0, stream>>>(x4, w5b, x5, b5, 256, 256);

    // ---- fused xcat + tail ----
    tail_k<<<256, 256, 0, stream>>>(x5, kgT, kiT, kcT, kpT, clinn, W6, W7, out);
}

// Round 12
// 894.478 us; speedup vs baseline: 1.2920x; 1.0185x over previous
//
#include <hip/hip_runtime.h>

typedef unsigned short u16;
typedef __attribute__((ext_vector_type(4))) float f32x4;
typedef __attribute__((ext_vector_type(8))) short s16x8;

__device__ __forceinline__ u16 f2bf(float f) {
    union { float f; unsigned u; } c; c.f = f;
    return (u16)((c.u + 0x7fffu + ((c.u >> 16) & 1u)) >> 16);
}
__device__ __forceinline__ float bf2f(u16 u) {
    union { unsigned u; float f; } c; c.u = ((unsigned)u) << 16; return c.f;
}
__device__ __forceinline__ unsigned pk2(float a, float b) {
    return (unsigned)f2bf(a) | ((unsigned)f2bf(b) << 16);
}
__device__ __forceinline__ float sigm(float x) { return 1.0f / (1.0f + __expf(-x)); }
__device__ __forceinline__ void fma2(unsigned xv, float w, float& a0, float& a1) {
    union { float f; unsigned u; } lo, hi;
    lo.u = xv << 16; hi.u = xv & 0xFFFF0000u;
    a0 += w * lo.f; a1 += w * hi.f;
}

// async global->LDS, 16B/lane (dense gemm for L4/L5)
__device__ __forceinline__ void load16_g2l(const void* g, void* l) {
    __builtin_amdgcn_global_load_lds(
        (const __attribute__((address_space(1))) unsigned int*)(unsigned long long)g,
        (__attribute__((address_space(3))) unsigned int*)(unsigned int)(unsigned long long)l,
        16, 0, 0);
}

// ======================= prep_misc: transposes + find + conv =================
__device__ void d_transpF(const float* __restrict__ in, u16* __restrict__ out,
                          int Rr, int Cc, int bx, int by, float (*t)[65]) {
    const int r0 = by * 64, c0 = bx * 64;
    const int tid = threadIdx.x;
#pragma unroll
    for (int i = 0; i < 16; i++) {
        int idx = tid + i * 256;
        int rr = idx >> 6, cc = idx & 63;
        t[rr][cc] = in[(size_t)(r0 + rr) * Cc + c0 + cc];
    }
    __syncthreads();
#pragma unroll
    for (int i = 0; i < 16; i++) {
        int idx = tid + i * 256;
        int cc = idx >> 6, rr = idx & 63;
        out[(size_t)(c0 + cc) * Rr + r0 + rr] = f2bf(t[rr][cc]);
    }
}

__device__ void d_find(const float* __restrict__ mask, int n, int* __restrict__ outp,
                       int* red, int k) {
    int best = -1;
    for (int i = threadIdx.x; i < n; i += 256)
        if (mask[(size_t)i * 32 + k] != 0.0f) best = i;
    red[threadIdx.x] = best;
    __syncthreads();
    for (int off = 128; off > 0; off >>= 1) {
        if (threadIdx.x < off) {
            int o = red[threadIdx.x + off];
            if (o > red[threadIdx.x]) red[threadIdx.x] = o;
        }
        __syncthreads();
    }
    if (threadIdx.x == 0) *outp = red[0] < 0 ? 0 : red[0];
}

__device__ void d_conv(const float* __restrict__ in, u16* __restrict__ out,
                       int bid, unsigned n8) {
    unsigned i = bid * 256u + threadIdx.x;
    if (i >= n8) return;
    float4 a = ((const float4*)in)[2 * i];
    float4 b = ((const float4*)in)[2 * i + 1];
    uint4 o;
    o.x = pk2(a.x, a.y); o.y = pk2(a.z, a.w);
    o.z = pk2(b.x, b.y); o.w = pk2(b.z, b.w);
    ((uint4*)out)[i] = o;
}

// grid = 2048 + 2048 + 4096 + 128 + 256 + 32 = 8608
__global__ __launch_bounds__(256) void prep_misc(
    const float* __restrict__ xg_f, const float* __restrict__ xinv_f,
    const float* __restrict__ xcv_f,
    u16* __restrict__ xTg, u16* __restrict__ xinvT, u16* __restrict__ xcvT,
    const float* __restrict__ m0, const float* __restrict__ m1,
    const float* __restrict__ m2, const float* __restrict__ m3,
    int* __restrict__ idx,
    const float* __restrict__ W4, u16* __restrict__ w4b,
    const float* __restrict__ W5, u16* __restrict__ w5b) {
    __shared__ float tile[64][65];
    int id = blockIdx.x;
    if (id < 2048) { d_transpF(xg_f, xTg, 2048, 4096, id & 63, id >> 6, tile); return; }
    id -= 2048;
    if (id < 2048) { d_transpF(xinv_f, xinvT, 2048, 4096, id & 63, id >> 6, tile); return; }
    id -= 2048;
    if (id < 4096) { d_transpF(xcv_f, xcvT, 2048, 8192, id & 127, id >> 7, tile); return; }
    id -= 4096;
    if (id < 128) {
        const float* mk; int n;
        int which = id >> 5;
        if (which == 0)      { mk = m0; n = 4096; }
        else if (which == 1) { mk = m1; n = 4096; }
        else if (which == 2) { mk = m2; n = 8192; }
        else                 { mk = m3; n = 2048; }
        d_find(mk, n, idx + which * 32 + (id & 31), (int*)tile, id & 31);
        return;
    }
    id -= 128;
    if (id < 256) { d_conv(W4, w4b, id, 65536u); return; }
    id -= 256;
    d_conv(W5, w5b, id, 8192u);
}

// ======================= prep_ell v2: streamed mask+W, register-resident =====
// CHUNKS * 2048 = C. Per chunk: 8 float4 mask + 8 float4 W per lane loaded
// unconditionally (16 coalesced loads in flight); write pass consumes
// registers only -> no load-latency in the conditional store chain.
template <int CHUNKS>
__device__ void d_ell_reg(const float* __restrict__ M, const float* __restrict__ W,
                          unsigned* __restrict__ ell, int* __restrict__ cnt,
                          int PAD, int R, int bid) {
    const int lane = threadIdx.x & 63;
    const int row = bid * 4 + (threadIdx.x >> 6);
    if (row >= R) return;
    const int C = CHUNKS * 2048;
    const float4* mrow = (const float4*)(M + (size_t)row * C);
    const float4* wrow = (const float4*)(W + (size_t)row * C);
    unsigned* erow = ell + (size_t)row * PAD;
    int base = 0;
#pragma unroll
    for (int h = 0; h < CHUNKS; h++) {
        float4 m[8], w[8];
#pragma unroll
        for (int i = 0; i < 8; i++) m[i] = mrow[h * 512 + lane + i * 64];
#pragma unroll
        for (int i = 0; i < 8; i++) w[i] = wrow[h * 512 + lane + i * 64];
        int n = 0;
#pragma unroll
        for (int i = 0; i < 8; i++)
            n += (m[i].x != 0.f) + (m[i].y != 0.f) + (m[i].z != 0.f) + (m[i].w != 0.f);
        int pre = n;
#pragma unroll
        for (int off = 1; off < 64; off <<= 1) {
            int t = __shfl_up(pre, off, 64);
            if (lane >= off) pre += t;
        }
        int s = base + pre - n;
#pragma unroll
        for (int i = 0; i < 8; i++) {
            int c = h * 2048 + lane * 4 + i * 256;
            if (m[i].x != 0.f) { if (s < PAD) erow[s] = ((unsigned)f2bf(w[i].x) << 16) | (unsigned)(c + 0); s++; }
            if (m[i].y != 0.f) { if (s < PAD) erow[s] = ((unsigned)f2bf(w[i].y) << 16) | (unsigned)(c + 1); s++; }
            if (m[i].z != 0.f) { if (s < PAD) erow[s] = ((unsigned)f2bf(w[i].z) << 16) | (unsigned)(c + 2); s++; }
            if (m[i].w != 0.f) { if (s < PAD) erow[s] = ((unsigned)f2bf(w[i].w) << 16) | (unsigned)(c + 3); s++; }
        }
        base += __shfl(pre, 63, 64);
    }
    if (lane == 0) cnt[row] = base > PAD ? PAD : base;
}

// grid = 1024 + 2048 + 512 = 3584
__global__ __launch_bounds__(256) void prep_ell(
    const float* __restrict__ Adj, const float* __restrict__ W1,
    unsigned* __restrict__ ell1, int* __restrict__ cnt1,
    const float* __restrict__ edge, const float* __restrict__ W2,
    unsigned* __restrict__ ell2, int* __restrict__ cnt2,
    const float* __restrict__ path, const float* __restrict__ W3,
    unsigned* __restrict__ ell3, int* __restrict__ cnt3) {
    int id = blockIdx.x;
    if (id < 1024) { d_ell_reg<2>(Adj, W1, ell1, cnt1, 256, 4096, id); return; }
    id -= 1024;
    if (id < 2048) { d_ell_reg<2>(edge, W2, ell2, cnt2, 96, 8192, id); return; }
    id -= 2048;
    d_ell_reg<4>(path, W3, ell3, cnt3, 320, 2048, id);
}

// ---- sparse layer: wave = row j, lanes = batch slice -----------------------
// BPL=4, grid.x = 8 -> block id % 8 == batch-slice -> XCD-pinned x working set.
// Fused one-hot gather: if j is in gidx, mirror the packed store into gdst.
template <int BPL>
__global__ __launch_bounds__(256) void spmm(const unsigned* __restrict__ ell,
                                            const int* __restrict__ cnt,
                                            const u16* __restrict__ xT,    // [C][2048]
                                            u16* __restrict__ outT,        // [R][2048]
                                            const float* __restrict__ bias,
                                            const float* __restrict__ c1a,
                                            const float* __restrict__ c1b,
                                            const float* __restrict__ c2a,
                                            const float* __restrict__ c2b,
                                            const u16* __restrict__ invT,
                                            const int* __restrict__ gidx,
                                            u16* __restrict__ gdst,
                                            int PAD) {
    const int lane = threadIdx.x & 63;
    const int wv = __builtin_amdgcn_readfirstlane((int)(threadIdx.x >> 6));
    const int j = blockIdx.y * 4 + wv;
    const int b0 = blockIdx.x * (64 * BPL) + lane * BPL;

    const unsigned* ep = ell + (size_t)j * PAD;
    int len = cnt[j];
    if (len > PAD) len = PAD;

    float acc[BPL];
#pragma unroll
    for (int i = 0; i < BPL; i++) acc[i] = 0.f;

    const int nfull = len >> 3;
    unsigned eA[8];
    if (nfull > 0) {
#pragma unroll
        for (int t = 0; t < 8; t++) eA[t] = ep[t];
    }
    for (int g = 0; g < nfull; g++) {
        unsigned eB[8];
        const bool more = (g + 1 < nfull);
        if (more) {
#pragma unroll
            for (int t = 0; t < 8; t++) eB[t] = ep[(g + 1) * 8 + t];
        }
        if (BPL == 8) {
            uint4 xv[8];
#pragma unroll
            for (int t = 0; t < 8; t++)
                xv[t] = *(const uint4*)(xT + ((size_t)(eA[t] & 0xFFFFu) << 11) + b0);
#pragma unroll
            for (int t = 0; t < 8; t++) {
                union { float f; unsigned u; } w; w.u = (eA[t] >> 16) << 16;
                fma2(xv[t].x, w.f, acc[0], acc[1]);
                fma2(xv[t].y, w.f, acc[2], acc[3]);
                fma2(xv[t].z, w.f, acc[4], acc[5]);
                fma2(xv[t].w, w.f, acc[6], acc[7]);
            }
        } else {
            uint2 xv[8];
#pragma unroll
            for (int t = 0; t < 8; t++)
                xv[t] = *(const uint2*)(xT + ((size_t)(eA[t] & 0xFFFFu) << 11) + b0);
#pragma unroll
            for (int t = 0; t < 8; t++) {
                union { float f; unsigned u; } w; w.u = (eA[t] >> 16) << 16;
                fma2(xv[t].x, w.f, acc[0], acc[1]);
                fma2(xv[t].y, w.f, acc[2], acc[3]);
            }
        }
        if (more) {
#pragma unroll
            for (int t = 0; t < 8; t++) eA[t] = eB[t];
        }
    }
    for (int s = nfull * 8; s < len; ++s) {
        unsigned e = ep[s];
        union { float f; unsigned u; } w; w.u = (e >> 16) << 16;
        const u16* xp = xT + ((size_t)(e & 0xFFFFu) << 11) + b0;
        if (BPL == 8) {
            uint4 xv = *(const uint4*)xp;
            fma2(xv.x, w.f, acc[0], acc[1]); fma2(xv.y, w.f, acc[2], acc[3]);
            fma2(xv.z, w.f, acc[4], acc[5]); fma2(xv.w, w.f, acc[6], acc[7]);
        } else {
            uint2 xv = *(const uint2*)xp;
            fma2(xv.x, w.f, acc[0], acc[1]); fma2(xv.y, w.f, acc[2], acc[3]);
        }
    }

    const float bi = bias[j];
    float c1 = 0.f;
    if (c1a) { c1 = c1a[j]; if (c1b) c1 *= c1b[j]; }
    float c2 = 1.f;
    if (c2a) { c2 = c2a[j]; if (c2b) c2 *= c2b[j]; }

    float v[BPL];
#pragma unroll
    for (int i = 0; i < BPL; i++) v[i] = sigm(acc[i] + bi) * c2;
    if (invT) {
        const unsigned long long* ip = (const unsigned long long*)(invT + ((size_t)j << 11) + b0);
#pragma unroll
        for (int h = 0; h < BPL / 4; h++) {
            unsigned long long iv = __builtin_nontemporal_load(ip + h);
            unsigned lo = (unsigned)iv, hi = (unsigned)(iv >> 32);
            union { float f; unsigned u; } g0, g1, g2, g3;
            g0.u = lo << 16; g1.u = lo & 0xFFFF0000u;
            g2.u = hi << 16; g3.u = hi & 0xFFFF0000u;
            v[4 * h + 0] += g0.f * c1; v[4 * h + 1] += g1.f * c1;
            v[4 * h + 2] += g2.f * c1; v[4 * h + 3] += g3.f * c1;
        }
    }
    unsigned long long pkv[BPL / 4];
#pragma unroll
    for (int h = 0; h < BPL / 4; h++)
        pkv[h] = (unsigned long long)pk2(v[4 * h + 0], v[4 * h + 1])
               | ((unsigned long long)pk2(v[4 * h + 2], v[4 * h + 3]) << 32);
    unsigned long long* op = (unsigned long long*)(outT + ((size_t)j << 11) + b0);
#pragma unroll
    for (int h = 0; h < BPL / 4; h++) __builtin_nontemporal_store(pkv[h], op + h);

    // fused one-hot column gather (wave-uniform scalar compares)
    if (gdst) {
        for (int t = 0; t < 32; t++) {
            if (gidx[t] == j) {
                unsigned long long* gp = (unsigned long long*)(gdst + t * 2048 + b0);
#pragma unroll
                for (int h = 0; h < BPL / 4; h++) gp[h] = pkv[h];
            }
        }
    }
}

// ---- gather into transposed kept array [32][2048] from f32 source ----------
__global__ __launch_bounds__(256) void gatherFT(const float* __restrict__ src, int ld,
                                                const int* __restrict__ idx,
                                                u16* __restrict__ dstT) {
    int i = blockIdx.x * 256 + threadIdx.x;  // 65536
    int kk = i >> 11, b = i & 2047;
    dstT[i] = f2bf(src[(size_t)b * ld + idx[kk]]);
}

// ---- bf16 [Rr][Cc] -> bf16 transposed [Cc][Rr] -----------------------------
__global__ __launch_bounds__(256) void transpB(const u16* __restrict__ in,
                                               u16* __restrict__ out, int Rr, int Cc) {
    __shared__ u16 t[64][66];
    const int r0 = blockIdx.y * 64, c0 = blockIdx.x * 64;
    const int tid = threadIdx.x;
#pragma unroll
    for (int i = 0; i < 16; i++) {
        int idx = tid + i * 256;
        int rr = idx >> 6, cc = idx & 63;
        t[rr][cc] = in[(size_t)(r0 + rr) * Cc + c0 + cc];
    }
    __syncthreads();
#pragma unroll
    for (int i = 0; i < 16; i++) {
        int idx = tid + i * 256;
        int cc = idx >> 6, rr = idx & 63;
        out[(size_t)(c0 + cc) * Rr + r0 + rr] = t[rr][cc];
    }
}

// ---- dense NT GEMM, used for small L4/L5 only ------------------------------
template <int WR, int WC, int MF, int NF, int KC, int WPE>
__global__ __launch_bounds__(WR * WC * 64, WPE)
void gemm_t(const u16* __restrict__ A, const u16* __restrict__ W,
            u16* __restrict__ Out, const float* __restrict__ bias, int N, int K) {
    constexpr int NTHR = WR * WC * 64;
    constexpr int BM = WR * MF * 16;
    constexpr int BN = WC * NF * 16;
    constexpr int BK = KC * 32;
    constexpr int CPR = KC * 4;
    constexpr int MSK = CPR - 1;
    constexpr int CA = BM * CPR / NTHR;
    constexpr int CB = BN * CPR / NTHR;
    constexpr int L  = CA + CB;

    __shared__ u16 At[2][BM * BK];
    __shared__ u16 Bt[2][BN * BK];

    const int tid = threadIdx.x;
    const int lane = tid & 63;
    const int wave = tid >> 6;
    const int wr = wave / WC, wc = wave % WC;
    const int tn = blockIdx.x, tm = blockIdx.y;
    const int r16 = lane & 15;
    const int q = lane >> 4;

    const u16* aSrc[CA]; int aDst[CA];
#pragma unroll
    for (int j = 0; j < CA; j++) {
        int c = tid + j * NTHR;
        int r = c / CPR, p = c - r * CPR;
        aSrc[j] = A + (size_t)(tm * BM + r) * K + (p ^ (r & MSK)) * 8;
        aDst[j] = c * 8;
    }
    const u16* bSrc[CB]; int bDst[CB];
#pragma unroll
    for (int j = 0; j < CB; j++) {
        int c = tid + j * NTHR;
        int r = c / CPR, p = c - r * CPR;
        bSrc[j] = W + (size_t)(tn * BN + r) * K + (p ^ (r & MSK)) * 8;
        bDst[j] = c * 8;
    }
    int aRd[MF][KC], bRd[NF][KC];
#pragma unroll
    for (int mi = 0; mi < MF; mi++)
#pragma unroll
        for (int kc = 0; kc < KC; kc++)
            aRd[mi][kc] = (wr * MF * 16 + mi * 16 + r16) * BK + (((kc * 4 + q) ^ (r16 & MSK)) << 3);
#pragma unroll
    for (int ni = 0; ni < NF; ni++)
#pragma unroll
        for (int kc = 0; kc < KC; kc++)
            bRd[ni][kc] = (wc * NF * 16 + ni * 16 + r16) * BK + (((kc * 4 + q) ^ (r16 & MSK)) << 3);

    const int nIter = K / BK;

#define ISSUE(slot, it_)                                              \
    do {                                                              \
        const int k0_ = (it_) * BK;                                   \
        _Pragma("unroll")                                             \
        for (int j = 0; j < CA; j++)                                  \
            load16_g2l(aSrc[j] + k0_, &At[slot][aDst[j]]);            \
        _Pragma("unroll")                                             \
        for (int j = 0; j < CB; j++)                                  \
            load16_g2l(bSrc[j] + k0_, &Bt[slot][bDst[j]]);            \
    } while (0)

    ISSUE(0, 0);
    if (nIter > 1) ISSUE(1, 1);

    f32x4 acc[MF][NF];
#pragma unroll
    for (int i = 0; i < MF; i++)
#pragma unroll
        for (int j = 0; j < NF; j++) acc[i][j] = (f32x4){0.f, 0.f, 0.f, 0.f};

    for (int it = 0; it < nIter; ++it) {
        const int s = it & 1;
        if (it + 1 < nIter) __builtin_amdgcn_s_waitcnt(0xF70 | L);
        else                __builtin_amdgcn_s_waitcnt(0xF70);
        __asm__ volatile("" ::: "memory");
        __builtin_amdgcn_s_barrier();
        __asm__ volatile("" ::: "memory");

        s16x8 af[KC][MF], bfr[KC][NF];
#pragma unroll
        for (int kc = 0; kc < KC; kc++) {
#pragma unroll
            for (int mi = 0; mi < MF; mi++) af[kc][mi] = *(const s16x8*)(&At[s][aRd[mi][kc]]);
#pragma unroll
            for (int ni = 0; ni < NF; ni++) bfr[kc][ni] = *(const s16x8*)(&Bt[s][bRd[ni][kc]]);
        }
        __asm__ volatile("" ::: "memory");
        __builtin_amdgcn_s_waitcnt(0xC07F);
        __builtin_amdgcn_s_barrier();
        __asm__ volatile("" ::: "memory");

        if (it + 2 < nIter) ISSUE(s, it + 2);

#pragma unroll
        for (int kc = 0; kc < KC; kc++)
#pragma unroll
            for (int mi = 0; mi < MF; mi++)
#pragma unroll
                for (int ni = 0; ni < NF; ni++)
                    acc[mi][ni] = __builtin_amdgcn_mfma_f32_16x16x32_bf16(af[kc][mi], bfr[kc][ni], acc[mi][ni], 0, 0, 0);
    }
#undef ISSUE

#pragma unroll
    for (int ni = 0; ni < NF; ni++) {
        const int n = tn * BN + wc * NF * 16 + ni * 16 + r16;
        const float bi = bias ? bias[n] : 0.f;
#pragma unroll
        for (int mi = 0; mi < MF; mi++) {
#pragma unroll
            for (int rg = 0; rg < 4; rg++) {
                const int m = tm * BM + wr * MF * 16 + mi * 16 + q * 4 + rg;
                Out[(size_t)m * N + n] = f2bf(sigm(acc[mi][ni][rg] + bi));
            }
        }
    }
}

// ---- tail (fused xcat): lp = sig(xcat @ W6^T); out = (lp - mean) @ W7^T ----
__global__ __launch_bounds__(256) void tail_k(const u16* __restrict__ x5,
                                              const u16* __restrict__ kgT,
                                              const u16* __restrict__ kiT,
                                              const u16* __restrict__ kcT,
                                              const u16* __restrict__ kpT,
                                              const float* __restrict__ clinn,
                                              const float* __restrict__ W6,
                                              const float* __restrict__ W7,
                                              float* __restrict__ out) {
    __shared__ float xs[8 * 400];
    __shared__ float s1[4][8], s2[4][8], s3[4];
    const int tid = threadIdx.x;
    const int b0 = blockIdx.x * 8;
    for (int i = tid; i < 8 * 400; i += 256) {
        int r = i / 400, c = i - r * 400;
        int b = b0 + r;
        float v;
        if (c < 256)      v = bf2f(x5[b * 256 + c]);
        else if (c < 288) v = bf2f(kgT[(c - 256) * 2048 + b]);
        else if (c < 320) v = bf2f(kiT[(c - 288) * 2048 + b]);
        else if (c < 352) v = bf2f(kcT[(c - 320) * 2048 + b]);
        else if (c < 384) v = bf2f(kpT[(c - 352) * 2048 + b]);
        else              v = clinn[b * 16 + (c - 384)];
        xs[i] = v;
    }
    __syncthreads();
    const int j = tid;
    float acc[8];
#pragma unroll
    for (int r = 0; r < 8; r++) acc[r] = 0.f;
    const float4* wrow = (const float4*)(W6 + (size_t)j * 400);
    for (int c = 0; c < 100; c++) {
        float4 wv = wrow[c];
        const float* wp = (const float*)&wv;
#pragma unroll
        for (int t = 0; t < 4; t++) {
            float w = wp[t];
            int k = c * 4 + t;
#pragma unroll
            for (int r = 0; r < 8; r++) acc[r] += w * xs[r * 400 + k];
        }
    }
    const float w7j = W7[j];
    const int lane = tid & 63, wave = tid >> 6;
    float t3 = w7j;
#pragma unroll
    for (int off = 32; off > 0; off >>= 1) t3 += __shfl_down(t3, off, 64);
    if (lane == 0) s3[wave] = t3;
#pragma unroll
    for (int r = 0; r < 8; r++) {
        float lp = sigm(acc[r]);
        float t1 = lp, t2 = lp * w7j;
#pragma unroll
        for (int off = 32; off > 0; off >>= 1) {
            t1 += __shfl_down(t1, off, 64);
            t2 += __shfl_down(t2, off, 64);
        }
        if (lane == 0) { s1[wave][r] = t1; s2[wave][r] = t2; }
    }
    __syncthreads();
    if (tid < 8) {
        float S1 = s1[0][tid] + s1[1][tid] + s1[2][tid] + s1[3][tid];
        float S2 = s2[0][tid] + s2[1][tid] + s2[2][tid] + s2[3][tid];
        float SW = s3[0] + s3[1] + s3[2] + s3[3];
        out[b0 + tid] = S2 - (S1 * (1.f / 256.f)) * SW;
    }
}

// ---------------------------------------------------------------------------
extern "C" void kernel_launch(void* const* d_in, const int* in_sizes, int n_in,
                              void* d_out, int out_size, void* d_ws, size_t ws_size,
                              hipStream_t stream) {
    const float* x_gene   = (const float*)d_in[0];
    const float* x_invmea = (const float*)d_in[1];
    const float* x_curv   = (const float*)d_in[2];
    const float* clinn    = (const float*)d_in[3];
    const float* Adj      = (const float*)d_in[4];
    const float* edge_m   = (const float*)d_in[5];
    const float* path_m   = (const float*)d_in[6];
    const float* tg_mask  = (const float*)d_in[7];
    const float* ti_mask  = (const float*)d_in[8];
    const float* tc_mask  = (const float*)d_in[9];
    const float* tp_mask  = (const float*)d_in[10];
    const float* W1 = (const float*)d_in[11];  const float* b1 = (const float*)d_in[12];
    const float* W2 = (const float*)d_in[13];  const float* b2 = (const float*)d_in[14];
    const float* W3 = (const float*)d_in[15];  const float* b3 = (const float*)d_in[16];
    const float* W4 = (const float*)d_in[17];  const float* b4 = (const float*)d_in[18];
    const float* W5 = (const float*)d_in[19];  const float* b5 = (const float*)d_in[20];
    const float* W6 = (const float*)d_in[21];
    const float* W7 = (const float*)d_in[22];
    const float* mp11 = (const float*)d_in[23];
    const float* mp12 = (const float*)d_in[24];
    const float* mp1  = (const float*)d_in[25];
    const float* mp21 = (const float*)d_in[26];
    const float* mp22 = (const float*)d_in[27];
    const float* mp2  = (const float*)d_in[28];
    const float* mp3  = (const float*)d_in[29];

    char* ws = (char*)d_ws;
    const float* nulf = nullptr;
    float* out = (float*)d_out;

    u16*  xTg   = (u16*)(ws + 0);            // 16 MiB [4096][2048]
    u16*  xinvT = (u16*)(ws + 16777216);     // 16 MiB
    u16*  xcvT  = (u16*)(ws + 33554432);     // 32 MiB
    u16*  x1T   = (u16*)(ws + 67108864);     // 16 MiB
    u16*  x2T   = (u16*)(ws + 83886080);     // 32 MiB
    u16*  x3T   = (u16*)(ws + 117440512);    //  8 MiB
    u16*  x3    = (u16*)(ws + 125829120);    //  8 MiB
    unsigned* ell1 = (unsigned*)(ws + 134217728);  // 4 MiB
    unsigned* ell2 = (unsigned*)(ws + 138412032);  // 3 MiB
    unsigned* ell3 = (unsigned*)(ws + 141557760);  // 2.5 MiB
    int* cnt1 = (int*)(ws + 144179200);
    int* cnt2 = (int*)(ws + 144195584);
    int* cnt3 = (int*)(ws + 144228352);
    int* idxg = (int*)(ws + 144236544);      // 512 B (4 x 32 ints)
    int* idxi = idxg + 32;
    int* idxc = idxg + 64;
    int* idxp = idxg + 96;
    u16* kgT  = (u16*)(ws + 144237056);      // 128 KiB [32][2048]
    u16* kiT  = (u16*)(ws + 144368128);
    u16* kcT  = (u16*)(ws + 144499200);
    u16* kpT  = (u16*)(ws + 144630272);
    u16* w4b  = (u16*)(ws + 144761344);      // 1 MiB
    u16* w5b  = (u16*)(ws + 145809920);      // 128 KiB
    u16* x4   = (u16*)(ws + 145940992);      // 1 MiB
    u16* x5   = (u16*)(ws + 146989568);      // 1 MiB

    // ---- prep (streaming mask+W ELL build; streaming misc) -----------------
    prep_ell<<<3584, 256, 0, stream>>>(
        Adj, W1, ell1, cnt1, edge_m, W2, ell2, cnt2, path_m, W3, ell3, cnt3);
    prep_misc<<<8608, 256, 0, stream>>>(
        x_gene, x_invmea, x_curv, xTg, xinvT, xcvT,
        tg_mask, ti_mask, tc_mask, tp_mask, idxg, W4, w4b, W5, w5b);
    gatherFT<<<256, 256, 0, stream>>>(x_gene, 4096, idxg, kgT);

    // ---- L1 (fused kiT gather) ----
    spmm<4><<<dim3(8, 1024), 256, 0, stream>>>(ell1, cnt1, xTg, x1T, b1,
                                               mp11, mp1, mp12, mp1, xinvT,
                                               idxi, kiT, 256);
    // ---- L2 (fused kcT gather) ----
    spmm<4><<<dim3(8, 2048), 256, 0, stream>>>(ell2, cnt2, x1T, x2T, b2,
                                               mp21, mp2, mp22, mp2, xcvT,
                                               idxc, kcT, 96);
    // ---- L3 (fused kpT gather) ----
    spmm<4><<<dim3(8, 512), 256, 0, stream>>>(ell3, cnt3, x2T, x3T, b3,
                                              nulf, nulf, mp3, nulf, (const u16*)nullptr,
                                              idxp, kpT, 320);
    transpB<<<dim3(32, 32), 256, 0, stream>>>(x3T, x3, 2048, 2048);

    // ---- L4/L5 dense ----
    gemm_t<2, 2, 2, 2, 2, 4><<<dim3(4, 32), 256, 0, stream>>>(x3, w4b, x4, b4, 256, 2048);
    gemm_t<2, 2, 2, 2, 2, 4><<<dim3(4, 32), 256, 0, stream>>>(x4, w5b, x5, b5, 256, 256);

    // ---- fused xcat + tail ----
    tail_k<<<256, 256, 0, stream>>>(x5, kgT, kiT, kcT, kpT, clinn, W6, W7, out);
}